// Round 4
// baseline (3103.832 us; speedup 1.0000x reference)
//
#include <hip/hip_runtime.h>
#include <hip/hip_bf16.h>

using bf16 = __hip_bfloat16;

#define DI __device__ __forceinline__

DI float b2f(bf16 v) { return __bfloat162float(v); }
DI float leaky(float x) { return x > 0.f ? x : 0.1f * x; }

// Flag-dispatched input load: inputs may be fp32 (per reference) or bf16.
// Decided at runtime by k_detect. (R3 evidence: fp32.)
DI float ldin(const void* p, size_t i, int isbf) {
  return isbf ? b2f(((const bf16*)p)[i]) : ((const float*)p)[i];
}

// Problem constants: B=2, C=64, H=64, W=64, N=4096
static constexpr int N_ = 4096;
static constexpr size_t CN = 262144;   // C*N per batch
static constexpr size_t BCN = 524288;  // B*C*N

// ---- Workspace layout (float indices) ----
static constexpr size_t LW_O = 0, LB_O = 1, GM_O = 2, AL_O = 3;
static constexpr size_t CW_O  = 4;                  // 38016
static constexpr size_t XQW_O = 38020;              // 4096
static constexpr size_t XQB_O = 42116;              // 64
static constexpr size_t XKW_O = 42180;
static constexpr size_t XKB_O = 46276;
static constexpr size_t XVW_O = 46340;
static constexpr size_t XVB_O = 50436;
static constexpr size_t GQW_O = 50500;
static constexpr size_t GQB_O = 54596;
static constexpr size_t GKW_O = 54660;
static constexpr size_t GKB_O = 58756;
static constexpr size_t C1W_O = 58820;              // 36864
static constexpr size_t C1B_O = 95684;
static constexpr size_t C2W_O = 95748;              // 36864
static constexpr size_t C2B_O = 132612;
static constexpr size_t SCW_O = 132676;             // 4096
static constexpr size_t SCB_O = 136772;             // 64
static constexpr size_t CA_O  = 136836;             // 256: [src][b][c]
static constexpr size_t FLAG_O = 137092;            // int flag
static constexpr size_t XG_OFF = 137104;
static constexpr size_t GG_OFF = XG_OFF + BCN;
static constexpr size_t QX_OFF = GG_OFF + BCN;      // [b][n][c]
static constexpr size_t KX_OFF = QX_OFF + BCN;
static constexpr size_t VX_OFF = KX_OFF + BCN;
static constexpr size_t QG_OFF = VX_OFF + BCN;
static constexpr size_t KG_OFF = QG_OFF + BCN;
static constexpr size_t XO_OFF = XG_OFF;            // [b][c][n] (reuse XG)
static constexpr size_t GO_OFF = GG_OFF;            // (reuse GG)
static constexpr size_t OB_OFF = QX_OFF;            // (reuse QX)
static constexpr size_t UB_OFF = KX_OFF;            // (reuse KX)
// Total: 137104 + 7*524288 floats = 15.2 MB

// ---------------- K0: dtype detect + param conversion to fp32 ----------------
__global__ __launch_bounds__(256) void k_detect(
    const void* x, const void* lw, const void* lb, const void* cw,
    const void* xqw, const void* xqb, const void* xkw, const void* xkb,
    const void* xvw, const void* xvb, const void* gqw, const void* gqb,
    const void* gkw, const void* gkb, const void* gm, const void* al,
    const void* c1w, const void* c1b, const void* c2w, const void* c2b,
    const void* scw, const void* scb, float* ws) {
  __shared__ int sflag;
  int t = threadIdx.x;
  if (t == 0) {
    const unsigned short* u = (const unsigned short*)x;
    int cnt = 0;
    for (int i = 0; i < 256; ++i) {
      int e = (u[i * 2] >> 7) & 0xFF;
      if (e >= 117 && e <= 130) ++cnt;
    }
    sflag = (cnt > 128) ? 1 : 0;
    ((int*)ws)[FLAG_O] = sflag;
  }
  __syncthreads();
  int isbf = sflag;
  auto cv = [&](const void* p, size_t off, int n) {
    for (int i = t; i < n; i += 256) ws[off + i] = ldin(p, i, isbf);
  };
  cv(lw, LW_O, 1);      cv(lb, LB_O, 1);
  cv(gm, GM_O, 1);      cv(al, AL_O, 1);
  cv(cw, CW_O, 38016);
  cv(xqw, XQW_O, 4096); cv(xqb, XQB_O, 64);
  cv(xkw, XKW_O, 4096); cv(xkb, XKB_O, 64);
  cv(xvw, XVW_O, 4096); cv(xvb, XVB_O, 64);
  cv(gqw, GQW_O, 4096); cv(gqb, GQB_O, 64);
  cv(gkw, GKW_O, 4096); cv(gkb, GKB_O, 64);
  cv(c1w, C1W_O, 36864); cv(c1b, C1B_O, 64);
  cv(c2w, C2W_O, 36864); cv(c2b, C2B_O, 64);
  cv(scw, SCW_O, 4096);  cv(scb, SCB_O, 64);
}

// ---------------- K1: channel attention scalars ----------------
__global__ __launch_bounds__(256) void k_chattn(const void* __restrict__ x,
                                                const void* __restrict__ g,
                                                float* __restrict__ ws) {
  int isbf = ((const int*)ws)[FLAG_O];
  int blk = blockIdx.x;          // 0..255
  int src = blk >> 7;
  int rem = blk & 127;
  int b = rem >> 6, c = rem & 63;
  const void* base = src ? g : x;
  size_t off0 = ((size_t)(b * 64 + c)) * N_;
  float s = 0.f;
  for (int i = threadIdx.x; i < N_; i += 256) s += ldin(base, off0 + i, isbf);
  __shared__ float red[256];
  red[threadIdx.x] = s;
  __syncthreads();
  for (int off = 128; off; off >>= 1) {
    if (threadIdx.x < off) red[threadIdx.x] += red[threadIdx.x + off];
    __syncthreads();
  }
  if (threadIdx.x == 0) {
    float p = red[0] * (1.f / (float)N_);
    float lw = ws[LW_O], lb = ws[LB_O];
    float h = leaky(lw * p + lb);
    float z = lw * h + lb;
    ws[CA_O + src * 128 + b * 64 + c] = 1.f / (1.f + expf(-z));
  }
}

// ---------------- K2: coord-conv 3x3 (66 in-ch) * channel attn ----------------
__global__ __launch_bounds__(256) void k_coordconv(const void* __restrict__ x,
                                                   const void* __restrict__ g,
                                                   float* __restrict__ ws) {
  int isbf = ((const int*)ws)[FLAG_O];
  int blk = blockIdx.x;  // 2*2*64*16
  int rt = blk & 15; blk >>= 4;
  int o  = blk & 63; blk >>= 6;
  int b  = blk & 1;  blk >>= 1;
  int src = blk;
  const void* in = src ? g : x;
  float* outp = ws + (src ? GG_OFF : XG_OFF);
  __shared__ float wl[594];
  __shared__ float tile[384];  // 6 rows x 64 cols
  int t = threadIdx.x;
  for (int idx = t; idx < 594; idx += 256) wl[idx] = ws[CW_O + (size_t)o * 594 + idx];
  int row = t >> 6, col = t & 63;
  int h = rt * 4 + row;
  float acc = 0.f;
  for (int i = 0; i < 66; ++i) {
    __syncthreads();
    for (int idx = t; idx < 384; idx += 256) {
      int r = idx >> 6, cc = idx & 63;
      int hh = rt * 4 - 1 + r;
      float v = 0.f;
      if (hh >= 0 && hh < 64) {
        if (i < 64)       v = ldin(in, ((size_t)(b * 64 + i)) * N_ + hh * 64 + cc, isbf);
        else if (i == 64) v = (float)cc * (2.f / 63.f) - 1.f;   // xx: varies along width
        else              v = (float)hh * (2.f / 63.f) - 1.f;   // yy: varies along height
      }
      tile[idx] = v;
    }
    __syncthreads();
    const float* wli = &wl[i * 9];
#pragma unroll
    for (int ky = 0; ky < 3; ++ky) {
#pragma unroll
      for (int kx = 0; kx < 3; ++kx) {
        int wc = col + kx - 1;
        float v = (wc >= 0 && wc < 64) ? tile[(row + ky) * 64 + wc] : 0.f;
        acc = fmaf(wli[ky * 3 + kx], v, acc);
      }
    }
  }
  float cav = ws[CA_O + src * 128 + b * 64 + o];
  outp[((size_t)(b * 64 + o)) * N_ + h * 64 + col] = cav * acc;
}

// ---------------- K3: 1x1 conv projections (q/k/v/gq/gk), transposed out ----------------
__global__ __launch_bounds__(256) void k_proj(float* __restrict__ ws) {
  int blk = blockIdx.x;  // 5 * 2 * 64
  int pt = blk & 63; blk >>= 6;
  int b  = blk & 1;  blk >>= 1;
  int which = blk;  // 0..4
  size_t in_o, w_o, b_o, out_o;
  if (which == 0)      { in_o = XG_OFF; w_o = XQW_O; b_o = XQB_O; out_o = QX_OFF; }
  else if (which == 1) { in_o = XG_OFF; w_o = XKW_O; b_o = XKB_O; out_o = KX_OFF; }
  else if (which == 2) { in_o = XG_OFF; w_o = XVW_O; b_o = XVB_O; out_o = VX_OFF; }
  else if (which == 3) { in_o = GG_OFF; w_o = GQW_O; b_o = GQB_O; out_o = QG_OFF; }
  else                 { in_o = GG_OFF; w_o = GKW_O; b_o = GKB_O; out_o = KG_OFF; }

  __shared__ float tile[64 * 64];
  __shared__ float wl[64 * 65];
  __shared__ float bl[64];
  int t = threadIdx.x;
  int pb = pt * 64;
  const float* in0 = ws + in_o + (size_t)b * CN + pb;
  for (int c0 = (t >> 6); c0 < 64; c0 += 4)
    tile[c0 * 64 + (t & 63)] = in0[(size_t)c0 * N_ + (t & 63)];
  for (int idx = t; idx < 4096; idx += 256)
    wl[(idx >> 6) * 65 + (idx & 63)] = ws[w_o + idx];
  if (t < 64) bl[t] = ws[b_o + t];
  __syncthreads();
  int o = t & 63, grp = t >> 6;
  float* outp = ws + out_o;
  for (int j = 0; j < 16; ++j) {
    int pix = grp * 16 + j;
    float acc = bl[o];
    const float* wr = &wl[o * 65];
#pragma unroll
    for (int c = 0; c < 64; ++c) acc = fmaf(wr[c], tile[c * 64 + pix], acc);
    outp[((size_t)b * N_ + pb + pix) * 64 + o] = acc;
  }
}

// ---------------- K4: attention (softmax(q k^T) applied to v) ----------------
__global__ __launch_bounds__(256) void k_attn(float* __restrict__ ws) {
  int blk = blockIdx.x;  // 2 * 2 * 4096
  int n = blk & 4095; blk >>= 12;
  int b = blk & 1;    blk >>= 1;
  int at = blk;  // 0: x-attn, 1: guide-attn
  const float* q = ws + (at ? QG_OFF : QX_OFF) + ((size_t)b * N_ + n) * 64;
  const float* k = ws + (at ? KG_OFF : KX_OFF) + (size_t)b * N_ * 64;
  const float* v = ws + VX_OFF + (size_t)b * N_ * 64;  // both attns use x_value
  float* outp = ws + (at ? GO_OFF : XO_OFF) + (size_t)b * CN + n;

  __shared__ float qs[64];
  __shared__ float sc[4096];
  __shared__ float red[256];
  int t = threadIdx.x;
  if (t < 64) qs[t] = q[t];
  __syncthreads();
  float lmax = -1e30f;
  for (int i = 0; i < 16; ++i) {
    int m = i * 256 + t;
    const float* kr = k + (size_t)m * 64;
    float s = 0.f;
#pragma unroll
    for (int c = 0; c < 64; c += 4) {
      float4 kv = *reinterpret_cast<const float4*>(kr + c);
      s = fmaf(qs[c], kv.x, s);
      s = fmaf(qs[c + 1], kv.y, s);
      s = fmaf(qs[c + 2], kv.z, s);
      s = fmaf(qs[c + 3], kv.w, s);
    }
    sc[m] = s;
    lmax = fmaxf(lmax, s);
  }
  red[t] = lmax;
  __syncthreads();
  for (int off = 128; off; off >>= 1) {
    if (t < off) red[t] = fmaxf(red[t], red[t + off]);
    __syncthreads();
  }
  float mx = red[0];
  __syncthreads();
  float lsum = 0.f;
  for (int i = 0; i < 16; ++i) {
    int m = i * 256 + t;
    float p = expf(sc[m] - mx);
    sc[m] = p;
    lsum += p;
  }
  red[t] = lsum;
  __syncthreads();
  for (int off = 128; off; off >>= 1) {
    if (t < off) red[t] += red[t + off];
    __syncthreads();
  }
  float inv = 1.f / red[0];
  __syncthreads();
  int c = t & 63, grp = t >> 6;
  float acc = 0.f;
  const float* vb = v + (size_t)grp * 1024 * 64 + c;
  const float* sb = &sc[grp * 1024];
  for (int m = 0; m < 1024; ++m) acc = fmaf(sb[m], vb[(size_t)m * 64], acc);
  red[t] = acc;
  __syncthreads();
  if (t < 64) {
    float tot = red[t] + red[t + 64] + red[t + 128] + red[t + 192];
    outp[(size_t)t * N_] = tot * inv;
  }
}

// ---------------- K5: out = gamma*x_out + alpha*guide_out ----------------
__global__ __launch_bounds__(256) void k_combine(float* __restrict__ ws) {
  size_t i = (size_t)blockIdx.x * 256 + threadIdx.x;
  float gm = ws[GM_O], al = ws[AL_O];
  ws[OB_OFF + i] = gm * ws[XO_OFF + i] + al * ws[GO_OFF + i];
}

// ---------------- K6: u = leaky(conv3x3(leaky(out), c1)) ----------------
__global__ __launch_bounds__(256) void k_conv1(float* __restrict__ ws) {
  int blk = blockIdx.x;  // 2*64*16
  int rt = blk & 15; blk >>= 4;
  int o  = blk & 63; blk >>= 6;
  int b  = blk;
  __shared__ float wl[576];
  __shared__ float tile[384];
  int t = threadIdx.x;
  for (int idx = t; idx < 576; idx += 256) wl[idx] = ws[C1W_O + (size_t)o * 576 + idx];
  int row = t >> 6, col = t & 63;
  int h = rt * 4 + row;
  float acc = 0.f;
  const float* in0 = ws + OB_OFF + (size_t)b * CN;
  for (int i = 0; i < 64; ++i) {
    __syncthreads();
    for (int idx = t; idx < 384; idx += 256) {
      int r = idx >> 6, cc = idx & 63;
      int hh = rt * 4 - 1 + r;
      float v = 0.f;
      if (hh >= 0 && hh < 64) v = leaky(in0[(size_t)i * N_ + hh * 64 + cc]);
      tile[idx] = v;
    }
    __syncthreads();
    const float* wli = &wl[i * 9];
#pragma unroll
    for (int ky = 0; ky < 3; ++ky) {
#pragma unroll
      for (int kx = 0; kx < 3; ++kx) {
        int wc = col + kx - 1;
        float v = (wc >= 0 && wc < 64) ? tile[(row + ky) * 64 + wc] : 0.f;
        acc = fmaf(wli[ky * 3 + kx], v, acc);
      }
    }
  }
  acc = leaky(acc + ws[C1B_O + o]);
  ws[UB_OFF + (size_t)b * CN + (size_t)o * N_ + h * 64 + col] = acc;
}

// ---------------- K7: final = conv3x3(u,c2) + conv1x1(out,sc)*guide_out ----------------
// Output is fp32 (reference returns float32).
__global__ __launch_bounds__(256) void k_final(const float* __restrict__ ws,
                                               float* __restrict__ out) {
  int blk = blockIdx.x;  // 2*64*16
  int rt = blk & 15; blk >>= 4;
  int o  = blk & 63; blk >>= 6;
  int b  = blk;
  __shared__ float wl[576];
  __shared__ float scl[64];
  __shared__ float tile[384];
  int t = threadIdx.x;
  for (int idx = t; idx < 576; idx += 256) wl[idx] = ws[C2W_O + (size_t)o * 576 + idx];
  if (t < 64) scl[t] = ws[SCW_O + (size_t)o * 64 + t];
  int row = t >> 6, col = t & 63;
  int h = rt * 4 + row;
  int pix = h * 64 + col;
  float acc = 0.f, accsc = 0.f;
  const float* u0 = ws + UB_OFF + (size_t)b * CN;
  const float* ob0 = ws + OB_OFF + (size_t)b * CN;
  for (int i = 0; i < 64; ++i) {
    __syncthreads();
    for (int idx = t; idx < 384; idx += 256) {
      int r = idx >> 6, cc = idx & 63;
      int hh = rt * 4 - 1 + r;
      float v = 0.f;
      if (hh >= 0 && hh < 64) v = u0[(size_t)i * N_ + hh * 64 + cc];
      tile[idx] = v;
    }
    __syncthreads();
    const float* wli = &wl[i * 9];
#pragma unroll
    for (int ky = 0; ky < 3; ++ky) {
#pragma unroll
      for (int kx = 0; kx < 3; ++kx) {
        int wc = col + kx - 1;
        float v = (wc >= 0 && wc < 64) ? tile[(row + ky) * 64 + wc] : 0.f;
        acc = fmaf(wli[ky * 3 + kx], v, acc);
      }
    }
    accsc = fmaf(scl[i], ob0[(size_t)i * N_ + pix], accsc);
  }
  float branch = acc + ws[C2B_O + o];
  float scv = accsc + ws[SCB_O + o];
  float gv = ws[GO_OFF + (size_t)b * CN + (size_t)o * N_ + pix];
  out[(size_t)b * CN + (size_t)o * N_ + pix] = branch + scv * gv;
}

extern "C" void kernel_launch(void* const* d_in, const int* in_sizes, int n_in,
                              void* d_out, int out_size, void* d_ws, size_t ws_size,
                              hipStream_t stream) {
  const void* x      = d_in[0];
  const void* guide  = d_in[1];
  float* out = (float*)d_out;
  float* ws = (float*)d_ws;

  k_detect<<<1, 256, 0, stream>>>(d_in[0], d_in[2], d_in[3], d_in[4],
                                  d_in[5], d_in[6], d_in[7], d_in[8],
                                  d_in[9], d_in[10], d_in[11], d_in[12],
                                  d_in[13], d_in[14], d_in[15], d_in[16],
                                  d_in[17], d_in[18], d_in[19], d_in[20],
                                  d_in[21], d_in[22], ws);
  k_chattn<<<256, 256, 0, stream>>>(x, guide, ws);
  k_coordconv<<<4096, 256, 0, stream>>>(x, guide, ws);
  k_proj<<<640, 256, 0, stream>>>(ws);
  k_attn<<<16384, 256, 0, stream>>>(ws);
  k_combine<<<2048, 256, 0, stream>>>(ws);
  k_conv1<<<2048, 256, 0, stream>>>(ws);
  k_final<<<2048, 256, 0, stream>>>(ws, out);
}

// Round 5
// 1070.159 us; speedup vs baseline: 2.9003x; 2.9003x over previous
//
#include <hip/hip_runtime.h>
#include <hip/hip_bf16.h>

using bf16 = __hip_bfloat16;

#define DI __device__ __forceinline__

DI float b2f(bf16 v) { return __bfloat162float(v); }
DI float leaky(float x) { return x > 0.f ? x : 0.1f * x; }

// Flag-dispatched input load: inputs may be fp32 (per reference) or bf16.
// Decided at runtime by k_detect. (R3 evidence: fp32.)
DI float ldin(const void* p, size_t i, int isbf) {
  return isbf ? b2f(((const bf16*)p)[i]) : ((const float*)p)[i];
}

// Problem constants: B=2, C=64, H=64, W=64, N=4096
static constexpr int N_ = 4096;
static constexpr size_t CN = 262144;   // C*N per batch
static constexpr size_t BCN = 524288;  // B*C*N

// ---- Workspace layout (float indices) ----
static constexpr size_t LW_O = 0, LB_O = 1, GM_O = 2, AL_O = 3;
static constexpr size_t CW_O  = 4;                  // 38016
static constexpr size_t XQW_O = 38020;              // 4096
static constexpr size_t XQB_O = 42116;              // 64
static constexpr size_t XKW_O = 42180;
static constexpr size_t XKB_O = 46276;
static constexpr size_t XVW_O = 46340;
static constexpr size_t XVB_O = 50436;
static constexpr size_t GQW_O = 50500;
static constexpr size_t GQB_O = 54596;
static constexpr size_t GKW_O = 54660;
static constexpr size_t GKB_O = 58756;
static constexpr size_t C1W_O = 58820;              // 36864
static constexpr size_t C1B_O = 95684;
static constexpr size_t C2W_O = 95748;              // 36864
static constexpr size_t C2B_O = 132612;
static constexpr size_t SCW_O = 132676;             // 4096
static constexpr size_t SCB_O = 136772;             // 64
static constexpr size_t CA_O  = 136836;             // 256: [src][b][c]
static constexpr size_t FLAG_O = 137092;            // int flag
static constexpr size_t XG_OFF = 137104;
static constexpr size_t GG_OFF = XG_OFF + BCN;
static constexpr size_t QX_OFF = GG_OFF + BCN;      // [b][n][c]
static constexpr size_t KX_OFF = QX_OFF + BCN;
static constexpr size_t VX_OFF = KX_OFF + BCN;
static constexpr size_t QG_OFF = VX_OFF + BCN;
static constexpr size_t KG_OFF = QG_OFF + BCN;
static constexpr size_t XO_OFF = XG_OFF;            // [b][c][n] (reuse XG)
static constexpr size_t GO_OFF = GG_OFF;            // (reuse GG)
static constexpr size_t OB_OFF = QX_OFF;            // (reuse QX)
static constexpr size_t UB_OFF = KX_OFF;            // (reuse KX)
// Total: 137104 + 7*524288 floats = 15.2 MB

// ---------------- K0: dtype detect + param conversion to fp32 ----------------
__global__ __launch_bounds__(256) void k_detect(
    const void* x, const void* lw, const void* lb, const void* cw,
    const void* xqw, const void* xqb, const void* xkw, const void* xkb,
    const void* xvw, const void* xvb, const void* gqw, const void* gqb,
    const void* gkw, const void* gkb, const void* gm, const void* al,
    const void* c1w, const void* c1b, const void* c2w, const void* c2b,
    const void* scw, const void* scb, float* ws) {
  __shared__ int sflag;
  int t = threadIdx.x;
  if (t == 0) {
    const unsigned short* u = (const unsigned short*)x;
    int cnt = 0;
    for (int i = 0; i < 256; ++i) {
      int e = (u[i * 2] >> 7) & 0xFF;
      if (e >= 117 && e <= 130) ++cnt;
    }
    sflag = (cnt > 128) ? 1 : 0;
    ((int*)ws)[FLAG_O] = sflag;
  }
  __syncthreads();
  int isbf = sflag;
  auto cv = [&](const void* p, size_t off, int n) {
    for (int i = t; i < n; i += 256) ws[off + i] = ldin(p, i, isbf);
  };
  cv(lw, LW_O, 1);      cv(lb, LB_O, 1);
  cv(gm, GM_O, 1);      cv(al, AL_O, 1);
  cv(cw, CW_O, 38016);
  cv(xqw, XQW_O, 4096); cv(xqb, XQB_O, 64);
  cv(xkw, XKW_O, 4096); cv(xkb, XKB_O, 64);
  cv(xvw, XVW_O, 4096); cv(xvb, XVB_O, 64);
  cv(gqw, GQW_O, 4096); cv(gqb, GQB_O, 64);
  cv(gkw, GKW_O, 4096); cv(gkb, GKB_O, 64);
  cv(c1w, C1W_O, 36864); cv(c1b, C1B_O, 64);
  cv(c2w, C2W_O, 36864); cv(c2b, C2B_O, 64);
  cv(scw, SCW_O, 4096);  cv(scb, SCB_O, 64);
}

// ---------------- K1: channel attention scalars ----------------
__global__ __launch_bounds__(256) void k_chattn(const void* __restrict__ x,
                                                const void* __restrict__ g,
                                                float* __restrict__ ws) {
  int isbf = ((const int*)ws)[FLAG_O];
  int blk = blockIdx.x;          // 0..255
  int src = blk >> 7;
  int rem = blk & 127;
  int b = rem >> 6, c = rem & 63;
  const void* base = src ? g : x;
  size_t off0 = ((size_t)(b * 64 + c)) * N_;
  float s = 0.f;
  for (int i = threadIdx.x; i < N_; i += 256) s += ldin(base, off0 + i, isbf);
  __shared__ float red[256];
  red[threadIdx.x] = s;
  __syncthreads();
  for (int off = 128; off; off >>= 1) {
    if (threadIdx.x < off) red[threadIdx.x] += red[threadIdx.x + off];
    __syncthreads();
  }
  if (threadIdx.x == 0) {
    float p = red[0] * (1.f / (float)N_);
    float lw = ws[LW_O], lb = ws[LB_O];
    float h = leaky(lw * p + lb);
    float z = lw * h + lb;
    ws[CA_O + src * 128 + b * 64 + c] = 1.f / (1.f + expf(-z));
  }
}

// ---------------- K2: coord-conv 3x3 (66 in-ch) * channel attn ----------------
__global__ __launch_bounds__(256) void k_coordconv(const void* __restrict__ x,
                                                   const void* __restrict__ g,
                                                   float* __restrict__ ws) {
  int isbf = ((const int*)ws)[FLAG_O];
  int blk = blockIdx.x;  // 2*2*64*16
  int rt = blk & 15; blk >>= 4;
  int o  = blk & 63; blk >>= 6;
  int b  = blk & 1;  blk >>= 1;
  int src = blk;
  const void* in = src ? g : x;
  float* outp = ws + (src ? GG_OFF : XG_OFF);
  __shared__ float wl[594];
  __shared__ float tile[384];  // 6 rows x 64 cols
  int t = threadIdx.x;
  for (int idx = t; idx < 594; idx += 256) wl[idx] = ws[CW_O + (size_t)o * 594 + idx];
  int row = t >> 6, col = t & 63;
  int h = rt * 4 + row;
  float acc = 0.f;
  for (int i = 0; i < 66; ++i) {
    __syncthreads();
    for (int idx = t; idx < 384; idx += 256) {
      int r = idx >> 6, cc = idx & 63;
      int hh = rt * 4 - 1 + r;
      float v = 0.f;
      if (hh >= 0 && hh < 64) {
        if (i < 64)       v = ldin(in, ((size_t)(b * 64 + i)) * N_ + hh * 64 + cc, isbf);
        else if (i == 64) v = (float)cc * (2.f / 63.f) - 1.f;   // xx: varies along width
        else              v = (float)hh * (2.f / 63.f) - 1.f;   // yy: varies along height
      }
      tile[idx] = v;
    }
    __syncthreads();
    const float* wli = &wl[i * 9];
#pragma unroll
    for (int ky = 0; ky < 3; ++ky) {
#pragma unroll
      for (int kx = 0; kx < 3; ++kx) {
        int wc = col + kx - 1;
        float v = (wc >= 0 && wc < 64) ? tile[(row + ky) * 64 + wc] : 0.f;
        acc = fmaf(wli[ky * 3 + kx], v, acc);
      }
    }
  }
  float cav = ws[CA_O + src * 128 + b * 64 + o];
  outp[((size_t)(b * 64 + o)) * N_ + h * 64 + col] = cav * acc;
}

// ---------------- K3: 1x1 conv projections (q/k/v/gq/gk), transposed out ----------------
__global__ __launch_bounds__(256) void k_proj(float* __restrict__ ws) {
  int blk = blockIdx.x;  // 5 * 2 * 64
  int pt = blk & 63; blk >>= 6;
  int b  = blk & 1;  blk >>= 1;
  int which = blk;  // 0..4
  size_t in_o, w_o, b_o, out_o;
  if (which == 0)      { in_o = XG_OFF; w_o = XQW_O; b_o = XQB_O; out_o = QX_OFF; }
  else if (which == 1) { in_o = XG_OFF; w_o = XKW_O; b_o = XKB_O; out_o = KX_OFF; }
  else if (which == 2) { in_o = XG_OFF; w_o = XVW_O; b_o = XVB_O; out_o = VX_OFF; }
  else if (which == 3) { in_o = GG_OFF; w_o = GQW_O; b_o = GQB_O; out_o = QG_OFF; }
  else                 { in_o = GG_OFF; w_o = GKW_O; b_o = GKB_O; out_o = KG_OFF; }

  __shared__ float tile[64 * 64];
  __shared__ float wl[64 * 65];
  __shared__ float bl[64];
  int t = threadIdx.x;
  int pb = pt * 64;
  const float* in0 = ws + in_o + (size_t)b * CN + pb;
  for (int c0 = (t >> 6); c0 < 64; c0 += 4)
    tile[c0 * 64 + (t & 63)] = in0[(size_t)c0 * N_ + (t & 63)];
  for (int idx = t; idx < 4096; idx += 256)
    wl[(idx >> 6) * 65 + (idx & 63)] = ws[w_o + idx];
  if (t < 64) bl[t] = ws[b_o + t];
  __syncthreads();
  int o = t & 63, grp = t >> 6;
  float* outp = ws + out_o;
  for (int j = 0; j < 16; ++j) {
    int pix = grp * 16 + j;
    float acc = bl[o];
    const float* wr = &wl[o * 65];
#pragma unroll
    for (int c = 0; c < 64; ++c) acc = fmaf(wr[c], tile[c * 64 + pix], acc);
    outp[((size_t)b * N_ + pb + pix) * 64 + o] = acc;
  }
}

// ---------------- K4: flash-style attention ----------------
// One block per (at, b, 64-row Q tile). S = Q K^T with online softmax, O += P V.
// Thread (ty,tx): S patch rows n=ty*4+i, cols m=16*j+tx (conflict-free K reads);
//                 O patch rows n=ty*4+i, cols c=tx*4+j  (b128 V reads).
__global__ __launch_bounds__(256) void k_attn(float* __restrict__ ws) {
  int blk = blockIdx.x;  // 256: at*128 + b*64 + nt
  int nt = blk & 63; blk >>= 6;
  int b  = blk & 1;  blk >>= 1;
  int at = blk;
  const float* Qg = ws + (at ? QG_OFF : QX_OFF) + ((size_t)b * N_ + nt * 64) * 64;
  const float* Kg = ws + (at ? KG_OFF : KX_OFF) + (size_t)b * N_ * 64;
  const float* Vg = ws + VX_OFF + (size_t)b * N_ * 64;  // both attns use x_value
  float* Og = ws + (at ? GO_OFF : XO_OFF) + (size_t)b * CN + nt * 64;

  constexpr int RS = 68;  // LDS row stride (floats), 16B-aligned rows
  __shared__ float Qs[64 * RS];
  __shared__ float Ks[64 * RS];
  __shared__ float Vs[64 * RS];
  __shared__ float Ps[64 * RS];

  int t = threadIdx.x;
  int ty = t >> 4, tx = t & 15;

  // stage Q tile (contiguous 16 KB)
#pragma unroll
  for (int it = 0; it < 4; ++it) {
    int f = (it * 256 + t) * 4;
    int r = f >> 6, c = f & 63;
    *reinterpret_cast<float4*>(&Qs[r * RS + c]) = *reinterpret_cast<const float4*>(Qg + f);
  }

  float O[4][4] = {};
  float M[4], L[4];
#pragma unroll
  for (int i = 0; i < 4; ++i) { M[i] = -1e30f; L[i] = 0.f; }

  for (int mt = 0; mt < 64; ++mt) {
    __syncthreads();  // previous iter's readers of Ks/Vs/Ps done
    const float* Kt = Kg + (size_t)mt * 4096;
    const float* Vt = Vg + (size_t)mt * 4096;
#pragma unroll
    for (int it = 0; it < 4; ++it) {
      int f = (it * 256 + t) * 4;
      int r = f >> 6, c = f & 63;
      *reinterpret_cast<float4*>(&Ks[r * RS + c]) = *reinterpret_cast<const float4*>(Kt + f);
      *reinterpret_cast<float4*>(&Vs[r * RS + c]) = *reinterpret_cast<const float4*>(Vt + f);
    }
    __syncthreads();

    // ---- S = Q K^T (4x4 patch, cols m=16j+tx) ----
    float s[4][4] = {};
    for (int c0 = 0; c0 < 64; c0 += 4) {
      float4 qv[4], kv[4];
#pragma unroll
      for (int i = 0; i < 4; ++i)
        qv[i] = *reinterpret_cast<const float4*>(&Qs[(ty * 4 + i) * RS + c0]);
#pragma unroll
      for (int j = 0; j < 4; ++j)
        kv[j] = *reinterpret_cast<const float4*>(&Ks[(16 * j + tx) * RS + c0]);
#pragma unroll
      for (int i = 0; i < 4; ++i)
#pragma unroll
        for (int j = 0; j < 4; ++j) {
          s[i][j] = fmaf(qv[i].x, kv[j].x, s[i][j]);
          s[i][j] = fmaf(qv[i].y, kv[j].y, s[i][j]);
          s[i][j] = fmaf(qv[i].z, kv[j].z, s[i][j]);
          s[i][j] = fmaf(qv[i].w, kv[j].w, s[i][j]);
        }
    }

    // ---- online softmax per row ----
#pragma unroll
    for (int i = 0; i < 4; ++i) {
      float tm = fmaxf(fmaxf(s[i][0], s[i][1]), fmaxf(s[i][2], s[i][3]));
#pragma unroll
      for (int d = 1; d < 16; d <<= 1) tm = fmaxf(tm, __shfl_xor(tm, d, 16));
      float mn = fmaxf(M[i], tm);
      float sc = __expf(M[i] - mn);
      float ts = 0.f;
#pragma unroll
      for (int j = 0; j < 4; ++j) { s[i][j] = __expf(s[i][j] - mn); ts += s[i][j]; }
#pragma unroll
      for (int d = 1; d < 16; d <<= 1) ts += __shfl_xor(ts, d, 16);
      L[i] = L[i] * sc + ts;
      M[i] = mn;
#pragma unroll
      for (int j = 0; j < 4; ++j) O[i][j] *= sc;
      int rp = (ty * 4 + i) * RS;
#pragma unroll
      for (int j = 0; j < 4; ++j) Ps[rp + 16 * j + tx] = s[i][j];
    }
    __syncthreads();

    // ---- O += P * V (cols c=tx*4+j) ----
    for (int m0 = 0; m0 < 64; m0 += 4) {
      float4 pv[4];
#pragma unroll
      for (int i = 0; i < 4; ++i)
        pv[i] = *reinterpret_cast<const float4*>(&Ps[(ty * 4 + i) * RS + m0]);
#pragma unroll
      for (int kk = 0; kk < 4; ++kk) {
        float4 vr = *reinterpret_cast<const float4*>(&Vs[(m0 + kk) * RS + tx * 4]);
#pragma unroll
        for (int i = 0; i < 4; ++i) {
          float p = (kk == 0) ? pv[i].x : (kk == 1) ? pv[i].y : (kk == 2) ? pv[i].z : pv[i].w;
          O[i][0] = fmaf(p, vr.x, O[i][0]);
          O[i][1] = fmaf(p, vr.y, O[i][1]);
          O[i][2] = fmaf(p, vr.z, O[i][2]);
          O[i][3] = fmaf(p, vr.w, O[i][3]);
        }
      }
    }
  }

  // epilogue: normalize, write transposed [c][n] (n contiguous per store)
  float inv[4];
#pragma unroll
  for (int i = 0; i < 4; ++i) inv[i] = 1.f / L[i];
#pragma unroll
  for (int j = 0; j < 4; ++j) {
    float4 o = make_float4(O[0][j] * inv[0], O[1][j] * inv[1],
                           O[2][j] * inv[2], O[3][j] * inv[3]);
    *reinterpret_cast<float4*>(Og + (size_t)(tx * 4 + j) * N_ + ty * 4) = o;
  }
}

// ---------------- K5: out = gamma*x_out + alpha*guide_out ----------------
__global__ __launch_bounds__(256) void k_combine(float* __restrict__ ws) {
  size_t i = (size_t)blockIdx.x * 256 + threadIdx.x;
  float gm = ws[GM_O], al = ws[AL_O];
  ws[OB_OFF + i] = gm * ws[XO_OFF + i] + al * ws[GO_OFF + i];
}

// ---------------- K6: u = leaky(conv3x3(leaky(out), c1)) ----------------
__global__ __launch_bounds__(256) void k_conv1(float* __restrict__ ws) {
  int blk = blockIdx.x;  // 2*64*16
  int rt = blk & 15; blk >>= 4;
  int o  = blk & 63; blk >>= 6;
  int b  = blk;
  __shared__ float wl[576];
  __shared__ float tile[384];
  int t = threadIdx.x;
  for (int idx = t; idx < 576; idx += 256) wl[idx] = ws[C1W_O + (size_t)o * 576 + idx];
  int row = t >> 6, col = t & 63;
  int h = rt * 4 + row;
  float acc = 0.f;
  const float* in0 = ws + OB_OFF + (size_t)b * CN;
  for (int i = 0; i < 64; ++i) {
    __syncthreads();
    for (int idx = t; idx < 384; idx += 256) {
      int r = idx >> 6, cc = idx & 63;
      int hh = rt * 4 - 1 + r;
      float v = 0.f;
      if (hh >= 0 && hh < 64) v = leaky(in0[(size_t)i * N_ + hh * 64 + cc]);
      tile[idx] = v;
    }
    __syncthreads();
    const float* wli = &wl[i * 9];
#pragma unroll
    for (int ky = 0; ky < 3; ++ky) {
#pragma unroll
      for (int kx = 0; kx < 3; ++kx) {
        int wc = col + kx - 1;
        float v = (wc >= 0 && wc < 64) ? tile[(row + ky) * 64 + wc] : 0.f;
        acc = fmaf(wli[ky * 3 + kx], v, acc);
      }
    }
  }
  acc = leaky(acc + ws[C1B_O + o]);
  ws[UB_OFF + (size_t)b * CN + (size_t)o * N_ + h * 64 + col] = acc;
}

// ---------------- K7: final = conv3x3(u,c2) + conv1x1(out,sc)*guide_out ----------------
__global__ __launch_bounds__(256) void k_final(const float* __restrict__ ws,
                                               float* __restrict__ out) {
  int blk = blockIdx.x;  // 2*64*16
  int rt = blk & 15; blk >>= 4;
  int o  = blk & 63; blk >>= 6;
  int b  = blk;
  __shared__ float wl[576];
  __shared__ float scl[64];
  __shared__ float tile[384];
  int t = threadIdx.x;
  for (int idx = t; idx < 576; idx += 256) wl[idx] = ws[C2W_O + (size_t)o * 576 + idx];
  if (t < 64) scl[t] = ws[SCW_O + (size_t)o * 64 + t];
  int row = t >> 6, col = t & 63;
  int h = rt * 4 + row;
  int pix = h * 64 + col;
  float acc = 0.f, accsc = 0.f;
  const float* u0 = ws + UB_OFF + (size_t)b * CN;
  const float* ob0 = ws + OB_OFF + (size_t)b * CN;
  for (int i = 0; i < 64; ++i) {
    __syncthreads();
    for (int idx = t; idx < 384; idx += 256) {
      int r = idx >> 6, cc = idx & 63;
      int hh = rt * 4 - 1 + r;
      float v = 0.f;
      if (hh >= 0 && hh < 64) v = u0[(size_t)i * N_ + hh * 64 + cc];
      tile[idx] = v;
    }
    __syncthreads();
    const float* wli = &wl[i * 9];
#pragma unroll
    for (int ky = 0; ky < 3; ++ky) {
#pragma unroll
      for (int kx = 0; kx < 3; ++kx) {
        int wc = col + kx - 1;
        float v = (wc >= 0 && wc < 64) ? tile[(row + ky) * 64 + wc] : 0.f;
        acc = fmaf(wli[ky * 3 + kx], v, acc);
      }
    }
    accsc = fmaf(scl[i], ob0[(size_t)i * N_ + pix], accsc);
  }
  float branch = acc + ws[C2B_O + o];
  float scv = accsc + ws[SCB_O + o];
  float gv = ws[GO_OFF + (size_t)b * CN + (size_t)o * N_ + pix];
  out[(size_t)b * CN + (size_t)o * N_ + pix] = branch + scv * gv;
}

extern "C" void kernel_launch(void* const* d_in, const int* in_sizes, int n_in,
                              void* d_out, int out_size, void* d_ws, size_t ws_size,
                              hipStream_t stream) {
  const void* x      = d_in[0];
  const void* guide  = d_in[1];
  float* out = (float*)d_out;
  float* ws = (float*)d_ws;

  k_detect<<<1, 256, 0, stream>>>(d_in[0], d_in[2], d_in[3], d_in[4],
                                  d_in[5], d_in[6], d_in[7], d_in[8],
                                  d_in[9], d_in[10], d_in[11], d_in[12],
                                  d_in[13], d_in[14], d_in[15], d_in[16],
                                  d_in[17], d_in[18], d_in[19], d_in[20],
                                  d_in[21], d_in[22], ws);
  k_chattn<<<256, 256, 0, stream>>>(x, guide, ws);
  k_coordconv<<<4096, 256, 0, stream>>>(x, guide, ws);
  k_proj<<<640, 256, 0, stream>>>(ws);
  k_attn<<<256, 256, 0, stream>>>(ws);
  k_combine<<<2048, 256, 0, stream>>>(ws);
  k_conv1<<<2048, 256, 0, stream>>>(ws);
  k_final<<<2048, 256, 0, stream>>>(ws, out);
}

// Round 6
// 731.584 us; speedup vs baseline: 4.2426x; 1.4628x over previous
//
#include <hip/hip_runtime.h>
#include <hip/hip_bf16.h>

using bf16 = __hip_bfloat16;

#define DI __device__ __forceinline__

DI float b2f(bf16 v) { return __bfloat162float(v); }
DI float leaky(float x) { return x > 0.f ? x : 0.1f * x; }

// Flag-dispatched input load: inputs may be fp32 (per reference) or bf16.
// Decided at runtime by k_detect. (R3 evidence: fp32.)
DI float ldin(const void* p, size_t i, int isbf) {
  return isbf ? b2f(((const bf16*)p)[i]) : ((const float*)p)[i];
}

// Problem constants: B=2, C=64, H=64, W=64, N=4096
static constexpr int N_ = 4096;
static constexpr size_t CN = 262144;   // C*N per batch
static constexpr size_t BCN = 524288;  // B*C*N

// ---- Workspace layout (float indices) ----
static constexpr size_t LW_O = 0, LB_O = 1, GM_O = 2, AL_O = 3;
static constexpr size_t CW_O  = 4;                  // 38016
static constexpr size_t XQW_O = 38020;              // 4096
static constexpr size_t XQB_O = 42116;              // 64
static constexpr size_t XKW_O = 42180;
static constexpr size_t XKB_O = 46276;
static constexpr size_t XVW_O = 46340;
static constexpr size_t XVB_O = 50436;
static constexpr size_t GQW_O = 50500;
static constexpr size_t GQB_O = 54596;
static constexpr size_t GKW_O = 54660;
static constexpr size_t GKB_O = 58756;
static constexpr size_t C1W_O = 58820;              // 36864
static constexpr size_t C1B_O = 95684;
static constexpr size_t C2W_O = 95748;              // 36864
static constexpr size_t C2B_O = 132612;
static constexpr size_t SCW_O = 132676;             // 4096
static constexpr size_t SCB_O = 136772;             // 64 (params end 136836)
static constexpr size_t CA_O  = 136836;             // 256: [src][b][c]
static constexpr size_t FLAG_O = 137092;            // int flag
static constexpr size_t XG_OFF = 137104;            // gated x; then x-attn half0 partial
static constexpr size_t GG_OFF = XG_OFF + BCN;      // gated g; then g-attn half0 partial; then GO
static constexpr size_t QX_OFF = GG_OFF + BCN;      // [b][n][c]; then OB
static constexpr size_t KX_OFF = QX_OFF + BCN;      // then UB
static constexpr size_t VX_OFF = KX_OFF + BCN;
static constexpr size_t QG_OFF = VX_OFF + BCN;
static constexpr size_t KG_OFF = QG_OFF + BCN;
static constexpr size_t P1X_OFF = KG_OFF + BCN;     // x-attn half1 partial [b][c][n]
static constexpr size_t P1G_OFF = P1X_OFF + BCN;    // g-attn half1 partial
static constexpr size_t ML_OFF  = P1G_OFF + BCN;    // M[at][half][b][n]  (8*4096)
static constexpr size_t MLL_OFF = ML_OFF + 32768;   // L[at][half][b][n]
static constexpr size_t XO_OFF = XG_OFF;            // (doc aliases)
static constexpr size_t GO_OFF = GG_OFF;
static constexpr size_t OB_OFF = QX_OFF;
static constexpr size_t UB_OFF = KX_OFF;
// Peak: MLL_OFF + 32768 = 137104 + 9*BCN + 65536 floats = 19.7 MB

// ---------------- K0: dtype detect + param conversion to fp32 (parallel) ----------------
__global__ __launch_bounds__(256) void k_detect(
    const void* x, const void* lw, const void* lb, const void* cw,
    const void* xqw, const void* xqb, const void* xkw, const void* xkb,
    const void* xvw, const void* xvb, const void* gqw, const void* gqb,
    const void* gkw, const void* gkb, const void* gm, const void* al,
    const void* c1w, const void* c1b, const void* c2w, const void* c2b,
    const void* scw, const void* scb, float* ws) {
  __shared__ int sred[256];
  int t = threadIdx.x;
  // every block derives the same flag locally (deterministic, no cross-block dep)
  const unsigned short* u = (const unsigned short*)x;
  int e = (u[t * 2] >> 7) & 0xFF;
  sred[t] = (e >= 117 && e <= 130) ? 1 : 0;
  __syncthreads();
  for (int off = 128; off; off >>= 1) {
    if (t < off) sred[t] += sred[t + off];
    __syncthreads();
  }
  int isbf = sred[0] > 128 ? 1 : 0;
  if (blockIdx.x == 0 && t == 0) ((int*)ws)[FLAG_O] = isbf;
  int gid = blockIdx.x * 256 + t;
  int stride = gridDim.x * 256;
  for (int i = gid; i < 136836; i += stride) {
    const void* p; int rel;
    if (i < 4)               { p = (i == 0 ? lw : i == 1 ? lb : i == 2 ? gm : al); rel = 0; }
    else if (i < (int)XQW_O) { p = cw;  rel = i - (int)CW_O; }
    else if (i < (int)XQB_O) { p = xqw; rel = i - (int)XQW_O; }
    else if (i < (int)XKW_O) { p = xqb; rel = i - (int)XQB_O; }
    else if (i < (int)XKB_O) { p = xkw; rel = i - (int)XKW_O; }
    else if (i < (int)XVW_O) { p = xkb; rel = i - (int)XKB_O; }
    else if (i < (int)XVB_O) { p = xvw; rel = i - (int)XVW_O; }
    else if (i < (int)GQW_O) { p = xvb; rel = i - (int)XVB_O; }
    else if (i < (int)GQB_O) { p = gqw; rel = i - (int)GQW_O; }
    else if (i < (int)GKW_O) { p = gqb; rel = i - (int)GQB_O; }
    else if (i < (int)GKB_O) { p = gkw; rel = i - (int)GKW_O; }
    else if (i < (int)C1W_O) { p = gkb; rel = i - (int)GKB_O; }
    else if (i < (int)C1B_O) { p = c1w; rel = i - (int)C1W_O; }
    else if (i < (int)C2W_O) { p = c1b; rel = i - (int)C1B_O; }
    else if (i < (int)C2B_O) { p = c2w; rel = i - (int)C2W_O; }
    else if (i < (int)SCW_O) { p = c2b; rel = i - (int)C2B_O; }
    else if (i < (int)SCB_O) { p = scw; rel = i - (int)SCW_O; }
    else                     { p = scb; rel = i - (int)SCB_O; }
    ws[i] = ldin(p, rel, isbf);
  }
}

// ---------------- K1: channel attention scalars ----------------
__global__ __launch_bounds__(256) void k_chattn(const void* __restrict__ x,
                                                const void* __restrict__ g,
                                                float* __restrict__ ws) {
  int isbf = ((const int*)ws)[FLAG_O];
  int blk = blockIdx.x;          // 0..255
  int src = blk >> 7;
  int rem = blk & 127;
  int b = rem >> 6, c = rem & 63;
  const void* base = src ? g : x;
  size_t off0 = ((size_t)(b * 64 + c)) * N_;
  float s = 0.f;
  for (int i = threadIdx.x; i < N_; i += 256) s += ldin(base, off0 + i, isbf);
  __shared__ float red[256];
  red[threadIdx.x] = s;
  __syncthreads();
  for (int off = 128; off; off >>= 1) {
    if (threadIdx.x < off) red[threadIdx.x] += red[threadIdx.x + off];
    __syncthreads();
  }
  if (threadIdx.x == 0) {
    float p = red[0] * (1.f / (float)N_);
    float lw = ws[LW_O], lb = ws[LB_O];
    float h = leaky(lw * p + lb);
    float z = lw * h + lb;
    ws[CA_O + src * 128 + b * 64 + c] = 1.f / (1.f + expf(-z));
  }
}

// ---------------- K2: coord-conv 3x3 (66 in-ch) * channel attn ----------------
__global__ __launch_bounds__(256) void k_coordconv(const void* __restrict__ x,
                                                   const void* __restrict__ g,
                                                   float* __restrict__ ws) {
  int isbf = ((const int*)ws)[FLAG_O];
  int blk = blockIdx.x;  // 2*2*64*16
  int rt = blk & 15; blk >>= 4;
  int o  = blk & 63; blk >>= 6;
  int b  = blk & 1;  blk >>= 1;
  int src = blk;
  const void* in = src ? g : x;
  float* outp = ws + (src ? GG_OFF : XG_OFF);
  __shared__ float wl[594];
  __shared__ float tile[384];  // 6 rows x 64 cols
  int t = threadIdx.x;
  for (int idx = t; idx < 594; idx += 256) wl[idx] = ws[CW_O + (size_t)o * 594 + idx];
  int row = t >> 6, col = t & 63;
  int h = rt * 4 + row;
  float acc = 0.f;
  for (int i = 0; i < 66; ++i) {
    __syncthreads();
    for (int idx = t; idx < 384; idx += 256) {
      int r = idx >> 6, cc = idx & 63;
      int hh = rt * 4 - 1 + r;
      float v = 0.f;
      if (hh >= 0 && hh < 64) {
        if (i < 64)       v = ldin(in, ((size_t)(b * 64 + i)) * N_ + hh * 64 + cc, isbf);
        else if (i == 64) v = (float)cc * (2.f / 63.f) - 1.f;   // xx: varies along width
        else              v = (float)hh * (2.f / 63.f) - 1.f;   // yy: varies along height
      }
      tile[idx] = v;
    }
    __syncthreads();
    const float* wli = &wl[i * 9];
#pragma unroll
    for (int ky = 0; ky < 3; ++ky) {
#pragma unroll
      for (int kx = 0; kx < 3; ++kx) {
        int wc = col + kx - 1;
        float v = (wc >= 0 && wc < 64) ? tile[(row + ky) * 64 + wc] : 0.f;
        acc = fmaf(wli[ky * 3 + kx], v, acc);
      }
    }
  }
  float cav = ws[CA_O + src * 128 + b * 64 + o];
  outp[((size_t)(b * 64 + o)) * N_ + h * 64 + col] = cav * acc;
}

// ---------------- K3: 1x1 conv projections (q/k/v/gq/gk), transposed out ----------------
__global__ __launch_bounds__(256) void k_proj(float* __restrict__ ws) {
  int blk = blockIdx.x;  // 5 * 2 * 64
  int pt = blk & 63; blk >>= 6;
  int b  = blk & 1;  blk >>= 1;
  int which = blk;  // 0..4
  size_t in_o, w_o, b_o, out_o;
  if (which == 0)      { in_o = XG_OFF; w_o = XQW_O; b_o = XQB_O; out_o = QX_OFF; }
  else if (which == 1) { in_o = XG_OFF; w_o = XKW_O; b_o = XKB_O; out_o = KX_OFF; }
  else if (which == 2) { in_o = XG_OFF; w_o = XVW_O; b_o = XVB_O; out_o = VX_OFF; }
  else if (which == 3) { in_o = GG_OFF; w_o = GQW_O; b_o = GQB_O; out_o = QG_OFF; }
  else                 { in_o = GG_OFF; w_o = GKW_O; b_o = GKB_O; out_o = KG_OFF; }

  __shared__ float tile[64 * 64];
  __shared__ float wl[64 * 65];
  __shared__ float bl[64];
  int t = threadIdx.x;
  int pb = pt * 64;
  const float* in0 = ws + in_o + (size_t)b * CN + pb;
  for (int c0 = (t >> 6); c0 < 64; c0 += 4)
    tile[c0 * 64 + (t & 63)] = in0[(size_t)c0 * N_ + (t & 63)];
  for (int idx = t; idx < 4096; idx += 256)
    wl[(idx >> 6) * 65 + (idx & 63)] = ws[w_o + idx];
  if (t < 64) bl[t] = ws[b_o + t];
  __syncthreads();
  int o = t & 63, grp = t >> 6;
  float* outp = ws + out_o;
  for (int j = 0; j < 16; ++j) {
    int pix = grp * 16 + j;
    float acc = bl[o];
    const float* wr = &wl[o * 65];
#pragma unroll
    for (int c = 0; c < 64; ++c) acc = fmaf(wr[c], tile[c * 64 + pix], acc);
    outp[((size_t)b * N_ + pb + pix) * 64 + o] = acc;
  }
}

// ---------------- K4: flash attention, m-split into halves ----------------
// Grid 512 = at(2) x b(2) x qt(64) x half(2); each block does 32 K-tiles.
// Writes UNNORMALIZED partial O ([b][c][n] layout) + per-row (M,L) for the merge.
__global__ __launch_bounds__(256) void k_attn(float* __restrict__ ws) {
  int blk = blockIdx.x;
  int half = blk & 1; blk >>= 1;
  int qt = blk & 63;  blk >>= 6;
  int b  = blk & 1;   blk >>= 1;
  int at = blk;
  const float* Qg = ws + (at ? QG_OFF : QX_OFF) + ((size_t)b * N_ + qt * 64) * 64;
  const float* Kg = ws + (at ? KG_OFF : KX_OFF) + (size_t)b * N_ * 64;
  const float* Vg = ws + VX_OFF + (size_t)b * N_ * 64;  // both attns use x_value
  float* Pg = ws + (at ? (half ? P1G_OFF : GG_OFF) : (half ? P1X_OFF : XG_OFF))
            + (size_t)b * CN + qt * 64;

  constexpr int RS = 68;  // LDS row stride, 16B-aligned rows
  __shared__ float Qs[64 * RS];
  __shared__ float Ks[64 * RS];
  __shared__ float Vs[64 * RS];
  __shared__ float Ps[64 * RS];

  int t = threadIdx.x;
  int ty = t >> 4, tx = t & 15;

#pragma unroll
  for (int it = 0; it < 4; ++it) {
    int f = (it * 256 + t) * 4;
    int r = f >> 6, c = f & 63;
    *reinterpret_cast<float4*>(&Qs[r * RS + c]) = *reinterpret_cast<const float4*>(Qg + f);
  }

  float O[4][4] = {};
  float M[4], L[4];
#pragma unroll
  for (int i = 0; i < 4; ++i) { M[i] = -1e30f; L[i] = 0.f; }

  for (int mt = half * 32; mt < half * 32 + 32; ++mt) {
    __syncthreads();
    const float* Kt = Kg + (size_t)mt * 4096;
    const float* Vt = Vg + (size_t)mt * 4096;
#pragma unroll
    for (int it = 0; it < 4; ++it) {
      int f = (it * 256 + t) * 4;
      int r = f >> 6, c = f & 63;
      *reinterpret_cast<float4*>(&Ks[r * RS + c]) = *reinterpret_cast<const float4*>(Kt + f);
      *reinterpret_cast<float4*>(&Vs[r * RS + c]) = *reinterpret_cast<const float4*>(Vt + f);
    }
    __syncthreads();

    // ---- S = Q K^T (4x4 patch, cols m=16j+tx) ----
    float s[4][4] = {};
    for (int c0 = 0; c0 < 64; c0 += 4) {
      float4 qv[4], kv[4];
#pragma unroll
      for (int i = 0; i < 4; ++i)
        qv[i] = *reinterpret_cast<const float4*>(&Qs[(ty * 4 + i) * RS + c0]);
#pragma unroll
      for (int j = 0; j < 4; ++j)
        kv[j] = *reinterpret_cast<const float4*>(&Ks[(16 * j + tx) * RS + c0]);
#pragma unroll
      for (int i = 0; i < 4; ++i)
#pragma unroll
        for (int j = 0; j < 4; ++j) {
          s[i][j] = fmaf(qv[i].x, kv[j].x, s[i][j]);
          s[i][j] = fmaf(qv[i].y, kv[j].y, s[i][j]);
          s[i][j] = fmaf(qv[i].z, kv[j].z, s[i][j]);
          s[i][j] = fmaf(qv[i].w, kv[j].w, s[i][j]);
        }
    }

    // ---- online softmax per row ----
#pragma unroll
    for (int i = 0; i < 4; ++i) {
      float tm = fmaxf(fmaxf(s[i][0], s[i][1]), fmaxf(s[i][2], s[i][3]));
#pragma unroll
      for (int d = 1; d < 16; d <<= 1) tm = fmaxf(tm, __shfl_xor(tm, d, 16));
      float mn = fmaxf(M[i], tm);
      float sc = __expf(M[i] - mn);
      float ts = 0.f;
#pragma unroll
      for (int j = 0; j < 4; ++j) { s[i][j] = __expf(s[i][j] - mn); ts += s[i][j]; }
#pragma unroll
      for (int d = 1; d < 16; d <<= 1) ts += __shfl_xor(ts, d, 16);
      L[i] = L[i] * sc + ts;
      M[i] = mn;
#pragma unroll
      for (int j = 0; j < 4; ++j) O[i][j] *= sc;
      int rp = (ty * 4 + i) * RS;
#pragma unroll
      for (int j = 0; j < 4; ++j) Ps[rp + 16 * j + tx] = s[i][j];
    }
    __syncthreads();

    // ---- O += P * V (cols c=tx*4+j) ----
    for (int m0 = 0; m0 < 64; m0 += 4) {
      float4 pv[4];
#pragma unroll
      for (int i = 0; i < 4; ++i)
        pv[i] = *reinterpret_cast<const float4*>(&Ps[(ty * 4 + i) * RS + m0]);
#pragma unroll
      for (int kk = 0; kk < 4; ++kk) {
        float4 vr = *reinterpret_cast<const float4*>(&Vs[(m0 + kk) * RS + tx * 4]);
#pragma unroll
        for (int i = 0; i < 4; ++i) {
          float p = (kk == 0) ? pv[i].x : (kk == 1) ? pv[i].y : (kk == 2) ? pv[i].z : pv[i].w;
          O[i][0] = fmaf(p, vr.x, O[i][0]);
          O[i][1] = fmaf(p, vr.y, O[i][1]);
          O[i][2] = fmaf(p, vr.z, O[i][2]);
          O[i][3] = fmaf(p, vr.w, O[i][3]);
        }
      }
    }
  }

  // epilogue: write unnormalized partial O transposed [c][n], plus (M,L) per row
#pragma unroll
  for (int j = 0; j < 4; ++j) {
    float4 o = make_float4(O[0][j], O[1][j], O[2][j], O[3][j]);
    *reinterpret_cast<float4*>(Pg + (size_t)(tx * 4 + j) * N_ + ty * 4) = o;
  }
  if (tx == 0) {
    int mlb = ((at * 2 + half) * 2 + b) * 4096 + qt * 64 + ty * 4;
#pragma unroll
    for (int i = 0; i < 4; ++i) {
      ws[ML_OFF + mlb + i]  = M[i];
      ws[MLL_OFF + mlb + i] = L[i];
    }
  }
}

// ---------------- K5: merge halves + combine ----------------
// xc/gc = softmax-merged attention outs; writes GO = gc (in-place over half0 g partial,
// same linear index -> race-free) and OB = gamma*xc + alpha*gc (into dead QX region).
__global__ __launch_bounds__(256) void k_merge(float* __restrict__ ws) {
  size_t i4 = (size_t)blockIdx.x * 256 + threadIdx.x;  // float4 idx into [b][c][n]
  size_t i = i4 * 4;
  int n = (int)(i & 4095);
  int b = (int)(i >> 18);
  float gm = ws[GM_O], al = ws[AL_O];
  float4 p0x = *reinterpret_cast<const float4*>(ws + XG_OFF + i);
  float4 p1x = *reinterpret_cast<const float4*>(ws + P1X_OFF + i);
  float4 p0g = *reinterpret_cast<const float4*>(ws + GG_OFF + i);
  float4 p1g = *reinterpret_cast<const float4*>(ws + P1G_OFF + i);
  float4 M0x = *reinterpret_cast<const float4*>(ws + ML_OFF  + (0 + b) * 4096 + n);
  float4 L0x = *reinterpret_cast<const float4*>(ws + MLL_OFF + (0 + b) * 4096 + n);
  float4 M1x = *reinterpret_cast<const float4*>(ws + ML_OFF  + (2 + b) * 4096 + n);
  float4 L1x = *reinterpret_cast<const float4*>(ws + MLL_OFF + (2 + b) * 4096 + n);
  float4 M0g = *reinterpret_cast<const float4*>(ws + ML_OFF  + (4 + b) * 4096 + n);
  float4 L0g = *reinterpret_cast<const float4*>(ws + MLL_OFF + (4 + b) * 4096 + n);
  float4 M1g = *reinterpret_cast<const float4*>(ws + ML_OFF  + (6 + b) * 4096 + n);
  float4 L1g = *reinterpret_cast<const float4*>(ws + MLL_OFF + (6 + b) * 4096 + n);
  const float* p0xv = (const float*)&p0x; const float* p1xv = (const float*)&p1x;
  const float* p0gv = (const float*)&p0g; const float* p1gv = (const float*)&p1g;
  const float* m0xv = (const float*)&M0x; const float* l0xv = (const float*)&L0x;
  const float* m1xv = (const float*)&M1x; const float* l1xv = (const float*)&L1x;
  const float* m0gv = (const float*)&M0g; const float* l0gv = (const float*)&L0g;
  const float* m1gv = (const float*)&M1g; const float* l1gv = (const float*)&L1g;
  float4 go, ob;
  float* gov = (float*)&go; float* obv = (float*)&ob;
#pragma unroll
  for (int l = 0; l < 4; ++l) {
    float mx = fmaxf(m0xv[l], m1xv[l]);
    float w0 = __expf(m0xv[l] - mx), w1 = __expf(m1xv[l] - mx);
    float xc = (p0xv[l] * w0 + p1xv[l] * w1) / (l0xv[l] * w0 + l1xv[l] * w1);
    float mg = fmaxf(m0gv[l], m1gv[l]);
    float v0 = __expf(m0gv[l] - mg), v1 = __expf(m1gv[l] - mg);
    float gc = (p0gv[l] * v0 + p1gv[l] * v1) / (l0gv[l] * v0 + l1gv[l] * v1);
    gov[l] = gc;
    obv[l] = gm * xc + al * gc;
  }
  *reinterpret_cast<float4*>(ws + GG_OFF + i) = go;  // GO
  *reinterpret_cast<float4*>(ws + QX_OFF + i) = ob;  // OB
}

// ---------------- K6: u = leaky(conv3x3(leaky(out), c1)) ----------------
__global__ __launch_bounds__(256) void k_conv1(float* __restrict__ ws) {
  int blk = blockIdx.x;  // 2*64*16
  int rt = blk & 15; blk >>= 4;
  int o  = blk & 63; blk >>= 6;
  int b  = blk;
  __shared__ float wl[576];
  __shared__ float tile[384];
  int t = threadIdx.x;
  for (int idx = t; idx < 576; idx += 256) wl[idx] = ws[C1W_O + (size_t)o * 576 + idx];
  int row = t >> 6, col = t & 63;
  int h = rt * 4 + row;
  float acc = 0.f;
  const float* in0 = ws + OB_OFF + (size_t)b * CN;
  for (int i = 0; i < 64; ++i) {
    __syncthreads();
    for (int idx = t; idx < 384; idx += 256) {
      int r = idx >> 6, cc = idx & 63;
      int hh = rt * 4 - 1 + r;
      float v = 0.f;
      if (hh >= 0 && hh < 64) v = leaky(in0[(size_t)i * N_ + hh * 64 + cc]);
      tile[idx] = v;
    }
    __syncthreads();
    const float* wli = &wl[i * 9];
#pragma unroll
    for (int ky = 0; ky < 3; ++ky) {
#pragma unroll
      for (int kx = 0; kx < 3; ++kx) {
        int wc = col + kx - 1;
        float v = (wc >= 0 && wc < 64) ? tile[(row + ky) * 64 + wc] : 0.f;
        acc = fmaf(wli[ky * 3 + kx], v, acc);
      }
    }
  }
  acc = leaky(acc + ws[C1B_O + o]);
  ws[UB_OFF + (size_t)b * CN + (size_t)o * N_ + h * 64 + col] = acc;
}

// ---------------- K7: final = conv3x3(u,c2) + conv1x1(out,sc)*guide_out ----------------
__global__ __launch_bounds__(256) void k_final(const float* __restrict__ ws,
                                               float* __restrict__ out) {
  int blk = blockIdx.x;  // 2*64*16
  int rt = blk & 15; blk >>= 4;
  int o  = blk & 63; blk >>= 6;
  int b  = blk;
  __shared__ float wl[576];
  __shared__ float scl[64];
  __shared__ float tile[384];
  int t = threadIdx.x;
  for (int idx = t; idx < 576; idx += 256) wl[idx] = ws[C2W_O + (size_t)o * 576 + idx];
  if (t < 64) scl[t] = ws[SCW_O + (size_t)o * 64 + t];
  int row = t >> 6, col = t & 63;
  int h = rt * 4 + row;
  int pix = h * 64 + col;
  float acc = 0.f, accsc = 0.f;
  const float* u0 = ws + UB_OFF + (size_t)b * CN;
  const float* ob0 = ws + OB_OFF + (size_t)b * CN;
  for (int i = 0; i < 64; ++i) {
    __syncthreads();
    for (int idx = t; idx < 384; idx += 256) {
      int r = idx >> 6, cc = idx & 63;
      int hh = rt * 4 - 1 + r;
      float v = 0.f;
      if (hh >= 0 && hh < 64) v = u0[(size_t)i * N_ + hh * 64 + cc];
      tile[idx] = v;
    }
    __syncthreads();
    const float* wli = &wl[i * 9];
#pragma unroll
    for (int ky = 0; ky < 3; ++ky) {
#pragma unroll
      for (int kx = 0; kx < 3; ++kx) {
        int wc = col + kx - 1;
        float v = (wc >= 0 && wc < 64) ? tile[(row + ky) * 64 + wc] : 0.f;
        acc = fmaf(wli[ky * 3 + kx], v, acc);
      }
    }
    accsc = fmaf(scl[i], ob0[(size_t)i * N_ + pix], accsc);
  }
  float branch = acc + ws[C2B_O + o];
  float scv = accsc + ws[SCB_O + o];
  float gv = ws[GO_OFF + (size_t)b * CN + (size_t)o * N_ + pix];
  out[(size_t)b * CN + (size_t)o * N_ + pix] = branch + scv * gv;
}

extern "C" void kernel_launch(void* const* d_in, const int* in_sizes, int n_in,
                              void* d_out, int out_size, void* d_ws, size_t ws_size,
                              hipStream_t stream) {
  const void* x      = d_in[0];
  const void* guide  = d_in[1];
  float* out = (float*)d_out;
  float* ws = (float*)d_ws;

  k_detect<<<64, 256, 0, stream>>>(d_in[0], d_in[2], d_in[3], d_in[4],
                                   d_in[5], d_in[6], d_in[7], d_in[8],
                                   d_in[9], d_in[10], d_in[11], d_in[12],
                                   d_in[13], d_in[14], d_in[15], d_in[16],
                                   d_in[17], d_in[18], d_in[19], d_in[20],
                                   d_in[21], d_in[22], ws);
  k_chattn<<<256, 256, 0, stream>>>(x, guide, ws);
  k_coordconv<<<4096, 256, 0, stream>>>(x, guide, ws);
  k_proj<<<640, 256, 0, stream>>>(ws);
  k_attn<<<512, 256, 0, stream>>>(ws);
  k_merge<<<512, 256, 0, stream>>>(ws);
  k_conv1<<<2048, 256, 0, stream>>>(ws);
  k_final<<<2048, 256, 0, stream>>>(ws, out);
}

// Round 7
// 562.646 us; speedup vs baseline: 5.5165x; 1.3003x over previous
//
#include <hip/hip_runtime.h>
#include <hip/hip_bf16.h>

using bf16 = __hip_bfloat16;

#define DI __device__ __forceinline__

typedef __attribute__((ext_vector_type(8))) short short8;
typedef __attribute__((ext_vector_type(4))) float f32x4;
typedef __attribute__((ext_vector_type(4))) unsigned short u16x4;

#define MFMA_BF16 __builtin_amdgcn_mfma_f32_16x16x32_bf16

DI float b2f(bf16 v) { return __bfloat162float(v); }
DI float leaky(float x) { return x > 0.f ? x : 0.1f * x; }

// bf16 split helpers (RNE). x = hi + lo to ~2^-16 relative.
DI unsigned short b16(float x) {
  union { float f; unsigned u; } v; v.f = x;
  unsigned r = v.u + 0x7FFFu + ((v.u >> 16) & 1u);
  return (unsigned short)(r >> 16);
}
DI float fromb16(unsigned short h) {
  union { unsigned u; float f; } v; v.u = ((unsigned)h) << 16; return v.f;
}

// Flag-dispatched input load (R3 evidence: fp32 inputs).
DI float ldin(const void* p, size_t i, int isbf) {
  return isbf ? b2f(((const bf16*)p)[i]) : ((const float*)p)[i];
}

// Problem constants: B=2, C=64, H=64, W=64, N=4096
static constexpr int N_ = 4096;
static constexpr size_t CN = 262144;   // C*N per batch
static constexpr size_t BCN = 524288;  // B*C*N

// ---- Workspace layout (float indices) ----
static constexpr size_t LW_O = 0, LB_O = 1, GM_O = 2, AL_O = 3;
static constexpr size_t CW_O  = 4;                  // 38016
static constexpr size_t XQW_O = 38020;              // 4096
static constexpr size_t XQB_O = 42116;              // 64
static constexpr size_t XKW_O = 42180;
static constexpr size_t XKB_O = 46276;
static constexpr size_t XVW_O = 46340;
static constexpr size_t XVB_O = 50436;
static constexpr size_t GQW_O = 50500;
static constexpr size_t GQB_O = 54596;
static constexpr size_t GKW_O = 54660;
static constexpr size_t GKB_O = 58756;
static constexpr size_t C1W_O = 58820;              // 36864
static constexpr size_t C1B_O = 95684;
static constexpr size_t C2W_O = 95748;              // 36864
static constexpr size_t C2B_O = 132612;
static constexpr size_t SCW_O = 132676;             // 4096
static constexpr size_t SCB_O = 136772;             // 64 (params end 136836)
static constexpr size_t CA_O  = 136836;             // 256: [src][b][c]
static constexpr size_t FLAG_O = 137092;            // int flag
static constexpr size_t XG_OFF = 137104;            // gated x; then x-attn half0 partial
static constexpr size_t GG_OFF = XG_OFF + BCN;      // gated g; then g-attn half0 partial; then GO
static constexpr size_t QX_OFF = GG_OFF + BCN;      // [b][n][c]; then OB
static constexpr size_t KX_OFF = QX_OFF + BCN;      // then UB
static constexpr size_t VX_OFF = KX_OFF + BCN;      // V stored TRANSPOSED: [b][c][n]
static constexpr size_t QG_OFF = VX_OFF + BCN;
static constexpr size_t KG_OFF = QG_OFF + BCN;
static constexpr size_t P1X_OFF = KG_OFF + BCN;     // x-attn half1 partial [b][c][n]
static constexpr size_t P1G_OFF = P1X_OFF + BCN;    // g-attn half1 partial
static constexpr size_t ML_OFF  = P1G_OFF + BCN;    // M[at][half][b][n]  (8*4096)
static constexpr size_t MLL_OFF = ML_OFF + 32768;   // L[at][half][b][n]
static constexpr size_t OB_OFF = QX_OFF;
static constexpr size_t UB_OFF = KX_OFF;
static constexpr size_t GO_OFF = GG_OFF;
// Peak: MLL_OFF + 32768 = 19.7 MB (validated: R6 passed with this layout)

// ---------------- K0: dtype detect + param conversion to fp32 (parallel) ----------------
__global__ __launch_bounds__(256) void k_detect(
    const void* x, const void* lw, const void* lb, const void* cw,
    const void* xqw, const void* xqb, const void* xkw, const void* xkb,
    const void* xvw, const void* xvb, const void* gqw, const void* gqb,
    const void* gkw, const void* gkb, const void* gm, const void* al,
    const void* c1w, const void* c1b, const void* c2w, const void* c2b,
    const void* scw, const void* scb, float* ws) {
  __shared__ int sred[256];
  int t = threadIdx.x;
  const unsigned short* u = (const unsigned short*)x;
  int e = (u[t * 2] >> 7) & 0xFF;
  sred[t] = (e >= 117 && e <= 130) ? 1 : 0;
  __syncthreads();
  for (int off = 128; off; off >>= 1) {
    if (t < off) sred[t] += sred[t + off];
    __syncthreads();
  }
  int isbf = sred[0] > 128 ? 1 : 0;
  if (blockIdx.x == 0 && t == 0) ((int*)ws)[FLAG_O] = isbf;
  int gid = blockIdx.x * 256 + t;
  int stride = gridDim.x * 256;
  for (int i = gid; i < 136836; i += stride) {
    const void* p; int rel;
    if (i < 4)               { p = (i == 0 ? lw : i == 1 ? lb : i == 2 ? gm : al); rel = 0; }
    else if (i < (int)XQW_O) { p = cw;  rel = i - (int)CW_O; }
    else if (i < (int)XQB_O) { p = xqw; rel = i - (int)XQW_O; }
    else if (i < (int)XKW_O) { p = xqb; rel = i - (int)XQB_O; }
    else if (i < (int)XKB_O) { p = xkw; rel = i - (int)XKW_O; }
    else if (i < (int)XVW_O) { p = xkb; rel = i - (int)XKB_O; }
    else if (i < (int)XVB_O) { p = xvw; rel = i - (int)XVW_O; }
    else if (i < (int)GQW_O) { p = xvb; rel = i - (int)XVB_O; }
    else if (i < (int)GQB_O) { p = gqw; rel = i - (int)GQW_O; }
    else if (i < (int)GKW_O) { p = gqb; rel = i - (int)GQB_O; }
    else if (i < (int)GKB_O) { p = gkw; rel = i - (int)GKW_O; }
    else if (i < (int)C1W_O) { p = gkb; rel = i - (int)GKB_O; }
    else if (i < (int)C1B_O) { p = c1w; rel = i - (int)C1W_O; }
    else if (i < (int)C2W_O) { p = c1b; rel = i - (int)C1B_O; }
    else if (i < (int)C2B_O) { p = c2w; rel = i - (int)C2W_O; }
    else if (i < (int)SCW_O) { p = c2b; rel = i - (int)C2B_O; }
    else if (i < (int)SCB_O) { p = scw; rel = i - (int)SCW_O; }
    else                     { p = scb; rel = i - (int)SCB_O; }
    ws[i] = ldin(p, rel, isbf);
  }
}

// ---------------- K1: channel attention scalars ----------------
__global__ __launch_bounds__(256) void k_chattn(const void* __restrict__ x,
                                                const void* __restrict__ g,
                                                float* __restrict__ ws) {
  int isbf = ((const int*)ws)[FLAG_O];
  int blk = blockIdx.x;          // 0..255
  int src = blk >> 7;
  int rem = blk & 127;
  int b = rem >> 6, c = rem & 63;
  const void* base = src ? g : x;
  size_t off0 = ((size_t)(b * 64 + c)) * N_;
  float s = 0.f;
  for (int i = threadIdx.x; i < N_; i += 256) s += ldin(base, off0 + i, isbf);
  __shared__ float red[256];
  red[threadIdx.x] = s;
  __syncthreads();
  for (int off = 128; off; off >>= 1) {
    if (threadIdx.x < off) red[threadIdx.x] += red[threadIdx.x + off];
    __syncthreads();
  }
  if (threadIdx.x == 0) {
    float p = red[0] * (1.f / (float)N_);
    float lw = ws[LW_O], lb = ws[LB_O];
    float h = leaky(lw * p + lb);
    float z = lw * h + lb;
    ws[CA_O + src * 128 + b * 64 + c] = 1.f / (1.f + expf(-z));
  }
}

// ---------------- K2: coord-conv 3x3 (66 in-ch) * channel attn ----------------
__global__ __launch_bounds__(256) void k_coordconv(const void* __restrict__ x,
                                                   const void* __restrict__ g,
                                                   float* __restrict__ ws) {
  int isbf = ((const int*)ws)[FLAG_O];
  int blk = blockIdx.x;  // 2*2*64*16
  int rt = blk & 15; blk >>= 4;
  int o  = blk & 63; blk >>= 6;
  int b  = blk & 1;  blk >>= 1;
  int src = blk;
  const void* in = src ? g : x;
  float* outp = ws + (src ? GG_OFF : XG_OFF);
  __shared__ float wl[594];
  __shared__ float tile[384];  // 6 rows x 64 cols
  int t = threadIdx.x;
  for (int idx = t; idx < 594; idx += 256) wl[idx] = ws[CW_O + (size_t)o * 594 + idx];
  int row = t >> 6, col = t & 63;
  int h = rt * 4 + row;
  float acc = 0.f;
  for (int i = 0; i < 66; ++i) {
    __syncthreads();
    for (int idx = t; idx < 384; idx += 256) {
      int r = idx >> 6, cc = idx & 63;
      int hh = rt * 4 - 1 + r;
      float v = 0.f;
      if (hh >= 0 && hh < 64) {
        if (i < 64)       v = ldin(in, ((size_t)(b * 64 + i)) * N_ + hh * 64 + cc, isbf);
        else if (i == 64) v = (float)cc * (2.f / 63.f) - 1.f;   // xx: varies along width
        else              v = (float)hh * (2.f / 63.f) - 1.f;   // yy: varies along height
      }
      tile[idx] = v;
    }
    __syncthreads();
    const float* wli = &wl[i * 9];
#pragma unroll
    for (int ky = 0; ky < 3; ++ky) {
#pragma unroll
      for (int kx = 0; kx < 3; ++kx) {
        int wc = col + kx - 1;
        float v = (wc >= 0 && wc < 64) ? tile[(row + ky) * 64 + wc] : 0.f;
        acc = fmaf(wli[ky * 3 + kx], v, acc);
      }
    }
  }
  float cav = ws[CA_O + src * 128 + b * 64 + o];
  outp[((size_t)(b * 64 + o)) * N_ + h * 64 + col] = cav * acc;
}

// ---------------- K3: 1x1 conv projections ----------------
// Q/K written [b][n][c]; V written TRANSPOSED [b][c][n] (for MFMA attention staging).
__global__ __launch_bounds__(256) void k_proj(float* __restrict__ ws) {
  int blk = blockIdx.x;  // 5 * 2 * 64
  int pt = blk & 63; blk >>= 6;
  int b  = blk & 1;  blk >>= 1;
  int which = blk;  // 0..4
  size_t in_o, w_o, b_o, out_o;
  if (which == 0)      { in_o = XG_OFF; w_o = XQW_O; b_o = XQB_O; out_o = QX_OFF; }
  else if (which == 1) { in_o = XG_OFF; w_o = XKW_O; b_o = XKB_O; out_o = KX_OFF; }
  else if (which == 2) { in_o = XG_OFF; w_o = XVW_O; b_o = XVB_O; out_o = VX_OFF; }
  else if (which == 3) { in_o = GG_OFF; w_o = GQW_O; b_o = GQB_O; out_o = QG_OFF; }
  else                 { in_o = GG_OFF; w_o = GKW_O; b_o = GKB_O; out_o = KG_OFF; }

  __shared__ float tile[64 * 64];
  __shared__ float wl[64 * 65];
  __shared__ float bl[64];
  int t = threadIdx.x;
  int pb = pt * 64;
  const float* in0 = ws + in_o + (size_t)b * CN + pb;
  for (int c0 = (t >> 6); c0 < 64; c0 += 4)
    tile[c0 * 64 + (t & 63)] = in0[(size_t)c0 * N_ + (t & 63)];
  for (int idx = t; idx < 4096; idx += 256)
    wl[(idx >> 6) * 65 + (idx & 63)] = ws[w_o + idx];
  if (t < 64) bl[t] = ws[b_o + t];
  __syncthreads();
  int o = t & 63, grp = t >> 6;
  float* outp = ws + out_o;
  if (which != 2) {
    for (int j = 0; j < 16; ++j) {
      int pix = grp * 16 + j;
      float acc = bl[o];
      const float* wr = &wl[o * 65];
#pragma unroll
      for (int c = 0; c < 64; ++c) acc = fmaf(wr[c], tile[c * 64 + pix], acc);
      outp[((size_t)b * N_ + pb + pix) * 64 + o] = acc;
    }
  } else {
    // V: compute into regs, retranspose via LDS, write [b][c][n]
    float accs[16];
#pragma unroll
    for (int j = 0; j < 16; ++j) {
      int pix = grp * 16 + j;
      float acc = bl[o];
      const float* wr = &wl[o * 65];
#pragma unroll
      for (int c = 0; c < 64; ++c) acc = fmaf(wr[c], tile[c * 64 + pix], acc);
      accs[j] = acc;
    }
    __syncthreads();           // all wl reads done
    float* ot = wl;            // reuse as [o][65]
#pragma unroll
    for (int j = 0; j < 16; ++j) ot[o * 65 + grp * 16 + j] = accs[j];
    __syncthreads();
    int o2 = t >> 2;
#pragma unroll
    for (int e = 0; e < 4; ++e) {
      int px = (t & 3) * 16 + e * 4;
      float4 vv = make_float4(ot[o2 * 65 + px], ot[o2 * 65 + px + 1],
                              ot[o2 * 65 + px + 2], ot[o2 * 65 + px + 3]);
      *reinterpret_cast<float4*>(outp + ((size_t)(b * 64 + o2)) * N_ + pb + px) = vv;
    }
  }
}

// ---------------- K4: split-bf16 MFMA flash attention (m-split halves) ----------------
// Grid 512 = at(2) x b(2) x qt(64) x half(2); each block: 32 K-tiles of 64.
// S = Q K^T via 3 split-MFMAs; online softmax; O^T = V^T P^T via 3 split-MFMAs.
// Writes unnormalized partial O^T in [b][c][n] + per-row (M,L) for k_merge.
__global__ __launch_bounds__(256) void k_attn(float* __restrict__ ws) {
  int blk = blockIdx.x;
  int half = blk & 1; blk >>= 1;
  int qt = blk & 63;  blk >>= 6;
  int b  = blk & 1;   blk >>= 1;
  int at = blk;
  const float* Qg = ws + (at ? QG_OFF : QX_OFF) + ((size_t)b * N_ + qt * 64) * 64;
  const float* Kg = ws + (at ? KG_OFF : KX_OFF) + (size_t)b * N_ * 64;
  const float* Vg = ws + VX_OFF + (size_t)b * CN;  // [c][n]
  float* Pg = ws + (at ? (half ? P1G_OFF : GG_OFF) : (half ? P1X_OFF : XG_OFF))
            + (size_t)b * CN + qt * 64;

  // LDS: rows of 64 bf16 (128 B), XOR swizzle on 16B chunks: chunk' = chunk ^ (row&7)
  __shared__ unsigned short Kh[4096], Kl[4096], Vth[4096], Vtl[4096], Ph[4096], Pl[4096];
  __shared__ float sAl[64];

  int t = threadIdx.x;
  int w = t >> 6, lane = t & 63, quad = lane >> 4, l15 = lane & 15;
  int swz = l15 & 7;  // row&7 for all per-lane MFMA reads (row = base16 + l15)

  // Q A-fragments in registers: row n = qt*64 + 16w + l15, k = ks*32 + quad*8 + j
  short8 qh[2], ql[2];
  {
    const float* qr = Qg + (size_t)(16 * w + l15) * 64;
#pragma unroll
    for (int ks = 0; ks < 2; ++ks) {
      int c0 = ks * 32 + quad * 8;
#pragma unroll
      for (int j = 0; j < 8; ++j) {
        float xv = qr[c0 + j];
        unsigned short h = b16(xv);
        unsigned short lo = b16(xv - fromb16(h));
        qh[ks][j] = (short)h; ql[ks][j] = (short)lo;
      }
    }
  }

  f32x4 Oa[4] = {{0.f, 0.f, 0.f, 0.f}, {0.f, 0.f, 0.f, 0.f},
                 {0.f, 0.f, 0.f, 0.f}, {0.f, 0.f, 0.f, 0.f}};
  float M[4] = {-1e30f, -1e30f, -1e30f, -1e30f};
  float L[4] = {0.f, 0.f, 0.f, 0.f};

  for (int mt = half * 32; mt < half * 32 + 32; ++mt) {
    __syncthreads();  // previous tile's readers done
    // ---- stage K rows [m][c] and V rows [c][m] as split bf16 ----
    {
      const float4* K4 = reinterpret_cast<const float4*>(Kg + (size_t)mt * 4096);
#pragma unroll
      for (int it = 0; it < 4; ++it) {
        int f4 = it * 256 + t;
        int r = f4 >> 4, c0 = (f4 & 15) * 4;
        float4 kv = K4[f4];
        u16x4 hv, lv;
        {
          unsigned short h, lo;
          h = b16(kv.x); lo = b16(kv.x - fromb16(h)); hv[0] = h; lv[0] = lo;
          h = b16(kv.y); lo = b16(kv.y - fromb16(h)); hv[1] = h; lv[1] = lo;
          h = b16(kv.z); lo = b16(kv.z - fromb16(h)); hv[2] = h; lv[2] = lo;
          h = b16(kv.w); lo = b16(kv.w - fromb16(h)); hv[3] = h; lv[3] = lo;
        }
        int off = r * 64 + (((c0 >> 3) ^ (r & 7)) << 3) + (c0 & 7);
        *reinterpret_cast<u16x4*>(&Kh[off]) = hv;
        *reinterpret_cast<u16x4*>(&Kl[off]) = lv;
        // V tile: row c=r, cols m = c0..c0+3 from global row r at mt*64+c0
        float4 vv = *reinterpret_cast<const float4*>(Vg + (size_t)r * N_ + mt * 64 + c0);
        {
          unsigned short h, lo;
          h = b16(vv.x); lo = b16(vv.x - fromb16(h)); hv[0] = h; lv[0] = lo;
          h = b16(vv.y); lo = b16(vv.y - fromb16(h)); hv[1] = h; lv[1] = lo;
          h = b16(vv.z); lo = b16(vv.z - fromb16(h)); hv[2] = h; lv[2] = lo;
          h = b16(vv.w); lo = b16(vv.w - fromb16(h)); hv[3] = h; lv[3] = lo;
        }
        *reinterpret_cast<u16x4*>(&Vth[off]) = hv;
        *reinterpret_cast<u16x4*>(&Vtl[off]) = lv;
      }
    }
    __syncthreads();

    // ---- S = Q K^T : wave w rows n=16w..+15, all 64 m (4 subtiles) ----
    f32x4 S[4];
#pragma unroll
    for (int ms = 0; ms < 4; ++ms) {
      f32x4 acc = {0.f, 0.f, 0.f, 0.f};
#pragma unroll
      for (int ks = 0; ks < 2; ++ks) {
        int row = ms * 16 + l15;
        int off = row * 64 + ((((ks * 4 + quad)) ^ swz) << 3);
        short8 khf = *reinterpret_cast<const short8*>(&Kh[off]);
        short8 klf = *reinterpret_cast<const short8*>(&Kl[off]);
        acc = MFMA_BF16(ql[ks], khf, acc, 0, 0, 0);
        acc = MFMA_BF16(qh[ks], klf, acc, 0, 0, 0);
        acc = MFMA_BF16(qh[ks], khf, acc, 0, 0, 0);
      }
      S[ms] = acc;
    }

    // ---- online softmax (rows n = 16w + quad*4 + r) ----
    float alpha[4];
#pragma unroll
    for (int r = 0; r < 4; ++r) {
      float tm = fmaxf(fmaxf(S[0][r], S[1][r]), fmaxf(S[2][r], S[3][r]));
#pragma unroll
      for (int d = 1; d < 16; d <<= 1) tm = fmaxf(tm, __shfl_xor(tm, d, 16));
      float mn = fmaxf(M[r], tm);
      float al = __expf(M[r] - mn);
      float ts = 0.f;
      float p[4];
#pragma unroll
      for (int ms = 0; ms < 4; ++ms) { p[ms] = __expf(S[ms][r] - mn); ts += p[ms]; }
#pragma unroll
      for (int d = 1; d < 16; d <<= 1) ts += __shfl_xor(ts, d, 16);
      L[r] = L[r] * al + ts;
      M[r] = mn;
      alpha[r] = al;
      int n = 16 * w + quad * 4 + r;
#pragma unroll
      for (int ms = 0; ms < 4; ++ms) {
        int m = ms * 16 + l15;
        int off = n * 64 + ((((m >> 3)) ^ (n & 7)) << 3) + (m & 7);
        unsigned short h = b16(p[ms]);
        unsigned short lo = b16(p[ms] - fromb16(h));
        Ph[off] = h; Pl[off] = lo;
      }
    }
    // per-row alpha to LDS (wave-private rows; in-wave lgkm dependency only)
    if (l15 < 4) {
      float av = (l15 == 0) ? alpha[0] : (l15 == 1) ? alpha[1] : (l15 == 2) ? alpha[2] : alpha[3];
      sAl[16 * w + quad * 4 + l15] = av;
    }
    float av = sAl[16 * w + l15];
#pragma unroll
    for (int cs = 0; cs < 4; ++cs) {
      Oa[cs][0] *= av; Oa[cs][1] *= av; Oa[cs][2] *= av; Oa[cs][3] *= av;
    }

    // ---- O^T += V^T P^T : A = Vt rows c, B = P cols n (wave's rows) ----
#pragma unroll
    for (int cs = 0; cs < 4; ++cs) {
      f32x4 acc = Oa[cs];
#pragma unroll
      for (int ks = 0; ks < 2; ++ks) {
        int vrow = cs * 16 + l15;
        int voff = vrow * 64 + ((((ks * 4 + quad)) ^ swz) << 3);
        short8 vhf = *reinterpret_cast<const short8*>(&Vth[voff]);
        short8 vlf = *reinterpret_cast<const short8*>(&Vtl[voff]);
        int prow = 16 * w + l15;
        int poff = prow * 64 + ((((ks * 4 + quad)) ^ swz) << 3);
        short8 phf = *reinterpret_cast<const short8*>(&Ph[poff]);
        short8 plf = *reinterpret_cast<const short8*>(&Pl[poff]);
        acc = MFMA_BF16(vlf, phf, acc, 0, 0, 0);
        acc = MFMA_BF16(vhf, plf, acc, 0, 0, 0);
        acc = MFMA_BF16(vhf, phf, acc, 0, 0, 0);
      }
      Oa[cs] = acc;
    }
  }

  // ---- epilogue: unnormalized O^T partial + (M,L) ----
#pragma unroll
  for (int cs = 0; cs < 4; ++cs) {
#pragma unroll
    for (int r = 0; r < 4; ++r) {
      int c = cs * 16 + quad * 4 + r;
      Pg[(size_t)c * N_ + 16 * w + l15] = Oa[cs][r];
    }
  }
  if (l15 < 4) {
    float Mv = (l15 == 0) ? M[0] : (l15 == 1) ? M[1] : (l15 == 2) ? M[2] : M[3];
    float Lv = (l15 == 0) ? L[0] : (l15 == 1) ? L[1] : (l15 == 2) ? L[2] : L[3];
    int mlb = ((at * 2 + half) * 2 + b) * 4096 + qt * 64 + 16 * w + quad * 4 + l15;
    ws[ML_OFF + mlb] = Mv;
    ws[MLL_OFF + mlb] = Lv;
  }
}

// ---------------- K5: merge halves + combine ----------------
__global__ __launch_bounds__(256) void k_merge(float* __restrict__ ws) {
  size_t i4 = (size_t)blockIdx.x * 256 + threadIdx.x;
  size_t i = i4 * 4;
  int n = (int)(i & 4095);
  int b = (int)(i >> 18);
  float gm = ws[GM_O], al = ws[AL_O];
  float4 p0x = *reinterpret_cast<const float4*>(ws + XG_OFF + i);
  float4 p1x = *reinterpret_cast<const float4*>(ws + P1X_OFF + i);
  float4 p0g = *reinterpret_cast<const float4*>(ws + GG_OFF + i);
  float4 p1g = *reinterpret_cast<const float4*>(ws + P1G_OFF + i);
  float4 M0x = *reinterpret_cast<const float4*>(ws + ML_OFF  + (0 + b) * 4096 + n);
  float4 L0x = *reinterpret_cast<const float4*>(ws + MLL_OFF + (0 + b) * 4096 + n);
  float4 M1x = *reinterpret_cast<const float4*>(ws + ML_OFF  + (2 + b) * 4096 + n);
  float4 L1x = *reinterpret_cast<const float4*>(ws + MLL_OFF + (2 + b) * 4096 + n);
  float4 M0g = *reinterpret_cast<const float4*>(ws + ML_OFF  + (4 + b) * 4096 + n);
  float4 L0g = *reinterpret_cast<const float4*>(ws + MLL_OFF + (4 + b) * 4096 + n);
  float4 M1g = *reinterpret_cast<const float4*>(ws + ML_OFF  + (6 + b) * 4096 + n);
  float4 L1g = *reinterpret_cast<const float4*>(ws + MLL_OFF + (6 + b) * 4096 + n);
  const float* p0xv = (const float*)&p0x; const float* p1xv = (const float*)&p1x;
  const float* p0gv = (const float*)&p0g; const float* p1gv = (const float*)&p1g;
  const float* m0xv = (const float*)&M0x; const float* l0xv = (const float*)&L0x;
  const float* m1xv = (const float*)&M1x; const float* l1xv = (const float*)&L1x;
  const float* m0gv = (const float*)&M0g; const float* l0gv = (const float*)&L0g;
  const float* m1gv = (const float*)&M1g; const float* l1gv = (const float*)&L1g;
  float4 go, ob;
  float* gov = (float*)&go; float* obv = (float*)&ob;
#pragma unroll
  for (int l = 0; l < 4; ++l) {
    float mx = fmaxf(m0xv[l], m1xv[l]);
    float w0 = __expf(m0xv[l] - mx), w1 = __expf(m1xv[l] - mx);
    float xc = (p0xv[l] * w0 + p1xv[l] * w1) / (l0xv[l] * w0 + l1xv[l] * w1);
    float mg = fmaxf(m0gv[l], m1gv[l]);
    float v0 = __expf(m0gv[l] - mg), v1 = __expf(m1gv[l] - mg);
    float gc = (p0gv[l] * v0 + p1gv[l] * v1) / (l0gv[l] * v0 + l1gv[l] * v1);
    gov[l] = gc;
    obv[l] = gm * xc + al * gc;
  }
  *reinterpret_cast<float4*>(ws + GG_OFF + i) = go;  // GO
  *reinterpret_cast<float4*>(ws + QX_OFF + i) = ob;  // OB
}

// ---------------- K6: u = leaky(conv3x3(leaky(out), c1)) ----------------
__global__ __launch_bounds__(256) void k_conv1(float* __restrict__ ws) {
  int blk = blockIdx.x;  // 2*64*16
  int rt = blk & 15; blk >>= 4;
  int o  = blk & 63; blk >>= 6;
  int b  = blk;
  __shared__ float wl[576];
  __shared__ float tile[384];
  int t = threadIdx.x;
  for (int idx = t; idx < 576; idx += 256) wl[idx] = ws[C1W_O + (size_t)o * 576 + idx];
  int row = t >> 6, col = t & 63;
  int h = rt * 4 + row;
  float acc = 0.f;
  const float* in0 = ws + OB_OFF + (size_t)b * CN;
  for (int i = 0; i < 64; ++i) {
    __syncthreads();
    for (int idx = t; idx < 384; idx += 256) {
      int r = idx >> 6, cc = idx & 63;
      int hh = rt * 4 - 1 + r;
      float v = 0.f;
      if (hh >= 0 && hh < 64) v = leaky(in0[(size_t)i * N_ + hh * 64 + cc]);
      tile[idx] = v;
    }
    __syncthreads();
    const float* wli = &wl[i * 9];
#pragma unroll
    for (int ky = 0; ky < 3; ++ky) {
#pragma unroll
      for (int kx = 0; kx < 3; ++kx) {
        int wc = col + kx - 1;
        float v = (wc >= 0 && wc < 64) ? tile[(row + ky) * 64 + wc] : 0.f;
        acc = fmaf(wli[ky * 3 + kx], v, acc);
      }
    }
  }
  acc = leaky(acc + ws[C1B_O + o]);
  ws[UB_OFF + (size_t)b * CN + (size_t)o * N_ + h * 64 + col] = acc;
}

// ---------------- K7: final = conv3x3(u,c2) + conv1x1(out,sc)*guide_out ----------------
__global__ __launch_bounds__(256) void k_final(const float* __restrict__ ws,
                                               float* __restrict__ out) {
  int blk = blockIdx.x;  // 2*64*16
  int rt = blk & 15; blk >>= 4;
  int o  = blk & 63; blk >>= 6;
  int b  = blk;
  __shared__ float wl[576];
  __shared__ float scl[64];
  __shared__ float tile[384];
  int t = threadIdx.x;
  for (int idx = t; idx < 576; idx += 256) wl[idx] = ws[C2W_O + (size_t)o * 576 + idx];
  if (t < 64) scl[t] = ws[SCW_O + (size_t)o * 64 + t];
  int row = t >> 6, col = t & 63;
  int h = rt * 4 + row;
  int pix = h * 64 + col;
  float acc = 0.f, accsc = 0.f;
  const float* u0 = ws + UB_OFF + (size_t)b * CN;
  const float* ob0 = ws + OB_OFF + (size_t)b * CN;
  for (int i = 0; i < 64; ++i) {
    __syncthreads();
    for (int idx = t; idx < 384; idx += 256) {
      int r = idx >> 6, cc = idx & 63;
      int hh = rt * 4 - 1 + r;
      float v = 0.f;
      if (hh >= 0 && hh < 64) v = u0[(size_t)i * N_ + hh * 64 + cc];
      tile[idx] = v;
    }
    __syncthreads();
    const float* wli = &wl[i * 9];
#pragma unroll
    for (int ky = 0; ky < 3; ++ky) {
#pragma unroll
      for (int kx = 0; kx < 3; ++kx) {
        int wc = col + kx - 1;
        float v = (wc >= 0 && wc < 64) ? tile[(row + ky) * 64 + wc] : 0.f;
        acc = fmaf(wli[ky * 3 + kx], v, acc);
      }
    }
    accsc = fmaf(scl[i], ob0[(size_t)i * N_ + pix], accsc);
  }
  float branch = acc + ws[C2B_O + o];
  float scv = accsc + ws[SCB_O + o];
  float gv = ws[GO_OFF + (size_t)b * CN + (size_t)o * N_ + pix];
  out[(size_t)b * CN + (size_t)o * N_ + pix] = branch + scv * gv;
}

extern "C" void kernel_launch(void* const* d_in, const int* in_sizes, int n_in,
                              void* d_out, int out_size, void* d_ws, size_t ws_size,
                              hipStream_t stream) {
  const void* x      = d_in[0];
  const void* guide  = d_in[1];
  float* out = (float*)d_out;
  float* ws = (float*)d_ws;

  k_detect<<<64, 256, 0, stream>>>(d_in[0], d_in[2], d_in[3], d_in[4],
                                   d_in[5], d_in[6], d_in[7], d_in[8],
                                   d_in[9], d_in[10], d_in[11], d_in[12],
                                   d_in[13], d_in[14], d_in[15], d_in[16],
                                   d_in[17], d_in[18], d_in[19], d_in[20],
                                   d_in[21], d_in[22], ws);
  k_chattn<<<256, 256, 0, stream>>>(x, guide, ws);
  k_coordconv<<<4096, 256, 0, stream>>>(x, guide, ws);
  k_proj<<<640, 256, 0, stream>>>(ws);
  k_attn<<<512, 256, 0, stream>>>(ws);
  k_merge<<<512, 256, 0, stream>>>(ws);
  k_conv1<<<2048, 256, 0, stream>>>(ws);
  k_final<<<2048, 256, 0, stream>>>(ws, out);
}

// Round 8
// 492.631 us; speedup vs baseline: 6.3005x; 1.1421x over previous
//
#include <hip/hip_runtime.h>
#include <hip/hip_bf16.h>

using bf16 = __hip_bfloat16;

#define DI __device__ __forceinline__

typedef __attribute__((ext_vector_type(8))) short short8;
typedef __attribute__((ext_vector_type(8))) unsigned short u16x8;
typedef __attribute__((ext_vector_type(4))) unsigned short u16x4;
typedef __attribute__((ext_vector_type(4))) float f32x4;

#define MFMA_BF16 __builtin_amdgcn_mfma_f32_16x16x32_bf16

DI float b2f(bf16 v) { return __bfloat162float(v); }
DI float leaky(float x) { return x > 0.f ? x : 0.1f * x; }

// bf16 split helpers (RNE). x = hi + lo to ~2^-16 relative.
DI unsigned short b16(float x) {
  union { float f; unsigned u; } v; v.f = x;
  unsigned r = v.u + 0x7FFFu + ((v.u >> 16) & 1u);
  return (unsigned short)(r >> 16);
}
DI float fromb16(unsigned short h) {
  union { unsigned u; float f; } v; v.u = ((unsigned)h) << 16; return v.f;
}

DI float ldin(const void* p, size_t i, int isbf) {
  return isbf ? b2f(((const bf16*)p)[i]) : ((const float*)p)[i];
}

// Problem constants: B=2, C=64, H=64, W=64, N=4096
static constexpr int N_ = 4096;
static constexpr size_t CN = 262144;
static constexpr size_t BCN = 524288;

// ---- Workspace layout (float indices) ----
static constexpr size_t LW_O = 0, LB_O = 1, GM_O = 2, AL_O = 3;
static constexpr size_t CW_O  = 4;
static constexpr size_t XQW_O = 38020;
static constexpr size_t XQB_O = 42116;
static constexpr size_t XKW_O = 42180;
static constexpr size_t XKB_O = 46276;
static constexpr size_t XVW_O = 46340;
static constexpr size_t XVB_O = 50436;
static constexpr size_t GQW_O = 50500;
static constexpr size_t GQB_O = 54596;
static constexpr size_t GKW_O = 54660;
static constexpr size_t GKB_O = 58756;
static constexpr size_t C1W_O = 58820;
static constexpr size_t C1B_O = 95684;
static constexpr size_t C2W_O = 95748;
static constexpr size_t C2B_O = 132612;
static constexpr size_t SCW_O = 132676;
static constexpr size_t SCB_O = 136772;
static constexpr size_t CA_O  = 136836;
static constexpr size_t FLAG_O = 137092;
static constexpr size_t XG_OFF = 137104;            // xg fp32; then x-attn half0 partial
static constexpr size_t GG_OFF = XG_OFF + BCN;      // gg fp32; then g-attn half0 partial; then GO
static constexpr size_t QX_OFF = GG_OFF + BCN;      // Qx split ushort hi/lo; then OB
static constexpr size_t KX_OFF = QX_OFF + BCN;      // Kx split; then UB
static constexpr size_t VX_OFF = KX_OFF + BCN;      // V split, TRANSPOSED [b][c][n]
static constexpr size_t QG_OFF = VX_OFF + BCN;      // Qg split
static constexpr size_t KG_OFF = QG_OFF + BCN;      // Kg split
static constexpr size_t P1X_OFF = KG_OFF + BCN;
static constexpr size_t P1G_OFF = P1X_OFF + BCN;
static constexpr size_t ML_OFF  = P1G_OFF + BCN;
static constexpr size_t MLL_OFF = ML_OFF + 32768;
static constexpr size_t OB_OFF = QX_OFF;
static constexpr size_t UB_OFF = KX_OFF;
static constexpr size_t GO_OFF = GG_OFF;
// ushort-unit offsets for the split arrays (hi array, then lo array)
static constexpr size_t QXH_U = QX_OFF * 2, QXL_U = QXH_U + BCN;
static constexpr size_t KXH_U = KX_OFF * 2, KXL_U = KXH_U + BCN;
static constexpr size_t VXH_U = VX_OFF * 2, VXL_U = VXH_U + BCN;
static constexpr size_t QGH_U = QG_OFF * 2, QGL_U = QGH_U + BCN;
static constexpr size_t KGH_U = KG_OFF * 2, KGL_U = KGH_U + BCN;
// Peak: MLL_OFF + 32768 = 19.7 MB (validated R6/R7)

// ---------------- K0: dtype detect + param conversion ----------------
__global__ __launch_bounds__(256) void k_detect(
    const void* x, const void* lw, const void* lb, const void* cw,
    const void* xqw, const void* xqb, const void* xkw, const void* xkb,
    const void* xvw, const void* xvb, const void* gqw, const void* gqb,
    const void* gkw, const void* gkb, const void* gm, const void* al,
    const void* c1w, const void* c1b, const void* c2w, const void* c2b,
    const void* scw, const void* scb, float* ws) {
  __shared__ int sred[256];
  int t = threadIdx.x;
  const unsigned short* u = (const unsigned short*)x;
  int e = (u[t * 2] >> 7) & 0xFF;
  sred[t] = (e >= 117 && e <= 130) ? 1 : 0;
  __syncthreads();
  for (int off = 128; off; off >>= 1) {
    if (t < off) sred[t] += sred[t + off];
    __syncthreads();
  }
  int isbf = sred[0] > 128 ? 1 : 0;
  if (blockIdx.x == 0 && t == 0) ((int*)ws)[FLAG_O] = isbf;
  int gid = blockIdx.x * 256 + t;
  int stride = gridDim.x * 256;
  for (int i = gid; i < 136836; i += stride) {
    const void* p; int rel;
    if (i < 4)               { p = (i == 0 ? lw : i == 1 ? lb : i == 2 ? gm : al); rel = 0; }
    else if (i < (int)XQW_O) { p = cw;  rel = i - (int)CW_O; }
    else if (i < (int)XQB_O) { p = xqw; rel = i - (int)XQW_O; }
    else if (i < (int)XKW_O) { p = xqb; rel = i - (int)XQB_O; }
    else if (i < (int)XKB_O) { p = xkw; rel = i - (int)XKW_O; }
    else if (i < (int)XVW_O) { p = xkb; rel = i - (int)XKB_O; }
    else if (i < (int)XVB_O) { p = xvw; rel = i - (int)XVW_O; }
    else if (i < (int)GQW_O) { p = xvb; rel = i - (int)XVB_O; }
    else if (i < (int)GQB_O) { p = gqw; rel = i - (int)GQW_O; }
    else if (i < (int)GKW_O) { p = gqb; rel = i - (int)GQB_O; }
    else if (i < (int)GKB_O) { p = gkw; rel = i - (int)GKW_O; }
    else if (i < (int)C1W_O) { p = gkb; rel = i - (int)GKB_O; }
    else if (i < (int)C1B_O) { p = c1w; rel = i - (int)C1W_O; }
    else if (i < (int)C2W_O) { p = c1b; rel = i - (int)C1B_O; }
    else if (i < (int)C2B_O) { p = c2w; rel = i - (int)C2W_O; }
    else if (i < (int)SCW_O) { p = c2b; rel = i - (int)C2B_O; }
    else if (i < (int)SCB_O) { p = scw; rel = i - (int)SCW_O; }
    else                     { p = scb; rel = i - (int)SCB_O; }
    ws[i] = ldin(p, rel, isbf);
  }
}

// ---------------- K1: channel attention scalars ----------------
__global__ __launch_bounds__(256) void k_chattn(const void* __restrict__ x,
                                                const void* __restrict__ g,
                                                float* __restrict__ ws) {
  int isbf = ((const int*)ws)[FLAG_O];
  int blk = blockIdx.x;
  int src = blk >> 7;
  int rem = blk & 127;
  int b = rem >> 6, c = rem & 63;
  const void* base = src ? g : x;
  size_t off0 = ((size_t)(b * 64 + c)) * N_;
  float s = 0.f;
  for (int i = threadIdx.x; i < N_; i += 256) s += ldin(base, off0 + i, isbf);
  __shared__ float red[256];
  red[threadIdx.x] = s;
  __syncthreads();
  for (int off = 128; off; off >>= 1) {
    if (threadIdx.x < off) red[threadIdx.x] += red[threadIdx.x + off];
    __syncthreads();
  }
  if (threadIdx.x == 0) {
    float p = red[0] * (1.f / (float)N_);
    float lw = ws[LW_O], lb = ws[LB_O];
    float h = leaky(lw * p + lb);
    float z = lw * h + lb;
    ws[CA_O + src * 128 + b * 64 + c] = 1.f / (1.f + expf(-z));
  }
}

// ---------------- K2: coord-conv 3x3, 4 output channels per block ----------------
__global__ __launch_bounds__(256) void k_coordconv(const void* __restrict__ x,
                                                   const void* __restrict__ g,
                                                   float* __restrict__ ws) {
  int isbf = ((const int*)ws)[FLAG_O];
  int blk = blockIdx.x;  // 1024 = src*512 + b*256 + og*16 + rt
  int rt = blk & 15; blk >>= 4;
  int og = blk & 15; blk >>= 4;
  int b  = blk & 1;  blk >>= 1;
  int src = blk;
  int o0 = og * 4;
  const void* in = src ? g : x;
  float* outp = ws + (src ? GG_OFF : XG_OFF);
  __shared__ __align__(16) float wl[2376];   // [ch][oo][tap]
  __shared__ float tile[384];
  int t = threadIdx.x;
  for (int idx = t; idx < 2376; idx += 256) {
    int ch = idx / 36, r = idx % 36;
    int oo = r / 9, k = r % 9;
    wl[idx] = ws[CW_O + (size_t)(o0 + oo) * 594 + ch * 9 + k];
  }
  int row = t >> 6, col = t & 63;
  int h = rt * 4 + row;
  float acc0 = 0.f, acc1 = 0.f, acc2 = 0.f, acc3 = 0.f;
  for (int ch = 0; ch < 66; ++ch) {
    __syncthreads();
    for (int idx = t; idx < 384; idx += 256) {
      int r = idx >> 6, cc = idx & 63;
      int hh = rt * 4 - 1 + r;
      float v = 0.f;
      if (hh >= 0 && hh < 64) {
        if (ch < 64)       v = ldin(in, ((size_t)(b * 64 + ch)) * N_ + hh * 64 + cc, isbf);
        else if (ch == 64) v = (float)cc * (2.f / 63.f) - 1.f;
        else               v = (float)hh * (2.f / 63.f) - 1.f;
      }
      tile[idx] = v;
    }
    __syncthreads();
    float t9[9];
#pragma unroll
    for (int ky = 0; ky < 3; ++ky)
#pragma unroll
      for (int kx = 0; kx < 3; ++kx) {
        int wc = col + kx - 1;
        t9[ky * 3 + kx] = (wc >= 0 && wc < 64) ? tile[(row + ky) * 64 + wc] : 0.f;
      }
    float w36[36];
    const float4* wp = reinterpret_cast<const float4*>(&wl[ch * 36]);
#pragma unroll
    for (int i = 0; i < 9; ++i) {
      float4 v = wp[i];
      w36[i * 4] = v.x; w36[i * 4 + 1] = v.y; w36[i * 4 + 2] = v.z; w36[i * 4 + 3] = v.w;
    }
#pragma unroll
    for (int k = 0; k < 9; ++k) {
      acc0 = fmaf(w36[k], t9[k], acc0);
      acc1 = fmaf(w36[9 + k], t9[k], acc1);
      acc2 = fmaf(w36[18 + k], t9[k], acc2);
      acc3 = fmaf(w36[27 + k], t9[k], acc3);
    }
  }
  size_t pix = (size_t)h * 64 + col;
  const float* cav = ws + CA_O + src * 128 + b * 64 + o0;
  outp[((size_t)(b * 64 + o0 + 0)) * N_ + pix] = cav[0] * acc0;
  outp[((size_t)(b * 64 + o0 + 1)) * N_ + pix] = cav[1] * acc1;
  outp[((size_t)(b * 64 + o0 + 2)) * N_ + pix] = cav[2] * acc2;
  outp[((size_t)(b * 64 + o0 + 3)) * N_ + pix] = cav[3] * acc3;
}

// ---------------- K3: 1x1 projections; outputs pre-split bf16 hi/lo ----------------
__global__ __launch_bounds__(256) void k_proj(float* __restrict__ ws) {
  int blk = blockIdx.x;  // 5 * 2 * 64
  int pt = blk & 63; blk >>= 6;
  int b  = blk & 1;  blk >>= 1;
  int which = blk;
  size_t in_o, w_o, b_o;
  size_t hU = 0, lU = 0;
  if (which == 0)      { in_o = XG_OFF; w_o = XQW_O; b_o = XQB_O; hU = QXH_U; lU = QXL_U; }
  else if (which == 1) { in_o = XG_OFF; w_o = XKW_O; b_o = XKB_O; hU = KXH_U; lU = KXL_U; }
  else if (which == 2) { in_o = XG_OFF; w_o = XVW_O; b_o = XVB_O; }
  else if (which == 3) { in_o = GG_OFF; w_o = GQW_O; b_o = GQB_O; hU = QGH_U; lU = QGL_U; }
  else                 { in_o = GG_OFF; w_o = GKW_O; b_o = GKB_O; hU = KGH_U; lU = KGL_U; }

  __shared__ float tile[64 * 64];
  __shared__ float wl[64 * 65];
  __shared__ float bl[64];
  unsigned short* us = (unsigned short*)ws;
  int t = threadIdx.x;
  int pb = pt * 64;
  const float* in0 = ws + in_o + (size_t)b * CN + pb;
  for (int c0 = (t >> 6); c0 < 64; c0 += 4)
    tile[c0 * 64 + (t & 63)] = in0[(size_t)c0 * N_ + (t & 63)];
  for (int idx = t; idx < 4096; idx += 256)
    wl[(idx >> 6) * 65 + (idx & 63)] = ws[w_o + idx];
  if (t < 64) bl[t] = ws[b_o + t];
  __syncthreads();
  int o = t & 63, grp = t >> 6;
  const float* wr = &wl[o * 65];
  float acc[16];
  float bv = bl[o];
#pragma unroll
  for (int j = 0; j < 16; ++j) acc[j] = bv;
  for (int c = 0; c < 64; ++c) {
    float wv = wr[c];
    const float4* tb = reinterpret_cast<const float4*>(&tile[c * 64 + grp * 16]);
    float4 t0 = tb[0], t1 = tb[1], t2 = tb[2], t3 = tb[3];
    acc[0] = fmaf(wv, t0.x, acc[0]);   acc[1] = fmaf(wv, t0.y, acc[1]);
    acc[2] = fmaf(wv, t0.z, acc[2]);   acc[3] = fmaf(wv, t0.w, acc[3]);
    acc[4] = fmaf(wv, t1.x, acc[4]);   acc[5] = fmaf(wv, t1.y, acc[5]);
    acc[6] = fmaf(wv, t1.z, acc[6]);   acc[7] = fmaf(wv, t1.w, acc[7]);
    acc[8] = fmaf(wv, t2.x, acc[8]);   acc[9] = fmaf(wv, t2.y, acc[9]);
    acc[10] = fmaf(wv, t2.z, acc[10]); acc[11] = fmaf(wv, t2.w, acc[11]);
    acc[12] = fmaf(wv, t3.x, acc[12]); acc[13] = fmaf(wv, t3.y, acc[13]);
    acc[14] = fmaf(wv, t3.z, acc[14]); acc[15] = fmaf(wv, t3.w, acc[15]);
  }
  if (which != 2) {
#pragma unroll
    for (int j = 0; j < 16; ++j) {
      size_t idx = ((size_t)b * N_ + pb + grp * 16 + j) * 64 + o;
      unsigned short hi = b16(acc[j]);
      us[hU + idx] = hi;
      us[lU + idx] = b16(acc[j] - fromb16(hi));
    }
  } else {
    // V: retranspose via LDS, split, write [b][c][n] hi/lo
    __syncthreads();
    float* ot = wl;
#pragma unroll
    for (int j = 0; j < 16; ++j) ot[o * 65 + grp * 16 + j] = acc[j];
    __syncthreads();
    int o2 = t >> 2;
#pragma unroll
    for (int e = 0; e < 4; ++e) {
      int px = (t & 3) * 16 + e * 4;
      u16x4 hv, lv;
#pragma unroll
      for (int q = 0; q < 4; ++q) {
        float v = ot[o2 * 65 + px + q];
        unsigned short hi = b16(v);
        hv[q] = hi; lv[q] = b16(v - fromb16(hi));
      }
      size_t idx = ((size_t)(b * 64 + o2)) * N_ + pb + px;
      *reinterpret_cast<u16x4*>(&us[VXH_U + idx]) = hv;
      *reinterpret_cast<u16x4*>(&us[VXL_U + idx]) = lv;
    }
  }
}

// ---------------- K4: MFMA flash attention (pre-split inputs) ----------------
__global__ __launch_bounds__(256) void k_attn(float* __restrict__ ws) {
  unsigned short* us = (unsigned short*)ws;
  int blk = blockIdx.x;
  int half = blk & 1; blk >>= 1;
  int qt = blk & 63;  blk >>= 6;
  int b  = blk & 1;   blk >>= 1;
  int at = blk;
  const unsigned short* QH = us + (at ? QGH_U : QXH_U);
  const unsigned short* QL = us + (at ? QGL_U : QXL_U);
  const unsigned short* KHg = us + (at ? KGH_U : KXH_U);
  const unsigned short* KLg = us + (at ? KGL_U : KXL_U);
  const unsigned short* VHg = us + VXH_U;
  const unsigned short* VLg = us + VXL_U;
  float* Pg = ws + (at ? (half ? P1G_OFF : GG_OFF) : (half ? P1X_OFF : XG_OFF))
            + (size_t)b * CN + qt * 64;

  __shared__ unsigned short Kh[4096], Kl[4096], Vth[4096], Vtl[4096], Ph[4096], Pl[4096];
  __shared__ float sAl[64];

  int t = threadIdx.x;
  int w = t >> 6, lane = t & 63, quad = lane >> 4, l15 = lane & 15;
  int swz = l15 & 7;

  short8 qh[2], ql[2];
  {
    size_t qbase = ((size_t)b * N_ + qt * 64 + 16 * w + l15) * 64;
#pragma unroll
    for (int ks = 0; ks < 2; ++ks) {
      qh[ks] = *reinterpret_cast<const short8*>(&QH[qbase + ks * 32 + quad * 8]);
      ql[ks] = *reinterpret_cast<const short8*>(&QL[qbase + ks * 32 + quad * 8]);
    }
  }

  f32x4 Oa[4] = {{0.f, 0.f, 0.f, 0.f}, {0.f, 0.f, 0.f, 0.f},
                 {0.f, 0.f, 0.f, 0.f}, {0.f, 0.f, 0.f, 0.f}};
  float M[4] = {-1e30f, -1e30f, -1e30f, -1e30f};
  float L[4] = {0.f, 0.f, 0.f, 0.f};

  for (int mt = half * 32; mt < half * 32 + 32; ++mt) {
    __syncthreads();
#pragma unroll
    for (int it = 0; it < 2; ++it) {
      int f8 = it * 256 + t;
      int r = f8 >> 3, ch = f8 & 7;
      int off = r * 64 + ((ch ^ (r & 7)) << 3);
      size_t kgi = ((size_t)b * N_ + mt * 64 + r) * 64 + ch * 8;
      *reinterpret_cast<u16x8*>(&Kh[off]) = *reinterpret_cast<const u16x8*>(&KHg[kgi]);
      *reinterpret_cast<u16x8*>(&Kl[off]) = *reinterpret_cast<const u16x8*>(&KLg[kgi]);
      size_t vgi = ((size_t)(b * 64 + r)) * N_ + mt * 64 + ch * 8;
      *reinterpret_cast<u16x8*>(&Vth[off]) = *reinterpret_cast<const u16x8*>(&VHg[vgi]);
      *reinterpret_cast<u16x8*>(&Vtl[off]) = *reinterpret_cast<const u16x8*>(&VLg[vgi]);
    }
    __syncthreads();

    // ---- S = Q K^T ----
    f32x4 S[4];
#pragma unroll
    for (int ms = 0; ms < 4; ++ms) {
      f32x4 acc = {0.f, 0.f, 0.f, 0.f};
#pragma unroll
      for (int ks = 0; ks < 2; ++ks) {
        int row = ms * 16 + l15;
        int off = row * 64 + (((ks * 4 + quad) ^ swz) << 3);
        short8 khf = *reinterpret_cast<const short8*>(&Kh[off]);
        short8 klf = *reinterpret_cast<const short8*>(&Kl[off]);
        acc = MFMA_BF16(ql[ks], khf, acc, 0, 0, 0);
        acc = MFMA_BF16(qh[ks], klf, acc, 0, 0, 0);
        acc = MFMA_BF16(qh[ks], khf, acc, 0, 0, 0);
      }
      S[ms] = acc;
    }

    // ---- online softmax ----
    float alpha[4];
#pragma unroll
    for (int r = 0; r < 4; ++r) {
      float tm = fmaxf(fmaxf(S[0][r], S[1][r]), fmaxf(S[2][r], S[3][r]));
#pragma unroll
      for (int d = 1; d < 16; d <<= 1) tm = fmaxf(tm, __shfl_xor(tm, d, 16));
      float mn = fmaxf(M[r], tm);
      float al = __expf(M[r] - mn);
      float ts = 0.f;
      float p[4];
#pragma unroll
      for (int ms = 0; ms < 4; ++ms) { p[ms] = __expf(S[ms][r] - mn); ts += p[ms]; }
#pragma unroll
      for (int d = 1; d < 16; d <<= 1) ts += __shfl_xor(ts, d, 16);
      L[r] = L[r] * al + ts;
      M[r] = mn;
      alpha[r] = al;
      int n = 16 * w + quad * 4 + r;
#pragma unroll
      for (int ms = 0; ms < 4; ++ms) {
        int m = ms * 16 + l15;
        int off = n * 64 + (((m >> 3) ^ (n & 7)) << 3) + (m & 7);
        unsigned short h = b16(p[ms]);
        unsigned short lo = b16(p[ms] - fromb16(h));
        Ph[off] = h; Pl[off] = lo;
      }
    }
    if (l15 < 4) {
      float av = (l15 == 0) ? alpha[0] : (l15 == 1) ? alpha[1] : (l15 == 2) ? alpha[2] : alpha[3];
      sAl[16 * w + quad * 4 + l15] = av;
    }
    float av = sAl[16 * w + l15];
#pragma unroll
    for (int cs = 0; cs < 4; ++cs) {
      Oa[cs][0] *= av; Oa[cs][1] *= av; Oa[cs][2] *= av; Oa[cs][3] *= av;
    }

    // ---- O^T += V^T P^T ----
#pragma unroll
    for (int cs = 0; cs < 4; ++cs) {
      f32x4 acc = Oa[cs];
#pragma unroll
      for (int ks = 0; ks < 2; ++ks) {
        int vrow = cs * 16 + l15;
        int voff = vrow * 64 + (((ks * 4 + quad) ^ swz) << 3);
        short8 vhf = *reinterpret_cast<const short8*>(&Vth[voff]);
        short8 vlf = *reinterpret_cast<const short8*>(&Vtl[voff]);
        int prow = 16 * w + l15;
        int poff = prow * 64 + (((ks * 4 + quad) ^ swz) << 3);
        short8 phf = *reinterpret_cast<const short8*>(&Ph[poff]);
        short8 plf = *reinterpret_cast<const short8*>(&Pl[poff]);
        acc = MFMA_BF16(vlf, phf, acc, 0, 0, 0);
        acc = MFMA_BF16(vhf, plf, acc, 0, 0, 0);
        acc = MFMA_BF16(vhf, phf, acc, 0, 0, 0);
      }
      Oa[cs] = acc;
    }
  }

#pragma unroll
  for (int cs = 0; cs < 4; ++cs) {
#pragma unroll
    for (int r = 0; r < 4; ++r) {
      int c = cs * 16 + quad * 4 + r;
      Pg[(size_t)c * N_ + 16 * w + l15] = Oa[cs][r];
    }
  }
  if (l15 < 4) {
    float Mv = (l15 == 0) ? M[0] : (l15 == 1) ? M[1] : (l15 == 2) ? M[2] : M[3];
    float Lv = (l15 == 0) ? L[0] : (l15 == 1) ? L[1] : (l15 == 2) ? L[2] : L[3];
    int mlb = ((at * 2 + half) * 2 + b) * 4096 + qt * 64 + 16 * w + quad * 4 + l15;
    ws[ML_OFF + mlb] = Mv;
    ws[MLL_OFF + mlb] = Lv;
  }
}

// ---------------- K5: merge halves + combine ----------------
__global__ __launch_bounds__(256) void k_merge(float* __restrict__ ws) {
  size_t i4 = (size_t)blockIdx.x * 256 + threadIdx.x;
  size_t i = i4 * 4;
  int n = (int)(i & 4095);
  int b = (int)(i >> 18);
  float gm = ws[GM_O], al = ws[AL_O];
  float4 p0x = *reinterpret_cast<const float4*>(ws + XG_OFF + i);
  float4 p1x = *reinterpret_cast<const float4*>(ws + P1X_OFF + i);
  float4 p0g = *reinterpret_cast<const float4*>(ws + GG_OFF + i);
  float4 p1g = *reinterpret_cast<const float4*>(ws + P1G_OFF + i);
  float4 M0x = *reinterpret_cast<const float4*>(ws + ML_OFF  + (0 + b) * 4096 + n);
  float4 L0x = *reinterpret_cast<const float4*>(ws + MLL_OFF + (0 + b) * 4096 + n);
  float4 M1x = *reinterpret_cast<const float4*>(ws + ML_OFF  + (2 + b) * 4096 + n);
  float4 L1x = *reinterpret_cast<const float4*>(ws + MLL_OFF + (2 + b) * 4096 + n);
  float4 M0g = *reinterpret_cast<const float4*>(ws + ML_OFF  + (4 + b) * 4096 + n);
  float4 L0g = *reinterpret_cast<const float4*>(ws + MLL_OFF + (4 + b) * 4096 + n);
  float4 M1g = *reinterpret_cast<const float4*>(ws + ML_OFF  + (6 + b) * 4096 + n);
  float4 L1g = *reinterpret_cast<const float4*>(ws + MLL_OFF + (6 + b) * 4096 + n);
  const float* p0xv = (const float*)&p0x; const float* p1xv = (const float*)&p1x;
  const float* p0gv = (const float*)&p0g; const float* p1gv = (const float*)&p1g;
  const float* m0xv = (const float*)&M0x; const float* l0xv = (const float*)&L0x;
  const float* m1xv = (const float*)&M1x; const float* l1xv = (const float*)&L1x;
  const float* m0gv = (const float*)&M0g; const float* l0gv = (const float*)&L0g;
  const float* m1gv = (const float*)&M1g; const float* l1gv = (const float*)&L1g;
  float4 go, ob;
  float* gov = (float*)&go; float* obv = (float*)&ob;
#pragma unroll
  for (int l = 0; l < 4; ++l) {
    float mx = fmaxf(m0xv[l], m1xv[l]);
    float w0 = __expf(m0xv[l] - mx), w1 = __expf(m1xv[l] - mx);
    float xc = (p0xv[l] * w0 + p1xv[l] * w1) / (l0xv[l] * w0 + l1xv[l] * w1);
    float mg = fmaxf(m0gv[l], m1gv[l]);
    float v0 = __expf(m0gv[l] - mg), v1 = __expf(m1gv[l] - mg);
    float gc = (p0gv[l] * v0 + p1gv[l] * v1) / (l0gv[l] * v0 + l1gv[l] * v1);
    gov[l] = gc;
    obv[l] = gm * xc + al * gc;
  }
  *reinterpret_cast<float4*>(ws + GG_OFF + i) = go;  // GO
  *reinterpret_cast<float4*>(ws + QX_OFF + i) = ob;  // OB
}

// ---------------- K6: u = leaky(conv3x3(leaky(out), c1)), 4 o per block ----------------
__global__ __launch_bounds__(256) void k_conv1(float* __restrict__ ws) {
  int blk = blockIdx.x;  // 512 = b*256 + og*16 + rt
  int rt = blk & 15; blk >>= 4;
  int og = blk & 15; blk >>= 4;
  int b  = blk;
  int o0 = og * 4;
  __shared__ __align__(16) float wl[2304];
  __shared__ float tile[384];
  int t = threadIdx.x;
  for (int idx = t; idx < 2304; idx += 256) {
    int ch = idx / 36, r = idx % 36;
    int oo = r / 9, k = r % 9;
    wl[idx] = ws[C1W_O + (size_t)(o0 + oo) * 576 + ch * 9 + k];
  }
  int row = t >> 6, col = t & 63;
  int h = rt * 4 + row;
  float acc0 = 0.f, acc1 = 0.f, acc2 = 0.f, acc3 = 0.f;
  const float* in0 = ws + OB_OFF + (size_t)b * CN;
  for (int ch = 0; ch < 64; ++ch) {
    __syncthreads();
    for (int idx = t; idx < 384; idx += 256) {
      int r = idx >> 6, cc = idx & 63;
      int hh = rt * 4 - 1 + r;
      float v = 0.f;
      if (hh >= 0 && hh < 64) v = leaky(in0[(size_t)ch * N_ + hh * 64 + cc]);
      tile[idx] = v;
    }
    __syncthreads();
    float t9[9];
#pragma unroll
    for (int ky = 0; ky < 3; ++ky)
#pragma unroll
      for (int kx = 0; kx < 3; ++kx) {
        int wc = col + kx - 1;
        t9[ky * 3 + kx] = (wc >= 0 && wc < 64) ? tile[(row + ky) * 64 + wc] : 0.f;
      }
    float w36[36];
    const float4* wp = reinterpret_cast<const float4*>(&wl[ch * 36]);
#pragma unroll
    for (int i = 0; i < 9; ++i) {
      float4 v = wp[i];
      w36[i * 4] = v.x; w36[i * 4 + 1] = v.y; w36[i * 4 + 2] = v.z; w36[i * 4 + 3] = v.w;
    }
#pragma unroll
    for (int k = 0; k < 9; ++k) {
      acc0 = fmaf(w36[k], t9[k], acc0);
      acc1 = fmaf(w36[9 + k], t9[k], acc1);
      acc2 = fmaf(w36[18 + k], t9[k], acc2);
      acc3 = fmaf(w36[27 + k], t9[k], acc3);
    }
  }
  size_t pix = (size_t)h * 64 + col;
  float* ub = ws + UB_OFF + (size_t)b * CN;
  ub[(size_t)(o0 + 0) * N_ + pix] = leaky(acc0 + ws[C1B_O + o0 + 0]);
  ub[(size_t)(o0 + 1) * N_ + pix] = leaky(acc1 + ws[C1B_O + o0 + 1]);
  ub[(size_t)(o0 + 2) * N_ + pix] = leaky(acc2 + ws[C1B_O + o0 + 2]);
  ub[(size_t)(o0 + 3) * N_ + pix] = leaky(acc3 + ws[C1B_O + o0 + 3]);
}

// ---------------- K7: final, 4 o per block ----------------
__global__ __launch_bounds__(256) void k_final(const float* __restrict__ ws,
                                               float* __restrict__ out) {
  int blk = blockIdx.x;  // 512 = b*256 + og*16 + rt
  int rt = blk & 15; blk >>= 4;
  int og = blk & 15; blk >>= 4;
  int b  = blk;
  int o0 = og * 4;
  __shared__ __align__(16) float wl[2304];
  __shared__ __align__(16) float scl[256];   // [ch][oo]
  __shared__ float tile[384];
  int t = threadIdx.x;
  for (int idx = t; idx < 2304; idx += 256) {
    int ch = idx / 36, r = idx % 36;
    int oo = r / 9, k = r % 9;
    wl[idx] = ws[C2W_O + (size_t)(o0 + oo) * 576 + ch * 9 + k];
  }
  {
    int oo = t & 3, ch = t >> 2;
    scl[ch * 4 + oo] = ws[SCW_O + (size_t)(o0 + oo) * 64 + ch];
  }
  int row = t >> 6, col = t & 63;
  int h = rt * 4 + row;
  size_t pix = (size_t)h * 64 + col;
  float acc0 = 0.f, acc1 = 0.f, acc2 = 0.f, acc3 = 0.f;
  float sc0 = 0.f, sc1 = 0.f, sc2 = 0.f, sc3 = 0.f;
  const float* u0 = ws + UB_OFF + (size_t)b * CN;
  const float* ob0 = ws + OB_OFF + (size_t)b * CN;
  for (int ch = 0; ch < 64; ++ch) {
    __syncthreads();
    for (int idx = t; idx < 384; idx += 256) {
      int r = idx >> 6, cc = idx & 63;
      int hh = rt * 4 - 1 + r;
      float v = 0.f;
      if (hh >= 0 && hh < 64) v = u0[(size_t)ch * N_ + hh * 64 + cc];
      tile[idx] = v;
    }
    __syncthreads();
    float t9[9];
#pragma unroll
    for (int ky = 0; ky < 3; ++ky)
#pragma unroll
      for (int kx = 0; kx < 3; ++kx) {
        int wc = col + kx - 1;
        t9[ky * 3 + kx] = (wc >= 0 && wc < 64) ? tile[(row + ky) * 64 + wc] : 0.f;
      }
    float w36[36];
    const float4* wp = reinterpret_cast<const float4*>(&wl[ch * 36]);
#pragma unroll
    for (int i = 0; i < 9; ++i) {
      float4 v = wp[i];
      w36[i * 4] = v.x; w36[i * 4 + 1] = v.y; w36[i * 4 + 2] = v.z; w36[i * 4 + 3] = v.w;
    }
#pragma unroll
    for (int k = 0; k < 9; ++k) {
      acc0 = fmaf(w36[k], t9[k], acc0);
      acc1 = fmaf(w36[9 + k], t9[k], acc1);
      acc2 = fmaf(w36[18 + k], t9[k], acc2);
      acc3 = fmaf(w36[27 + k], t9[k], acc3);
    }
    float obv = ob0[(size_t)ch * N_ + pix];
    float4 s4 = *reinterpret_cast<const float4*>(&scl[ch * 4]);
    sc0 = fmaf(s4.x, obv, sc0);
    sc1 = fmaf(s4.y, obv, sc1);
    sc2 = fmaf(s4.z, obv, sc2);
    sc3 = fmaf(s4.w, obv, sc3);
  }
  const float* go = ws + GO_OFF + (size_t)b * CN;
  float* ob = out + (size_t)b * CN;
  {
    float br = acc0 + ws[C2B_O + o0 + 0], sv = sc0 + ws[SCB_O + o0 + 0];
    ob[(size_t)(o0 + 0) * N_ + pix] = br + sv * go[(size_t)(o0 + 0) * N_ + pix];
  }
  {
    float br = acc1 + ws[C2B_O + o0 + 1], sv = sc1 + ws[SCB_O + o0 + 1];
    ob[(size_t)(o0 + 1) * N_ + pix] = br + sv * go[(size_t)(o0 + 1) * N_ + pix];
  }
  {
    float br = acc2 + ws[C2B_O + o0 + 2], sv = sc2 + ws[SCB_O + o0 + 2];
    ob[(size_t)(o0 + 2) * N_ + pix] = br + sv * go[(size_t)(o0 + 2) * N_ + pix];
  }
  {
    float br = acc3 + ws[C2B_O + o0 + 3], sv = sc3 + ws[SCB_O + o0 + 3];
    ob[(size_t)(o0 + 3) * N_ + pix] = br + sv * go[(size_t)(o0 + 3) * N_ + pix];
  }
}

extern "C" void kernel_launch(void* const* d_in, const int* in_sizes, int n_in,
                              void* d_out, int out_size, void* d_ws, size_t ws_size,
                              hipStream_t stream) {
  const void* x      = d_in[0];
  const void* guide  = d_in[1];
  float* out = (float*)d_out;
  float* ws = (float*)d_ws;

  k_detect<<<64, 256, 0, stream>>>(d_in[0], d_in[2], d_in[3], d_in[4],
                                   d_in[5], d_in[6], d_in[7], d_in[8],
                                   d_in[9], d_in[10], d_in[11], d_in[12],
                                   d_in[13], d_in[14], d_in[15], d_in[16],
                                   d_in[17], d_in[18], d_in[19], d_in[20],
                                   d_in[21], d_in[22], ws);
  k_chattn<<<256, 256, 0, stream>>>(x, guide, ws);
  k_coordconv<<<1024, 256, 0, stream>>>(x, guide, ws);
  k_proj<<<640, 256, 0, stream>>>(ws);
  k_attn<<<512, 256, 0, stream>>>(ws);
  k_merge<<<512, 256, 0, stream>>>(ws);
  k_conv1<<<512, 256, 0, stream>>>(ws);
  k_final<<<512, 256, 0, stream>>>(ws, out);
}

// Round 9
// 449.705 us; speedup vs baseline: 6.9019x; 1.0955x over previous
//
#include <hip/hip_runtime.h>
#include <hip/hip_bf16.h>

using bf16 = __hip_bfloat16;

#define DI __device__ __forceinline__

typedef __attribute__((ext_vector_type(8))) short short8;
typedef __attribute__((ext_vector_type(8))) unsigned short u16x8;
typedef __attribute__((ext_vector_type(4))) unsigned short u16x4;
typedef __attribute__((ext_vector_type(4))) float f32x4;

#define MFMA_BF16 __builtin_amdgcn_mfma_f32_16x16x32_bf16

DI float b2f(bf16 v) { return __bfloat162float(v); }
DI float leaky(float x) { return x > 0.f ? x : 0.1f * x; }

// bf16 split helpers (RNE). x = hi + lo to ~2^-16 relative.
DI unsigned short b16(float x) {
  union { float f; unsigned u; } v; v.f = x;
  unsigned r = v.u + 0x7FFFu + ((v.u >> 16) & 1u);
  return (unsigned short)(r >> 16);
}
DI float fromb16(unsigned short h) {
  union { unsigned u; float f; } v; v.u = ((unsigned)h) << 16; return v.f;
}

DI float ldin(const void* p, size_t i, int isbf) {
  return isbf ? b2f(((const bf16*)p)[i]) : ((const float*)p)[i];
}

// Problem constants: B=2, C=64, H=64, W=64, N=4096
static constexpr int N_ = 4096;
static constexpr size_t CN = 262144;
static constexpr size_t BCN = 524288;

// ---- Workspace layout (float indices) ----
static constexpr size_t LW_O = 0, LB_O = 1, GM_O = 2, AL_O = 3;
static constexpr size_t CW_O  = 4;
static constexpr size_t XQW_O = 38020;
static constexpr size_t XQB_O = 42116;
static constexpr size_t XKW_O = 42180;
static constexpr size_t XKB_O = 46276;
static constexpr size_t XVW_O = 46340;
static constexpr size_t XVB_O = 50436;
static constexpr size_t GQW_O = 50500;
static constexpr size_t GQB_O = 54596;
static constexpr size_t GKW_O = 54660;
static constexpr size_t GKB_O = 58756;
static constexpr size_t C1W_O = 58820;
static constexpr size_t C1B_O = 95684;
static constexpr size_t C2W_O = 95748;
static constexpr size_t C2B_O = 132612;
static constexpr size_t SCW_O = 132676;
static constexpr size_t SCB_O = 136772;
static constexpr size_t CA_O  = 136836;
static constexpr size_t FLAG_O = 137092;
static constexpr size_t XG_OFF = 137104;
static constexpr size_t GG_OFF = XG_OFF + BCN;
static constexpr size_t QX_OFF = GG_OFF + BCN;
static constexpr size_t KX_OFF = QX_OFF + BCN;
static constexpr size_t VX_OFF = KX_OFF + BCN;
static constexpr size_t QG_OFF = VX_OFF + BCN;
static constexpr size_t KG_OFF = QG_OFF + BCN;
static constexpr size_t P1X_OFF = KG_OFF + BCN;
static constexpr size_t P1G_OFF = P1X_OFF + BCN;
static constexpr size_t ML_OFF  = P1G_OFF + BCN;
static constexpr size_t MLL_OFF = ML_OFF + 32768;
static constexpr size_t OB_OFF = QX_OFF;
static constexpr size_t UB_OFF = KX_OFF;
static constexpr size_t GO_OFF = GG_OFF;
static constexpr size_t QXH_U = QX_OFF * 2, QXL_U = QXH_U + BCN;
static constexpr size_t KXH_U = KX_OFF * 2, KXL_U = KXH_U + BCN;
static constexpr size_t VXH_U = VX_OFF * 2, VXL_U = VXH_U + BCN;
static constexpr size_t QGH_U = QG_OFF * 2, QGL_U = QGH_U + BCN;
static constexpr size_t KGH_U = KG_OFF * 2, KGL_U = KGH_U + BCN;
// Peak 19.7 MB (validated R6-R8)

// ---------------- K0: dtype detect + param conversion ----------------
__global__ __launch_bounds__(256) void k_detect(
    const void* x, const void* lw, const void* lb, const void* cw,
    const void* xqw, const void* xqb, const void* xkw, const void* xkb,
    const void* xvw, const void* xvb, const void* gqw, const void* gqb,
    const void* gkw, const void* gkb, const void* gm, const void* al,
    const void* c1w, const void* c1b, const void* c2w, const void* c2b,
    const void* scw, const void* scb, float* ws) {
  __shared__ int sred[256];
  int t = threadIdx.x;
  const unsigned short* u = (const unsigned short*)x;
  int e = (u[t * 2] >> 7) & 0xFF;
  sred[t] = (e >= 117 && e <= 130) ? 1 : 0;
  __syncthreads();
  for (int off = 128; off; off >>= 1) {
    if (t < off) sred[t] += sred[t + off];
    __syncthreads();
  }
  int isbf = sred[0] > 128 ? 1 : 0;
  if (blockIdx.x == 0 && t == 0) ((int*)ws)[FLAG_O] = isbf;
  int gid = blockIdx.x * 256 + t;
  int stride = gridDim.x * 256;
  for (int i = gid; i < 136836; i += stride) {
    const void* p; int rel;
    if (i < 4)               { p = (i == 0 ? lw : i == 1 ? lb : i == 2 ? gm : al); rel = 0; }
    else if (i < (int)XQW_O) { p = cw;  rel = i - (int)CW_O; }
    else if (i < (int)XQB_O) { p = xqw; rel = i - (int)XQW_O; }
    else if (i < (int)XKW_O) { p = xqb; rel = i - (int)XQB_O; }
    else if (i < (int)XKB_O) { p = xkw; rel = i - (int)XKW_O; }
    else if (i < (int)XVW_O) { p = xkb; rel = i - (int)XKB_O; }
    else if (i < (int)XVB_O) { p = xvw; rel = i - (int)XVW_O; }
    else if (i < (int)GQW_O) { p = xvb; rel = i - (int)XVB_O; }
    else if (i < (int)GQB_O) { p = gqw; rel = i - (int)GQW_O; }
    else if (i < (int)GKW_O) { p = gqb; rel = i - (int)GQB_O; }
    else if (i < (int)GKB_O) { p = gkw; rel = i - (int)GKW_O; }
    else if (i < (int)C1W_O) { p = gkb; rel = i - (int)GKB_O; }
    else if (i < (int)C1B_O) { p = c1w; rel = i - (int)C1W_O; }
    else if (i < (int)C2W_O) { p = c1b; rel = i - (int)C1B_O; }
    else if (i < (int)C2B_O) { p = c2w; rel = i - (int)C2W_O; }
    else if (i < (int)SCW_O) { p = c2b; rel = i - (int)C2B_O; }
    else if (i < (int)SCB_O) { p = scw; rel = i - (int)SCW_O; }
    else                     { p = scb; rel = i - (int)SCB_O; }
    ws[i] = ldin(p, rel, isbf);
  }
}

// ---------------- K1: channel attention scalars ----------------
__global__ __launch_bounds__(256) void k_chattn(const void* __restrict__ x,
                                                const void* __restrict__ g,
                                                float* __restrict__ ws) {
  int isbf = ((const int*)ws)[FLAG_O];
  int blk = blockIdx.x;
  int src = blk >> 7;
  int rem = blk & 127;
  int b = rem >> 6, c = rem & 63;
  const void* base = src ? g : x;
  size_t off0 = ((size_t)(b * 64 + c)) * N_;
  float s = 0.f;
  for (int i = threadIdx.x; i < N_; i += 256) s += ldin(base, off0 + i, isbf);
  __shared__ float red[256];
  red[threadIdx.x] = s;
  __syncthreads();
  for (int off = 128; off; off >>= 1) {
    if (threadIdx.x < off) red[threadIdx.x] += red[threadIdx.x + off];
    __syncthreads();
  }
  if (threadIdx.x == 0) {
    float p = red[0] * (1.f / (float)N_);
    float lw = ws[LW_O], lb = ws[LB_O];
    float h = leaky(lw * p + lb);
    float z = lw * h + lb;
    ws[CA_O + src * 128 + b * 64 + c] = 1.f / (1.f + expf(-z));
  }
}

// ---- conv tile constants: 16 output rows x 64 cols, 18 input rows, stride 68 ----
static constexpr int TRS = 68;

// coordconv stage value: f4 of channel ch, input row hh, cols ci..ci+3
DI float4 cc_stage(const void* in, int isbf, int b, int ch, int hh, int ci) {
  float4 v = make_float4(0.f, 0.f, 0.f, 0.f);
  if (hh >= 0 && hh < 64) {
    if (ch < 64) {
      size_t base = ((size_t)(b * 64 + ch)) * N_ + (size_t)hh * 64 + ci;
      if (!isbf) v = *reinterpret_cast<const float4*>((const float*)in + base);
      else {
        v.x = b2f(((const bf16*)in)[base]);     v.y = b2f(((const bf16*)in)[base + 1]);
        v.z = b2f(((const bf16*)in)[base + 2]); v.w = b2f(((const bf16*)in)[base + 3]);
      }
    } else if (ch == 64) {
      v.x = (float)ci * (2.f / 63.f) - 1.f;       v.y = (float)(ci + 1) * (2.f / 63.f) - 1.f;
      v.z = (float)(ci + 2) * (2.f / 63.f) - 1.f; v.w = (float)(ci + 3) * (2.f / 63.f) - 1.f;
    } else {
      float y = (float)hh * (2.f / 63.f) - 1.f;
      v = make_float4(y, y, y, y);
    }
  }
  return v;
}

// ---------------- K2: coord-conv 3x3, 4 oc x 4 px per thread, dbuf pipeline ----------------
__global__ __launch_bounds__(256) void k_coordconv(const void* __restrict__ x,
                                                   const void* __restrict__ g,
                                                   float* __restrict__ ws) {
  int isbf = ((const int*)ws)[FLAG_O];
  int blk = blockIdx.x;  // 256 = src*128 + b*64 + og*4 + rt
  int rt = blk & 3;  blk >>= 2;
  int og = blk & 15; blk >>= 4;
  int b  = blk & 1;  blk >>= 1;
  int src = blk;
  int o0 = og * 4;
  int h0 = rt * 16;
  const void* in = src ? g : x;
  float* outp = ws + (src ? GG_OFF : XG_OFF);
  __shared__ __align__(16) float wl[2376];          // [ch][tap][oo]
  __shared__ __align__(16) float tile[2][18 * TRS];
  int t = threadIdx.x;
  for (int idx = t; idx < 2376; idx += 256) {
    int ch = idx / 36, rr = idx % 36;
    int k = rr >> 2, oo = rr & 3;
    wl[idx] = ws[CW_O + (size_t)(o0 + oo) * 594 + ch * 9 + k];
  }
  int r = t >> 4, c0 = (t & 15) * 4;
  int ria = t >> 4, cia = (t & 15) * 4;             // chunk i = t
  int rib = 16 + (t >> 4 >= 0 ? (t >> 4) : 0);      // placeholder
  // chunk i = t covers rows 0..15; chunk i = t+256 (t<32) covers rows 16..17
  int rib2 = 16 + (t >> 4);                          // only valid for t<32
  int cib = (t & 15) * 4;
  bool hasb = (t < 32);
  float4 pfa = cc_stage(in, isbf, b, 0, h0 - 1 + ria, cia);
  float4 pfb = hasb ? cc_stage(in, isbf, b, 0, h0 - 1 + rib2, cib) : make_float4(0, 0, 0, 0);
  float acc[4][4] = {};
  for (int ch = 0; ch < 66; ++ch) {
    float* buf = tile[ch & 1];
    *reinterpret_cast<float4*>(&buf[ria * TRS + cia]) = pfa;
    if (hasb) *reinterpret_cast<float4*>(&buf[rib2 * TRS + cib]) = pfb;
    if (ch + 1 < 66) {
      pfa = cc_stage(in, isbf, b, ch + 1, h0 - 1 + ria, cia);
      if (hasb) pfb = cc_stage(in, isbf, b, ch + 1, h0 - 1 + rib2, cib);
    }
    __syncthreads();
#pragma unroll
    for (int ky = 0; ky < 3; ++ky) {
      int base = (r + ky) * TRS;
      float4 m = *reinterpret_cast<const float4*>(&buf[base + c0]);
      float left = (c0 > 0) ? buf[base + c0 - 1] : 0.f;
      float right = (c0 < 60) ? buf[base + c0 + 4] : 0.f;
      float t6[6] = {left, m.x, m.y, m.z, m.w, right};
#pragma unroll
      for (int kx = 0; kx < 3; ++kx) {
        float4 w4 = *reinterpret_cast<const float4*>(&wl[ch * 36 + (ky * 3 + kx) * 4]);
#pragma unroll
        for (int j = 0; j < 4; ++j) {
          float tp = t6[kx + j];
          acc[0][j] = fmaf(w4.x, tp, acc[0][j]);
          acc[1][j] = fmaf(w4.y, tp, acc[1][j]);
          acc[2][j] = fmaf(w4.z, tp, acc[2][j]);
          acc[3][j] = fmaf(w4.w, tp, acc[3][j]);
        }
      }
    }
  }
  size_t opix = (size_t)(h0 + r) * 64 + c0;
  const float* cav = ws + CA_O + src * 128 + b * 64 + o0;
#pragma unroll
  for (int oo = 0; oo < 4; ++oo) {
    float s = cav[oo];
    float4 o = make_float4(acc[oo][0] * s, acc[oo][1] * s, acc[oo][2] * s, acc[oo][3] * s);
    *reinterpret_cast<float4*>(outp + ((size_t)(b * 64 + o0 + oo)) * N_ + opix) = o;
  }
}

// ---------------- K3: 1x1 projections; outputs pre-split bf16 hi/lo ----------------
__global__ __launch_bounds__(256) void k_proj(float* __restrict__ ws) {
  int blk = blockIdx.x;  // 5 * 2 * 64
  int pt = blk & 63; blk >>= 6;
  int b  = blk & 1;  blk >>= 1;
  int which = blk;
  size_t in_o, w_o, b_o;
  size_t hU = 0, lU = 0;
  if (which == 0)      { in_o = XG_OFF; w_o = XQW_O; b_o = XQB_O; hU = QXH_U; lU = QXL_U; }
  else if (which == 1) { in_o = XG_OFF; w_o = XKW_O; b_o = XKB_O; hU = KXH_U; lU = KXL_U; }
  else if (which == 2) { in_o = XG_OFF; w_o = XVW_O; b_o = XVB_O; }
  else if (which == 3) { in_o = GG_OFF; w_o = GQW_O; b_o = GQB_O; hU = QGH_U; lU = QGL_U; }
  else                 { in_o = GG_OFF; w_o = GKW_O; b_o = GKB_O; hU = KGH_U; lU = KGL_U; }

  __shared__ float tile[64 * 64];
  __shared__ float wl[64 * 65];
  __shared__ float bl[64];
  unsigned short* us = (unsigned short*)ws;
  int t = threadIdx.x;
  int pb = pt * 64;
  const float* in0 = ws + in_o + (size_t)b * CN + pb;
  for (int c0 = (t >> 6); c0 < 64; c0 += 4)
    tile[c0 * 64 + (t & 63)] = in0[(size_t)c0 * N_ + (t & 63)];
  for (int idx = t; idx < 4096; idx += 256)
    wl[(idx >> 6) * 65 + (idx & 63)] = ws[w_o + idx];
  if (t < 64) bl[t] = ws[b_o + t];
  __syncthreads();
  int o = t & 63, grp = t >> 6;
  const float* wr = &wl[o * 65];
  float acc[16];
  float bv = bl[o];
#pragma unroll
  for (int j = 0; j < 16; ++j) acc[j] = bv;
  for (int c = 0; c < 64; ++c) {
    float wv = wr[c];
    const float4* tb = reinterpret_cast<const float4*>(&tile[c * 64 + grp * 16]);
    float4 t0 = tb[0], t1 = tb[1], t2 = tb[2], t3 = tb[3];
    acc[0] = fmaf(wv, t0.x, acc[0]);   acc[1] = fmaf(wv, t0.y, acc[1]);
    acc[2] = fmaf(wv, t0.z, acc[2]);   acc[3] = fmaf(wv, t0.w, acc[3]);
    acc[4] = fmaf(wv, t1.x, acc[4]);   acc[5] = fmaf(wv, t1.y, acc[5]);
    acc[6] = fmaf(wv, t1.z, acc[6]);   acc[7] = fmaf(wv, t1.w, acc[7]);
    acc[8] = fmaf(wv, t2.x, acc[8]);   acc[9] = fmaf(wv, t2.y, acc[9]);
    acc[10] = fmaf(wv, t2.z, acc[10]); acc[11] = fmaf(wv, t2.w, acc[11]);
    acc[12] = fmaf(wv, t3.x, acc[12]); acc[13] = fmaf(wv, t3.y, acc[13]);
    acc[14] = fmaf(wv, t3.z, acc[14]); acc[15] = fmaf(wv, t3.w, acc[15]);
  }
  if (which != 2) {
#pragma unroll
    for (int j = 0; j < 16; ++j) {
      size_t idx = ((size_t)b * N_ + pb + grp * 16 + j) * 64 + o;
      unsigned short hi = b16(acc[j]);
      us[hU + idx] = hi;
      us[lU + idx] = b16(acc[j] - fromb16(hi));
    }
  } else {
    __syncthreads();
    float* ot = wl;
#pragma unroll
    for (int j = 0; j < 16; ++j) ot[o * 65 + grp * 16 + j] = acc[j];
    __syncthreads();
    int o2 = t >> 2;
#pragma unroll
    for (int e = 0; e < 4; ++e) {
      int px = (t & 3) * 16 + e * 4;
      u16x4 hv, lv;
#pragma unroll
      for (int q = 0; q < 4; ++q) {
        float v = ot[o2 * 65 + px + q];
        unsigned short hi = b16(v);
        hv[q] = hi; lv[q] = b16(v - fromb16(hi));
      }
      size_t idx = ((size_t)(b * 64 + o2)) * N_ + pb + px;
      *reinterpret_cast<u16x4*>(&us[VXH_U + idx]) = hv;
      *reinterpret_cast<u16x4*>(&us[VXL_U + idx]) = lv;
    }
  }
}

// ---------------- K4: MFMA flash attention (pre-split inputs) ----------------
__global__ __launch_bounds__(256) void k_attn(float* __restrict__ ws) {
  unsigned short* us = (unsigned short*)ws;
  int blk = blockIdx.x;
  int half = blk & 1; blk >>= 1;
  int qt = blk & 63;  blk >>= 6;
  int b  = blk & 1;   blk >>= 1;
  int at = blk;
  const unsigned short* QH = us + (at ? QGH_U : QXH_U);
  const unsigned short* QL = us + (at ? QGL_U : QXL_U);
  const unsigned short* KHg = us + (at ? KGH_U : KXH_U);
  const unsigned short* KLg = us + (at ? KGL_U : KXL_U);
  const unsigned short* VHg = us + VXH_U;
  const unsigned short* VLg = us + VXL_U;
  float* Pg = ws + (at ? (half ? P1G_OFF : GG_OFF) : (half ? P1X_OFF : XG_OFF))
            + (size_t)b * CN + qt * 64;

  __shared__ unsigned short Kh[4096], Kl[4096], Vth[4096], Vtl[4096], Ph[4096], Pl[4096];
  __shared__ float sAl[64];

  int t = threadIdx.x;
  int w = t >> 6, lane = t & 63, quad = lane >> 4, l15 = lane & 15;
  int swz = l15 & 7;

  short8 qh[2], ql[2];
  {
    size_t qbase = ((size_t)b * N_ + qt * 64 + 16 * w + l15) * 64;
#pragma unroll
    for (int ks = 0; ks < 2; ++ks) {
      qh[ks] = *reinterpret_cast<const short8*>(&QH[qbase + ks * 32 + quad * 8]);
      ql[ks] = *reinterpret_cast<const short8*>(&QL[qbase + ks * 32 + quad * 8]);
    }
  }

  f32x4 Oa[4] = {{0.f, 0.f, 0.f, 0.f}, {0.f, 0.f, 0.f, 0.f},
                 {0.f, 0.f, 0.f, 0.f}, {0.f, 0.f, 0.f, 0.f}};
  float M[4] = {-1e30f, -1e30f, -1e30f, -1e30f};
  float L[4] = {0.f, 0.f, 0.f, 0.f};

  for (int mt = half * 32; mt < half * 32 + 32; ++mt) {
    __syncthreads();
#pragma unroll
    for (int it = 0; it < 2; ++it) {
      int f8 = it * 256 + t;
      int r = f8 >> 3, ch = f8 & 7;
      int off = r * 64 + ((ch ^ (r & 7)) << 3);
      size_t kgi = ((size_t)b * N_ + mt * 64 + r) * 64 + ch * 8;
      *reinterpret_cast<u16x8*>(&Kh[off]) = *reinterpret_cast<const u16x8*>(&KHg[kgi]);
      *reinterpret_cast<u16x8*>(&Kl[off]) = *reinterpret_cast<const u16x8*>(&KLg[kgi]);
      size_t vgi = ((size_t)(b * 64 + r)) * N_ + mt * 64 + ch * 8;
      *reinterpret_cast<u16x8*>(&Vth[off]) = *reinterpret_cast<const u16x8*>(&VHg[vgi]);
      *reinterpret_cast<u16x8*>(&Vtl[off]) = *reinterpret_cast<const u16x8*>(&VLg[vgi]);
    }
    __syncthreads();

    f32x4 S[4];
#pragma unroll
    for (int ms = 0; ms < 4; ++ms) {
      f32x4 acc = {0.f, 0.f, 0.f, 0.f};
#pragma unroll
      for (int ks = 0; ks < 2; ++ks) {
        int row = ms * 16 + l15;
        int off = row * 64 + (((ks * 4 + quad) ^ swz) << 3);
        short8 khf = *reinterpret_cast<const short8*>(&Kh[off]);
        short8 klf = *reinterpret_cast<const short8*>(&Kl[off]);
        acc = MFMA_BF16(ql[ks], khf, acc, 0, 0, 0);
        acc = MFMA_BF16(qh[ks], klf, acc, 0, 0, 0);
        acc = MFMA_BF16(qh[ks], khf, acc, 0, 0, 0);
      }
      S[ms] = acc;
    }

    float alpha[4];
#pragma unroll
    for (int r = 0; r < 4; ++r) {
      float tm = fmaxf(fmaxf(S[0][r], S[1][r]), fmaxf(S[2][r], S[3][r]));
#pragma unroll
      for (int d = 1; d < 16; d <<= 1) tm = fmaxf(tm, __shfl_xor(tm, d, 16));
      float mn = fmaxf(M[r], tm);
      float al = __expf(M[r] - mn);
      float ts = 0.f;
      float p[4];
#pragma unroll
      for (int ms = 0; ms < 4; ++ms) { p[ms] = __expf(S[ms][r] - mn); ts += p[ms]; }
#pragma unroll
      for (int d = 1; d < 16; d <<= 1) ts += __shfl_xor(ts, d, 16);
      L[r] = L[r] * al + ts;
      M[r] = mn;
      alpha[r] = al;
      int n = 16 * w + quad * 4 + r;
#pragma unroll
      for (int ms = 0; ms < 4; ++ms) {
        int m = ms * 16 + l15;
        int off = n * 64 + (((m >> 3) ^ (n & 7)) << 3) + (m & 7);
        unsigned short h = b16(p[ms]);
        unsigned short lo = b16(p[ms] - fromb16(h));
        Ph[off] = h; Pl[off] = lo;
      }
    }
    if (l15 < 4) {
      float av = (l15 == 0) ? alpha[0] : (l15 == 1) ? alpha[1] : (l15 == 2) ? alpha[2] : alpha[3];
      sAl[16 * w + quad * 4 + l15] = av;
    }
    float av = sAl[16 * w + l15];
#pragma unroll
    for (int cs = 0; cs < 4; ++cs) {
      Oa[cs][0] *= av; Oa[cs][1] *= av; Oa[cs][2] *= av; Oa[cs][3] *= av;
    }

#pragma unroll
    for (int cs = 0; cs < 4; ++cs) {
      f32x4 acc = Oa[cs];
#pragma unroll
      for (int ks = 0; ks < 2; ++ks) {
        int vrow = cs * 16 + l15;
        int voff = vrow * 64 + (((ks * 4 + quad) ^ swz) << 3);
        short8 vhf = *reinterpret_cast<const short8*>(&Vth[voff]);
        short8 vlf = *reinterpret_cast<const short8*>(&Vtl[voff]);
        int prow = 16 * w + l15;
        int poff = prow * 64 + (((ks * 4 + quad) ^ swz) << 3);
        short8 phf = *reinterpret_cast<const short8*>(&Ph[poff]);
        short8 plf = *reinterpret_cast<const short8*>(&Pl[poff]);
        acc = MFMA_BF16(vlf, phf, acc, 0, 0, 0);
        acc = MFMA_BF16(vhf, plf, acc, 0, 0, 0);
        acc = MFMA_BF16(vhf, phf, acc, 0, 0, 0);
      }
      Oa[cs] = acc;
    }
  }

#pragma unroll
  for (int cs = 0; cs < 4; ++cs) {
#pragma unroll
    for (int r = 0; r < 4; ++r) {
      int c = cs * 16 + quad * 4 + r;
      Pg[(size_t)c * N_ + 16 * w + l15] = Oa[cs][r];
    }
  }
  if (l15 < 4) {
    float Mv = (l15 == 0) ? M[0] : (l15 == 1) ? M[1] : (l15 == 2) ? M[2] : M[3];
    float Lv = (l15 == 0) ? L[0] : (l15 == 1) ? L[1] : (l15 == 2) ? L[2] : L[3];
    int mlb = ((at * 2 + half) * 2 + b) * 4096 + qt * 64 + 16 * w + quad * 4 + l15;
    ws[ML_OFF + mlb] = Mv;
    ws[MLL_OFF + mlb] = Lv;
  }
}

// ---------------- K5: merge halves + combine ----------------
__global__ __launch_bounds__(256) void k_merge(float* __restrict__ ws) {
  size_t i4 = (size_t)blockIdx.x * 256 + threadIdx.x;
  size_t i = i4 * 4;
  int n = (int)(i & 4095);
  int b = (int)(i >> 18);
  float gm = ws[GM_O], al = ws[AL_O];
  float4 p0x = *reinterpret_cast<const float4*>(ws + XG_OFF + i);
  float4 p1x = *reinterpret_cast<const float4*>(ws + P1X_OFF + i);
  float4 p0g = *reinterpret_cast<const float4*>(ws + GG_OFF + i);
  float4 p1g = *reinterpret_cast<const float4*>(ws + P1G_OFF + i);
  float4 M0x = *reinterpret_cast<const float4*>(ws + ML_OFF  + (0 + b) * 4096 + n);
  float4 L0x = *reinterpret_cast<const float4*>(ws + MLL_OFF + (0 + b) * 4096 + n);
  float4 M1x = *reinterpret_cast<const float4*>(ws + ML_OFF  + (2 + b) * 4096 + n);
  float4 L1x = *reinterpret_cast<const float4*>(ws + MLL_OFF + (2 + b) * 4096 + n);
  float4 M0g = *reinterpret_cast<const float4*>(ws + ML_OFF  + (4 + b) * 4096 + n);
  float4 L0g = *reinterpret_cast<const float4*>(ws + MLL_OFF + (4 + b) * 4096 + n);
  float4 M1g = *reinterpret_cast<const float4*>(ws + ML_OFF  + (6 + b) * 4096 + n);
  float4 L1g = *reinterpret_cast<const float4*>(ws + MLL_OFF + (6 + b) * 4096 + n);
  const float* p0xv = (const float*)&p0x; const float* p1xv = (const float*)&p1x;
  const float* p0gv = (const float*)&p0g; const float* p1gv = (const float*)&p1g;
  const float* m0xv = (const float*)&M0x; const float* l0xv = (const float*)&L0x;
  const float* m1xv = (const float*)&M1x; const float* l1xv = (const float*)&L1x;
  const float* m0gv = (const float*)&M0g; const float* l0gv = (const float*)&L0g;
  const float* m1gv = (const float*)&M1g; const float* l1gv = (const float*)&L1g;
  float4 go, ob;
  float* gov = (float*)&go; float* obv = (float*)&ob;
#pragma unroll
  for (int l = 0; l < 4; ++l) {
    float mx = fmaxf(m0xv[l], m1xv[l]);
    float w0 = __expf(m0xv[l] - mx), w1 = __expf(m1xv[l] - mx);
    float xc = (p0xv[l] * w0 + p1xv[l] * w1) / (l0xv[l] * w0 + l1xv[l] * w1);
    float mg = fmaxf(m0gv[l], m1gv[l]);
    float v0 = __expf(m0gv[l] - mg), v1 = __expf(m1gv[l] - mg);
    float gc = (p0gv[l] * v0 + p1gv[l] * v1) / (l0gv[l] * v0 + l1gv[l] * v1);
    gov[l] = gc;
    obv[l] = gm * xc + al * gc;
  }
  *reinterpret_cast<float4*>(ws + GG_OFF + i) = go;  // GO
  *reinterpret_cast<float4*>(ws + QX_OFF + i) = ob;  // OB
}

// ---------------- K6: u = leaky(conv3x3(leaky(out), c1)), 4oc x 4px, dbuf ----------------
__global__ __launch_bounds__(256) void k_conv1(float* __restrict__ ws) {
  int blk = blockIdx.x;  // 128 = b*64 + og*4 + rt
  int rt = blk & 3;  blk >>= 2;
  int og = blk & 15; blk >>= 4;
  int b  = blk;
  int o0 = og * 4;
  int h0 = rt * 16;
  __shared__ __align__(16) float wl[2304];
  __shared__ __align__(16) float tile[2][18 * TRS];
  int t = threadIdx.x;
  for (int idx = t; idx < 2304; idx += 256) {
    int ch = idx / 36, rr = idx % 36;
    int k = rr >> 2, oo = rr & 3;
    wl[idx] = ws[C1W_O + (size_t)(o0 + oo) * 576 + ch * 9 + k];
  }
  const float* in0 = ws + OB_OFF + (size_t)b * CN;
  int r = t >> 4, c0 = (t & 15) * 4;
  int ria = t >> 4, cia = (t & 15) * 4;
  int rib2 = 16 + (t >> 4);
  bool hasb = (t < 32);
  auto stage = [&](int ch, int ri, int ci) -> float4 {
    int hh = h0 - 1 + ri;
    float4 v = make_float4(0.f, 0.f, 0.f, 0.f);
    if (hh >= 0 && hh < 64) {
      float4 g = *reinterpret_cast<const float4*>(in0 + (size_t)ch * N_ + (size_t)hh * 64 + ci);
      v = make_float4(leaky(g.x), leaky(g.y), leaky(g.z), leaky(g.w));
    }
    return v;
  };
  float4 pfa = stage(0, ria, cia);
  float4 pfb = hasb ? stage(0, rib2, cia) : make_float4(0, 0, 0, 0);
  float acc[4][4] = {};
  for (int ch = 0; ch < 64; ++ch) {
    float* buf = tile[ch & 1];
    *reinterpret_cast<float4*>(&buf[ria * TRS + cia]) = pfa;
    if (hasb) *reinterpret_cast<float4*>(&buf[rib2 * TRS + cia]) = pfb;
    if (ch + 1 < 64) {
      pfa = stage(ch + 1, ria, cia);
      if (hasb) pfb = stage(ch + 1, rib2, cia);
    }
    __syncthreads();
#pragma unroll
    for (int ky = 0; ky < 3; ++ky) {
      int base = (r + ky) * TRS;
      float4 m = *reinterpret_cast<const float4*>(&buf[base + c0]);
      float left = (c0 > 0) ? buf[base + c0 - 1] : 0.f;
      float right = (c0 < 60) ? buf[base + c0 + 4] : 0.f;
      float t6[6] = {left, m.x, m.y, m.z, m.w, right};
#pragma unroll
      for (int kx = 0; kx < 3; ++kx) {
        float4 w4 = *reinterpret_cast<const float4*>(&wl[ch * 36 + (ky * 3 + kx) * 4]);
#pragma unroll
        for (int j = 0; j < 4; ++j) {
          float tp = t6[kx + j];
          acc[0][j] = fmaf(w4.x, tp, acc[0][j]);
          acc[1][j] = fmaf(w4.y, tp, acc[1][j]);
          acc[2][j] = fmaf(w4.z, tp, acc[2][j]);
          acc[3][j] = fmaf(w4.w, tp, acc[3][j]);
        }
      }
    }
  }
  size_t opix = (size_t)(h0 + r) * 64 + c0;
  float* ub = ws + UB_OFF + (size_t)b * CN;
#pragma unroll
  for (int oo = 0; oo < 4; ++oo) {
    float bb = ws[C1B_O + o0 + oo];
    float4 o = make_float4(leaky(acc[oo][0] + bb), leaky(acc[oo][1] + bb),
                           leaky(acc[oo][2] + bb), leaky(acc[oo][3] + bb));
    *reinterpret_cast<float4*>(ub + (size_t)(o0 + oo) * N_ + opix) = o;
  }
}

// ---------------- K7: final, 4oc x 4px, dbuf + reg-prefetched ob ----------------
__global__ __launch_bounds__(256) void k_final(const float* __restrict__ ws,
                                               float* __restrict__ out) {
  int blk = blockIdx.x;  // 128 = b*64 + og*4 + rt
  int rt = blk & 3;  blk >>= 2;
  int og = blk & 15; blk >>= 4;
  int b  = blk;
  int o0 = og * 4;
  int h0 = rt * 16;
  __shared__ __align__(16) float wl[2304];
  __shared__ __align__(16) float scl[256];  // [ch][oo]
  __shared__ __align__(16) float tile[2][18 * TRS];
  int t = threadIdx.x;
  for (int idx = t; idx < 2304; idx += 256) {
    int ch = idx / 36, rr = idx % 36;
    int k = rr >> 2, oo = rr & 3;
    wl[idx] = ws[C2W_O + (size_t)(o0 + oo) * 576 + ch * 9 + k];
  }
  {
    int oo = t & 3, ch = t >> 2;
    scl[ch * 4 + oo] = ws[SCW_O + (size_t)(o0 + oo) * 64 + ch];
  }
  const float* u0 = ws + UB_OFF + (size_t)b * CN;
  const float* ob0 = ws + OB_OFF + (size_t)b * CN;
  int r = t >> 4, c0 = (t & 15) * 4;
  int ria = t >> 4, cia = (t & 15) * 4;
  int rib2 = 16 + (t >> 4);
  bool hasb = (t < 32);
  size_t mypix = (size_t)(h0 + r) * 64 + c0;
  auto stage = [&](int ch, int ri, int ci) -> float4 {
    int hh = h0 - 1 + ri;
    if (hh >= 0 && hh < 64)
      return *reinterpret_cast<const float4*>(u0 + (size_t)ch * N_ + (size_t)hh * 64 + ci);
    return make_float4(0.f, 0.f, 0.f, 0.f);
  };
  float4 pfa = stage(0, ria, cia);
  float4 pfb = hasb ? stage(0, rib2, cia) : make_float4(0, 0, 0, 0);
  float4 obc = *reinterpret_cast<const float4*>(ob0 + mypix);  // ch 0
  float acc[4][4] = {};
  float sc[4] = {0.f, 0.f, 0.f, 0.f};  // per oc: dot over ch applied to 4 px separately
  float scp[4][4] = {};
  for (int ch = 0; ch < 64; ++ch) {
    float* buf = tile[ch & 1];
    *reinterpret_cast<float4*>(&buf[ria * TRS + cia]) = pfa;
    if (hasb) *reinterpret_cast<float4*>(&buf[rib2 * TRS + cia]) = pfb;
    float4 obn;
    if (ch + 1 < 64) {
      pfa = stage(ch + 1, ria, cia);
      if (hasb) pfb = stage(ch + 1, rib2, cia);
      obn = *reinterpret_cast<const float4*>(ob0 + (size_t)(ch + 1) * N_ + mypix);
    }
    __syncthreads();
#pragma unroll
    for (int ky = 0; ky < 3; ++ky) {
      int base = (r + ky) * TRS;
      float4 m = *reinterpret_cast<const float4*>(&buf[base + c0]);
      float left = (c0 > 0) ? buf[base + c0 - 1] : 0.f;
      float right = (c0 < 60) ? buf[base + c0 + 4] : 0.f;
      float t6[6] = {left, m.x, m.y, m.z, m.w, right};
#pragma unroll
      for (int kx = 0; kx < 3; ++kx) {
        float4 w4 = *reinterpret_cast<const float4*>(&wl[ch * 36 + (ky * 3 + kx) * 4]);
#pragma unroll
        for (int j = 0; j < 4; ++j) {
          float tp = t6[kx + j];
          acc[0][j] = fmaf(w4.x, tp, acc[0][j]);
          acc[1][j] = fmaf(w4.y, tp, acc[1][j]);
          acc[2][j] = fmaf(w4.z, tp, acc[2][j]);
          acc[3][j] = fmaf(w4.w, tp, acc[3][j]);
        }
      }
    }
    float4 s4 = *reinterpret_cast<const float4*>(&scl[ch * 4]);
    float obvv[4] = {obc.x, obc.y, obc.z, obc.w};
#pragma unroll
    for (int j = 0; j < 4; ++j) {
      scp[0][j] = fmaf(s4.x, obvv[j], scp[0][j]);
      scp[1][j] = fmaf(s4.y, obvv[j], scp[1][j]);
      scp[2][j] = fmaf(s4.z, obvv[j], scp[2][j]);
      scp[3][j] = fmaf(s4.w, obvv[j], scp[3][j]);
    }
    obc = obn;
  }
  (void)sc;
  const float* go = ws + GO_OFF + (size_t)b * CN;
  float* ob = out + (size_t)b * CN;
#pragma unroll
  for (int oo = 0; oo < 4; ++oo) {
    float c2b = ws[C2B_O + o0 + oo];
    float scb = ws[SCB_O + o0 + oo];
    float4 gv = *reinterpret_cast<const float4*>(go + (size_t)(o0 + oo) * N_ + mypix);
    float4 o;
    o.x = (acc[oo][0] + c2b) + (scp[oo][0] + scb) * gv.x;
    o.y = (acc[oo][1] + c2b) + (scp[oo][1] + scb) * gv.y;
    o.z = (acc[oo][2] + c2b) + (scp[oo][2] + scb) * gv.z;
    o.w = (acc[oo][3] + c2b) + (scp[oo][3] + scb) * gv.w;
    *reinterpret_cast<float4*>(ob + (size_t)(o0 + oo) * N_ + mypix) = o;
  }
}

extern "C" void kernel_launch(void* const* d_in, const int* in_sizes, int n_in,
                              void* d_out, int out_size, void* d_ws, size_t ws_size,
                              hipStream_t stream) {
  const void* x      = d_in[0];
  const void* guide  = d_in[1];
  float* out = (float*)d_out;
  float* ws = (float*)d_ws;

  k_detect<<<64, 256, 0, stream>>>(d_in[0], d_in[2], d_in[3], d_in[4],
                                   d_in[5], d_in[6], d_in[7], d_in[8],
                                   d_in[9], d_in[10], d_in[11], d_in[12],
                                   d_in[13], d_in[14], d_in[15], d_in[16],
                                   d_in[17], d_in[18], d_in[19], d_in[20],
                                   d_in[21], d_in[22], ws);
  k_chattn<<<256, 256, 0, stream>>>(x, guide, ws);
  k_coordconv<<<256, 256, 0, stream>>>(x, guide, ws);
  k_proj<<<640, 256, 0, stream>>>(ws);
  k_attn<<<512, 256, 0, stream>>>(ws);
  k_merge<<<512, 256, 0, stream>>>(ws);
  k_conv1<<<128, 256, 0, stream>>>(ws);
  k_final<<<128, 256, 0, stream>>>(ws, out);
}

// Round 10
// 401.348 us; speedup vs baseline: 7.7335x; 1.1205x over previous
//
#include <hip/hip_runtime.h>
#include <hip/hip_bf16.h>

using bf16 = __hip_bfloat16;

#define DI __device__ __forceinline__

typedef __attribute__((ext_vector_type(8))) short short8;
typedef __attribute__((ext_vector_type(8))) unsigned short u16x8;
typedef __attribute__((ext_vector_type(4))) unsigned short u16x4;
typedef __attribute__((ext_vector_type(4))) float f32x4;

#define MFMA_BF16 __builtin_amdgcn_mfma_f32_16x16x32_bf16

DI float leaky(float x) { return x > 0.f ? x : 0.1f * x; }

// bf16 split helpers (RNE). x = hi + lo to ~2^-16 relative.
DI unsigned short b16(float x) {
  union { float f; unsigned u; } v; v.f = x;
  unsigned r = v.u + 0x7FFFu + ((v.u >> 16) & 1u);
  return (unsigned short)(r >> 16);
}
DI float fromb16(unsigned short h) {
  union { unsigned u; float f; } v; v.u = ((unsigned)h) << 16; return v.f;
}

// Problem constants: B=2, C=64, H=64, W=64, N=4096
// Inputs are fp32 (established R3/R4: bf16 interpretation NaNs, fp32 passes).
static constexpr int N_ = 4096;
static constexpr size_t CN = 262144;
static constexpr size_t BCN = 524288;

// ---- Workspace layout (float indices) ----
static constexpr size_t XG_OFF = 137104;            // gated x; then x-attn half0 partial
static constexpr size_t GG_OFF = XG_OFF + BCN;      // gated g; then g-attn half0 partial; then GO
static constexpr size_t QX_OFF = GG_OFF + BCN;      // Qx split hi/lo; then OB
static constexpr size_t KX_OFF = QX_OFF + BCN;      // Kx split; then UB
static constexpr size_t VX_OFF = KX_OFF + BCN;      // V split, TRANSPOSED [b][c][n]
static constexpr size_t QG_OFF = VX_OFF + BCN;
static constexpr size_t KG_OFF = QG_OFF + BCN;
static constexpr size_t P1X_OFF = KG_OFF + BCN;
static constexpr size_t P1G_OFF = P1X_OFF + BCN;
static constexpr size_t ML_OFF  = P1G_OFF + BCN;
static constexpr size_t MLL_OFF = ML_OFF + 32768;
static constexpr size_t OB_OFF = QX_OFF;
static constexpr size_t UB_OFF = KX_OFF;
static constexpr size_t GO_OFF = GG_OFF;
static constexpr size_t QXH_U = QX_OFF * 2, QXL_U = QXH_U + BCN;
static constexpr size_t KXH_U = KX_OFF * 2, KXL_U = KXH_U + BCN;
static constexpr size_t VXH_U = VX_OFF * 2, VXL_U = VXH_U + BCN;
static constexpr size_t QGH_U = QG_OFF * 2, QGL_U = QGH_U + BCN;
static constexpr size_t KGH_U = KG_OFF * 2, KGL_U = KGH_U + BCN;
// Peak 19.7 MB (validated R6-R9)

// ---- conv tile constants: 16 output rows x 64 cols, 18 input rows, stride 68 ----
static constexpr int TRS = 68;

// coordconv stage value: f4 of channel ch, input row hh, cols ci..ci+3
DI float4 cc_stage(const float* in, int b, int ch, int hh, int ci) {
  float4 v = make_float4(0.f, 0.f, 0.f, 0.f);
  if (hh >= 0 && hh < 64) {
    if (ch < 64) {
      v = *reinterpret_cast<const float4*>(in + ((size_t)(b * 64 + ch)) * N_ + (size_t)hh * 64 + ci);
    } else if (ch == 64) {
      v.x = (float)ci * (2.f / 63.f) - 1.f;       v.y = (float)(ci + 1) * (2.f / 63.f) - 1.f;
      v.z = (float)(ci + 2) * (2.f / 63.f) - 1.f; v.w = (float)(ci + 3) * (2.f / 63.f) - 1.f;
    } else {
      float y = (float)hh * (2.f / 63.f) - 1.f;
      v = make_float4(y, y, y, y);
    }
  }
  return v;
}

// ---------------- K1: coord-conv 3x3 + inline channel attention ----------------
__global__ __launch_bounds__(256) void k_coordconv(const float* __restrict__ x,
                                                   const float* __restrict__ g,
                                                   const float* __restrict__ lw_p,
                                                   const float* __restrict__ lb_p,
                                                   const float* __restrict__ cw,
                                                   float* __restrict__ ws) {
  int blk = blockIdx.x;  // 256 = src*128 + b*64 + og*4 + rt
  int rt = blk & 3;  blk >>= 2;
  int og = blk & 15; blk >>= 4;
  int b  = blk & 1;  blk >>= 1;
  int src = blk;
  int o0 = og * 4;
  int h0 = rt * 16;
  const float* in = src ? g : x;
  float* outp = ws + (src ? GG_OFF : XG_OFF);
  __shared__ __align__(16) float wl[2376];          // [ch][tap][oo]
  __shared__ __align__(16) float tile[2][18 * TRS];
  __shared__ float sCA[4];
  int t = threadIdx.x;

  // channel attention for this block's 4 output channels (wave wv -> channel o0+wv)
  {
    int wv = t >> 6, lane = t & 63;
    const float* chp = in + ((size_t)(b * 64 + o0 + wv)) * N_;
    float s = 0.f;
    for (int i = lane; i < N_; i += 64) s += chp[i];
#pragma unroll
    for (int d = 1; d < 64; d <<= 1) s += __shfl_xor(s, d, 64);
    if (lane == 0) {
      float p = s * (1.f / (float)N_);
      float lwv = lw_p[0], lbv = lb_p[0];
      float h = leaky(lwv * p + lbv);
      sCA[wv] = 1.f / (1.f + expf(-(lwv * h + lbv)));
    }
  }

  for (int idx = t; idx < 2376; idx += 256) {
    int ch = idx / 36, rr = idx % 36;
    int k = rr >> 2, oo = rr & 3;
    wl[idx] = cw[(size_t)(o0 + oo) * 594 + ch * 9 + k];
  }
  int r = t >> 4, c0 = (t & 15) * 4;
  int ria = t >> 4, cia = (t & 15) * 4;
  int rib2 = 16 + (t >> 4);
  bool hasb = (t < 32);
  float4 pfa = cc_stage(in, b, 0, h0 - 1 + ria, cia);
  float4 pfb = hasb ? cc_stage(in, b, 0, h0 - 1 + rib2, cia) : make_float4(0, 0, 0, 0);
  float acc[4][4] = {};
  for (int ch = 0; ch < 66; ++ch) {
    float* buf = tile[ch & 1];
    *reinterpret_cast<float4*>(&buf[ria * TRS + cia]) = pfa;
    if (hasb) *reinterpret_cast<float4*>(&buf[rib2 * TRS + cia]) = pfb;
    if (ch + 1 < 66) {
      pfa = cc_stage(in, b, ch + 1, h0 - 1 + ria, cia);
      if (hasb) pfb = cc_stage(in, b, ch + 1, h0 - 1 + rib2, cia);
    }
    __syncthreads();
#pragma unroll
    for (int ky = 0; ky < 3; ++ky) {
      int base = (r + ky) * TRS;
      float4 m = *reinterpret_cast<const float4*>(&buf[base + c0]);
      float left = (c0 > 0) ? buf[base + c0 - 1] : 0.f;
      float right = (c0 < 60) ? buf[base + c0 + 4] : 0.f;
      float t6[6] = {left, m.x, m.y, m.z, m.w, right};
#pragma unroll
      for (int kx = 0; kx < 3; ++kx) {
        float4 w4 = *reinterpret_cast<const float4*>(&wl[ch * 36 + (ky * 3 + kx) * 4]);
#pragma unroll
        for (int j = 0; j < 4; ++j) {
          float tp = t6[kx + j];
          acc[0][j] = fmaf(w4.x, tp, acc[0][j]);
          acc[1][j] = fmaf(w4.y, tp, acc[1][j]);
          acc[2][j] = fmaf(w4.z, tp, acc[2][j]);
          acc[3][j] = fmaf(w4.w, tp, acc[3][j]);
        }
      }
    }
  }
  size_t opix = (size_t)(h0 + r) * 64 + c0;
#pragma unroll
  for (int oo = 0; oo < 4; ++oo) {
    float s = sCA[oo];
    float4 o = make_float4(acc[oo][0] * s, acc[oo][1] * s, acc[oo][2] * s, acc[oo][3] * s);
    *reinterpret_cast<float4*>(outp + ((size_t)(b * 64 + o0 + oo)) * N_ + opix) = o;
  }
}

// ---------------- K2: 1x1 projections; outputs pre-split bf16 hi/lo ----------------
__global__ __launch_bounds__(256) void k_proj(float* __restrict__ ws,
                                              const float* __restrict__ xqw, const float* __restrict__ xqb,
                                              const float* __restrict__ xkw, const float* __restrict__ xkb,
                                              const float* __restrict__ xvw, const float* __restrict__ xvb,
                                              const float* __restrict__ gqw, const float* __restrict__ gqb,
                                              const float* __restrict__ gkw, const float* __restrict__ gkb) {
  int blk = blockIdx.x;  // 5 * 2 * 64
  int pt = blk & 63; blk >>= 6;
  int b  = blk & 1;  blk >>= 1;
  int which = blk;
  size_t in_o;
  const float *wp, *bp;
  size_t hU = 0, lU = 0;
  if (which == 0)      { in_o = XG_OFF; wp = xqw; bp = xqb; hU = QXH_U; lU = QXL_U; }
  else if (which == 1) { in_o = XG_OFF; wp = xkw; bp = xkb; hU = KXH_U; lU = KXL_U; }
  else if (which == 2) { in_o = XG_OFF; wp = xvw; bp = xvb; }
  else if (which == 3) { in_o = GG_OFF; wp = gqw; bp = gqb; hU = QGH_U; lU = QGL_U; }
  else                 { in_o = GG_OFF; wp = gkw; bp = gkb; hU = KGH_U; lU = KGL_U; }

  __shared__ float tile[64 * 64];
  __shared__ float wl[64 * 65];
  __shared__ float bl[64];
  unsigned short* us = (unsigned short*)ws;
  int t = threadIdx.x;
  int pb = pt * 64;
  const float* in0 = ws + in_o + (size_t)b * CN + pb;
  for (int c0 = (t >> 6); c0 < 64; c0 += 4)
    tile[c0 * 64 + (t & 63)] = in0[(size_t)c0 * N_ + (t & 63)];
  for (int idx = t; idx < 4096; idx += 256)
    wl[(idx >> 6) * 65 + (idx & 63)] = wp[idx];
  if (t < 64) bl[t] = bp[t];
  __syncthreads();
  int o = t & 63, grp = t >> 6;
  const float* wr = &wl[o * 65];
  float acc[16];
  float bv = bl[o];
#pragma unroll
  for (int j = 0; j < 16; ++j) acc[j] = bv;
  for (int c = 0; c < 64; ++c) {
    float wv = wr[c];
    const float4* tb = reinterpret_cast<const float4*>(&tile[c * 64 + grp * 16]);
    float4 t0 = tb[0], t1 = tb[1], t2 = tb[2], t3 = tb[3];
    acc[0] = fmaf(wv, t0.x, acc[0]);   acc[1] = fmaf(wv, t0.y, acc[1]);
    acc[2] = fmaf(wv, t0.z, acc[2]);   acc[3] = fmaf(wv, t0.w, acc[3]);
    acc[4] = fmaf(wv, t1.x, acc[4]);   acc[5] = fmaf(wv, t1.y, acc[5]);
    acc[6] = fmaf(wv, t1.z, acc[6]);   acc[7] = fmaf(wv, t1.w, acc[7]);
    acc[8] = fmaf(wv, t2.x, acc[8]);   acc[9] = fmaf(wv, t2.y, acc[9]);
    acc[10] = fmaf(wv, t2.z, acc[10]); acc[11] = fmaf(wv, t2.w, acc[11]);
    acc[12] = fmaf(wv, t3.x, acc[12]); acc[13] = fmaf(wv, t3.y, acc[13]);
    acc[14] = fmaf(wv, t3.z, acc[14]); acc[15] = fmaf(wv, t3.w, acc[15]);
  }
  if (which != 2) {
#pragma unroll
    for (int j = 0; j < 16; ++j) {
      size_t idx = ((size_t)b * N_ + pb + grp * 16 + j) * 64 + o;
      unsigned short hi = b16(acc[j]);
      us[hU + idx] = hi;
      us[lU + idx] = b16(acc[j] - fromb16(hi));
    }
  } else {
    __syncthreads();
    float* ot = wl;
#pragma unroll
    for (int j = 0; j < 16; ++j) ot[o * 65 + grp * 16 + j] = acc[j];
    __syncthreads();
    int o2 = t >> 2;
#pragma unroll
    for (int e = 0; e < 4; ++e) {
      int px = (t & 3) * 16 + e * 4;
      u16x4 hv, lv;
#pragma unroll
      for (int q = 0; q < 4; ++q) {
        float v = ot[o2 * 65 + px + q];
        unsigned short hi = b16(v);
        hv[q] = hi; lv[q] = b16(v - fromb16(hi));
      }
      size_t idx = ((size_t)(b * 64 + o2)) * N_ + pb + px;
      *reinterpret_cast<u16x4*>(&us[VXH_U + idx]) = hv;
      *reinterpret_cast<u16x4*>(&us[VXL_U + idx]) = lv;
    }
  }
}

// ---------------- K3: MFMA flash attention (pre-split inputs, reg-prefetch dbuf) ----------------
__global__ __launch_bounds__(256) void k_attn(float* __restrict__ ws) {
  unsigned short* us = (unsigned short*)ws;
  int blk = blockIdx.x;
  int half = blk & 1; blk >>= 1;
  int qt = blk & 63;  blk >>= 6;
  int b  = blk & 1;   blk >>= 1;
  int at = blk;
  const unsigned short* QH = us + (at ? QGH_U : QXH_U);
  const unsigned short* QL = us + (at ? QGL_U : QXL_U);
  const unsigned short* KHg = us + (at ? KGH_U : KXH_U);
  const unsigned short* KLg = us + (at ? KGL_U : KXL_U);
  const unsigned short* VHg = us + VXH_U;
  const unsigned short* VLg = us + VXL_U;
  float* Pg = ws + (at ? (half ? P1G_OFF : GG_OFF) : (half ? P1X_OFF : XG_OFF))
            + (size_t)b * CN + qt * 64;

  __shared__ unsigned short Kh[4096], Kl[4096], Vth[4096], Vtl[4096], Ph[4096], Pl[4096];
  __shared__ float sAl[64];

  int t = threadIdx.x;
  int w = t >> 6, lane = t & 63, quad = lane >> 4, l15 = lane & 15;
  int swz = l15 & 7;

  short8 qh[2], ql[2];
  {
    size_t qbase = ((size_t)b * N_ + qt * 64 + 16 * w + l15) * 64;
#pragma unroll
    for (int ks = 0; ks < 2; ++ks) {
      qh[ks] = *reinterpret_cast<const short8*>(&QH[qbase + ks * 32 + quad * 8]);
      ql[ks] = *reinterpret_cast<const short8*>(&QL[qbase + ks * 32 + quad * 8]);
    }
  }

  // K/V prefetch registers (tile mt+1 loaded while computing mt)
  u16x8 rkh[2], rkl[2], rvh[2], rvl[2];
  auto prefetch = [&](int mt) {
#pragma unroll
    for (int it = 0; it < 2; ++it) {
      int f8 = it * 256 + t;
      int r = f8 >> 3, ch = f8 & 7;
      size_t kgi = ((size_t)b * N_ + mt * 64 + r) * 64 + ch * 8;
      rkh[it] = *reinterpret_cast<const u16x8*>(&KHg[kgi]);
      rkl[it] = *reinterpret_cast<const u16x8*>(&KLg[kgi]);
      size_t vgi = ((size_t)(b * 64 + r)) * N_ + mt * 64 + ch * 8;
      rvh[it] = *reinterpret_cast<const u16x8*>(&VHg[vgi]);
      rvl[it] = *reinterpret_cast<const u16x8*>(&VLg[vgi]);
    }
  };

  f32x4 Oa[4] = {{0.f, 0.f, 0.f, 0.f}, {0.f, 0.f, 0.f, 0.f},
                 {0.f, 0.f, 0.f, 0.f}, {0.f, 0.f, 0.f, 0.f}};
  float M[4] = {-1e30f, -1e30f, -1e30f, -1e30f};
  float L[4] = {0.f, 0.f, 0.f, 0.f};

  int mt0 = half * 32, mt1 = half * 32 + 32;
  prefetch(mt0);
  for (int mt = mt0; mt < mt1; ++mt) {
    __syncthreads();  // prev tile's LDS readers done
#pragma unroll
    for (int it = 0; it < 2; ++it) {
      int f8 = it * 256 + t;
      int r = f8 >> 3, ch = f8 & 7;
      int off = r * 64 + ((ch ^ (r & 7)) << 3);
      *reinterpret_cast<u16x8*>(&Kh[off]) = rkh[it];
      *reinterpret_cast<u16x8*>(&Kl[off]) = rkl[it];
      *reinterpret_cast<u16x8*>(&Vth[off]) = rvh[it];
      *reinterpret_cast<u16x8*>(&Vtl[off]) = rvl[it];
    }
    if (mt + 1 < mt1) prefetch(mt + 1);  // global latency overlaps compute below
    __syncthreads();

    f32x4 S[4];
#pragma unroll
    for (int ms = 0; ms < 4; ++ms) {
      f32x4 acc = {0.f, 0.f, 0.f, 0.f};
#pragma unroll
      for (int ks = 0; ks < 2; ++ks) {
        int row = ms * 16 + l15;
        int off = row * 64 + (((ks * 4 + quad) ^ swz) << 3);
        short8 khf = *reinterpret_cast<const short8*>(&Kh[off]);
        short8 klf = *reinterpret_cast<const short8*>(&Kl[off]);
        acc = MFMA_BF16(ql[ks], khf, acc, 0, 0, 0);
        acc = MFMA_BF16(qh[ks], klf, acc, 0, 0, 0);
        acc = MFMA_BF16(qh[ks], khf, acc, 0, 0, 0);
      }
      S[ms] = acc;
    }

    float alpha[4];
#pragma unroll
    for (int r = 0; r < 4; ++r) {
      float tm = fmaxf(fmaxf(S[0][r], S[1][r]), fmaxf(S[2][r], S[3][r]));
#pragma unroll
      for (int d = 1; d < 16; d <<= 1) tm = fmaxf(tm, __shfl_xor(tm, d, 16));
      float mn = fmaxf(M[r], tm);
      float al = __expf(M[r] - mn);
      float ts = 0.f;
      float p[4];
#pragma unroll
      for (int ms = 0; ms < 4; ++ms) { p[ms] = __expf(S[ms][r] - mn); ts += p[ms]; }
#pragma unroll
      for (int d = 1; d < 16; d <<= 1) ts += __shfl_xor(ts, d, 16);
      L[r] = L[r] * al + ts;
      M[r] = mn;
      alpha[r] = al;
      int n = 16 * w + quad * 4 + r;
#pragma unroll
      for (int ms = 0; ms < 4; ++ms) {
        int m = ms * 16 + l15;
        int off = n * 64 + (((m >> 3) ^ (n & 7)) << 3) + (m & 7);
        unsigned short h = b16(p[ms]);
        unsigned short lo = b16(p[ms] - fromb16(h));
        Ph[off] = h; Pl[off] = lo;
      }
    }
    if (l15 < 4) {
      float av = (l15 == 0) ? alpha[0] : (l15 == 1) ? alpha[1] : (l15 == 2) ? alpha[2] : alpha[3];
      sAl[16 * w + quad * 4 + l15] = av;
    }
    float av = sAl[16 * w + l15];
#pragma unroll
    for (int cs = 0; cs < 4; ++cs) {
      Oa[cs][0] *= av; Oa[cs][1] *= av; Oa[cs][2] *= av; Oa[cs][3] *= av;
    }

#pragma unroll
    for (int cs = 0; cs < 4; ++cs) {
      f32x4 acc = Oa[cs];
#pragma unroll
      for (int ks = 0; ks < 2; ++ks) {
        int vrow = cs * 16 + l15;
        int voff = vrow * 64 + (((ks * 4 + quad) ^ swz) << 3);
        short8 vhf = *reinterpret_cast<const short8*>(&Vth[voff]);
        short8 vlf = *reinterpret_cast<const short8*>(&Vtl[voff]);
        int prow = 16 * w + l15;
        int poff = prow * 64 + (((ks * 4 + quad) ^ swz) << 3);
        short8 phf = *reinterpret_cast<const short8*>(&Ph[poff]);
        short8 plf = *reinterpret_cast<const short8*>(&Pl[poff]);
        acc = MFMA_BF16(vlf, phf, acc, 0, 0, 0);
        acc = MFMA_BF16(vhf, plf, acc, 0, 0, 0);
        acc = MFMA_BF16(vhf, phf, acc, 0, 0, 0);
      }
      Oa[cs] = acc;
    }
  }

#pragma unroll
  for (int cs = 0; cs < 4; ++cs) {
#pragma unroll
    for (int r = 0; r < 4; ++r) {
      int c = cs * 16 + quad * 4 + r;
      Pg[(size_t)c * N_ + 16 * w + l15] = Oa[cs][r];
    }
  }
  if (l15 < 4) {
    float Mv = (l15 == 0) ? M[0] : (l15 == 1) ? M[1] : (l15 == 2) ? M[2] : M[3];
    float Lv = (l15 == 0) ? L[0] : (l15 == 1) ? L[1] : (l15 == 2) ? L[2] : L[3];
    int mlb = ((at * 2 + half) * 2 + b) * 4096 + qt * 64 + 16 * w + quad * 4 + l15;
    ws[ML_OFF + mlb] = Mv;
    ws[MLL_OFF + mlb] = Lv;
  }
}

// ---------------- K4: merge halves + combine ----------------
__global__ __launch_bounds__(256) void k_merge(float* __restrict__ ws,
                                               const float* __restrict__ gm_p,
                                               const float* __restrict__ al_p) {
  size_t i4 = (size_t)blockIdx.x * 256 + threadIdx.x;
  size_t i = i4 * 4;
  int n = (int)(i & 4095);
  int b = (int)(i >> 18);
  float gm = gm_p[0], al = al_p[0];
  float4 p0x = *reinterpret_cast<const float4*>(ws + XG_OFF + i);
  float4 p1x = *reinterpret_cast<const float4*>(ws + P1X_OFF + i);
  float4 p0g = *reinterpret_cast<const float4*>(ws + GG_OFF + i);
  float4 p1g = *reinterpret_cast<const float4*>(ws + P1G_OFF + i);
  float4 M0x = *reinterpret_cast<const float4*>(ws + ML_OFF  + (0 + b) * 4096 + n);
  float4 L0x = *reinterpret_cast<const float4*>(ws + MLL_OFF + (0 + b) * 4096 + n);
  float4 M1x = *reinterpret_cast<const float4*>(ws + ML_OFF  + (2 + b) * 4096 + n);
  float4 L1x = *reinterpret_cast<const float4*>(ws + MLL_OFF + (2 + b) * 4096 + n);
  float4 M0g = *reinterpret_cast<const float4*>(ws + ML_OFF  + (4 + b) * 4096 + n);
  float4 L0g = *reinterpret_cast<const float4*>(ws + MLL_OFF + (4 + b) * 4096 + n);
  float4 M1g = *reinterpret_cast<const float4*>(ws + ML_OFF  + (6 + b) * 4096 + n);
  float4 L1g = *reinterpret_cast<const float4*>(ws + MLL_OFF + (6 + b) * 4096 + n);
  const float* p0xv = (const float*)&p0x; const float* p1xv = (const float*)&p1x;
  const float* p0gv = (const float*)&p0g; const float* p1gv = (const float*)&p1g;
  const float* m0xv = (const float*)&M0x; const float* l0xv = (const float*)&L0x;
  const float* m1xv = (const float*)&M1x; const float* l1xv = (const float*)&L1x;
  const float* m0gv = (const float*)&M0g; const float* l0gv = (const float*)&L0g;
  const float* m1gv = (const float*)&M1g; const float* l1gv = (const float*)&L1g;
  float4 go, ob;
  float* gov = (float*)&go; float* obv = (float*)&ob;
#pragma unroll
  for (int l = 0; l < 4; ++l) {
    float mx = fmaxf(m0xv[l], m1xv[l]);
    float w0 = __expf(m0xv[l] - mx), w1 = __expf(m1xv[l] - mx);
    float xc = (p0xv[l] * w0 + p1xv[l] * w1) / (l0xv[l] * w0 + l1xv[l] * w1);
    float mg = fmaxf(m0gv[l], m1gv[l]);
    float v0 = __expf(m0gv[l] - mg), v1 = __expf(m1gv[l] - mg);
    float gc = (p0gv[l] * v0 + p1gv[l] * v1) / (l0gv[l] * v0 + l1gv[l] * v1);
    gov[l] = gc;
    obv[l] = gm * xc + al * gc;
  }
  *reinterpret_cast<float4*>(ws + GG_OFF + i) = go;  // GO
  *reinterpret_cast<float4*>(ws + QX_OFF + i) = ob;  // OB
}

// ---------------- K5: u = leaky(conv3x3(leaky(out), c1)), 4oc x 4px, dbuf ----------------
__global__ __launch_bounds__(256) void k_conv1(float* __restrict__ ws,
                                               const float* __restrict__ c1w,
                                               const float* __restrict__ c1b) {
  int blk = blockIdx.x;  // 128 = b*64 + og*4 + rt
  int rt = blk & 3;  blk >>= 2;
  int og = blk & 15; blk >>= 4;
  int b  = blk;
  int o0 = og * 4;
  int h0 = rt * 16;
  __shared__ __align__(16) float wl[2304];
  __shared__ __align__(16) float tile[2][18 * TRS];
  int t = threadIdx.x;
  for (int idx = t; idx < 2304; idx += 256) {
    int ch = idx / 36, rr = idx % 36;
    int k = rr >> 2, oo = rr & 3;
    wl[idx] = c1w[(size_t)(o0 + oo) * 576 + ch * 9 + k];
  }
  const float* in0 = ws + OB_OFF + (size_t)b * CN;
  int r = t >> 4, c0 = (t & 15) * 4;
  int ria = t >> 4, cia = (t & 15) * 4;
  int rib2 = 16 + (t >> 4);
  bool hasb = (t < 32);
  auto stage = [&](int ch, int ri, int ci) -> float4 {
    int hh = h0 - 1 + ri;
    float4 v = make_float4(0.f, 0.f, 0.f, 0.f);
    if (hh >= 0 && hh < 64) {
      float4 g = *reinterpret_cast<const float4*>(in0 + (size_t)ch * N_ + (size_t)hh * 64 + ci);
      v = make_float4(leaky(g.x), leaky(g.y), leaky(g.z), leaky(g.w));
    }
    return v;
  };
  float4 pfa = stage(0, ria, cia);
  float4 pfb = hasb ? stage(0, rib2, cia) : make_float4(0, 0, 0, 0);
  float acc[4][4] = {};
  for (int ch = 0; ch < 64; ++ch) {
    float* buf = tile[ch & 1];
    *reinterpret_cast<float4*>(&buf[ria * TRS + cia]) = pfa;
    if (hasb) *reinterpret_cast<float4*>(&buf[rib2 * TRS + cia]) = pfb;
    if (ch + 1 < 64) {
      pfa = stage(ch + 1, ria, cia);
      if (hasb) pfb = stage(ch + 1, rib2, cia);
    }
    __syncthreads();
#pragma unroll
    for (int ky = 0; ky < 3; ++ky) {
      int base = (r + ky) * TRS;
      float4 m = *reinterpret_cast<const float4*>(&buf[base + c0]);
      float left = (c0 > 0) ? buf[base + c0 - 1] : 0.f;
      float right = (c0 < 60) ? buf[base + c0 + 4] : 0.f;
      float t6[6] = {left, m.x, m.y, m.z, m.w, right};
#pragma unroll
      for (int kx = 0; kx < 3; ++kx) {
        float4 w4 = *reinterpret_cast<const float4*>(&wl[ch * 36 + (ky * 3 + kx) * 4]);
#pragma unroll
        for (int j = 0; j < 4; ++j) {
          float tp = t6[kx + j];
          acc[0][j] = fmaf(w4.x, tp, acc[0][j]);
          acc[1][j] = fmaf(w4.y, tp, acc[1][j]);
          acc[2][j] = fmaf(w4.z, tp, acc[2][j]);
          acc[3][j] = fmaf(w4.w, tp, acc[3][j]);
        }
      }
    }
  }
  size_t opix = (size_t)(h0 + r) * 64 + c0;
  float* ub = ws + UB_OFF + (size_t)b * CN;
#pragma unroll
  for (int oo = 0; oo < 4; ++oo) {
    float bb = c1b[o0 + oo];
    float4 o = make_float4(leaky(acc[oo][0] + bb), leaky(acc[oo][1] + bb),
                           leaky(acc[oo][2] + bb), leaky(acc[oo][3] + bb));
    *reinterpret_cast<float4*>(ub + (size_t)(o0 + oo) * N_ + opix) = o;
  }
}

// ---------------- K6: final, 4oc x 4px, dbuf + reg-prefetched ob ----------------
__global__ __launch_bounds__(256) void k_final(const float* __restrict__ ws,
                                               const float* __restrict__ c2w,
                                               const float* __restrict__ c2b,
                                               const float* __restrict__ scw,
                                               const float* __restrict__ scb,
                                               float* __restrict__ out) {
  int blk = blockIdx.x;  // 128 = b*64 + og*4 + rt
  int rt = blk & 3;  blk >>= 2;
  int og = blk & 15; blk >>= 4;
  int b  = blk;
  int o0 = og * 4;
  int h0 = rt * 16;
  __shared__ __align__(16) float wl[2304];
  __shared__ __align__(16) float scl[256];  // [ch][oo]
  __shared__ __align__(16) float tile[2][18 * TRS];
  int t = threadIdx.x;
  for (int idx = t; idx < 2304; idx += 256) {
    int ch = idx / 36, rr = idx % 36;
    int k = rr >> 2, oo = rr & 3;
    wl[idx] = c2w[(size_t)(o0 + oo) * 576 + ch * 9 + k];
  }
  {
    int oo = t & 3, ch = t >> 2;
    scl[ch * 4 + oo] = scw[(size_t)(o0 + oo) * 64 + ch];
  }
  const float* u0 = ws + UB_OFF + (size_t)b * CN;
  const float* ob0 = ws + OB_OFF + (size_t)b * CN;
  int r = t >> 4, c0 = (t & 15) * 4;
  int ria = t >> 4, cia = (t & 15) * 4;
  int rib2 = 16 + (t >> 4);
  bool hasb = (t < 32);
  size_t mypix = (size_t)(h0 + r) * 64 + c0;
  auto stage = [&](int ch, int ri, int ci) -> float4 {
    int hh = h0 - 1 + ri;
    if (hh >= 0 && hh < 64)
      return *reinterpret_cast<const float4*>(u0 + (size_t)ch * N_ + (size_t)hh * 64 + ci);
    return make_float4(0.f, 0.f, 0.f, 0.f);
  };
  float4 pfa = stage(0, ria, cia);
  float4 pfb = hasb ? stage(0, rib2, cia) : make_float4(0, 0, 0, 0);
  float4 obc = *reinterpret_cast<const float4*>(ob0 + mypix);  // ch 0
  float acc[4][4] = {};
  float scp[4][4] = {};
  for (int ch = 0; ch < 64; ++ch) {
    float* buf = tile[ch & 1];
    *reinterpret_cast<float4*>(&buf[ria * TRS + cia]) = pfa;
    if (hasb) *reinterpret_cast<float4*>(&buf[rib2 * TRS + cia]) = pfb;
    float4 obn;
    if (ch + 1 < 64) {
      pfa = stage(ch + 1, ria, cia);
      if (hasb) pfb = stage(ch + 1, rib2, cia);
      obn = *reinterpret_cast<const float4*>(ob0 + (size_t)(ch + 1) * N_ + mypix);
    }
    __syncthreads();
#pragma unroll
    for (int ky = 0; ky < 3; ++ky) {
      int base = (r + ky) * TRS;
      float4 m = *reinterpret_cast<const float4*>(&buf[base + c0]);
      float left = (c0 > 0) ? buf[base + c0 - 1] : 0.f;
      float right = (c0 < 60) ? buf[base + c0 + 4] : 0.f;
      float t6[6] = {left, m.x, m.y, m.z, m.w, right};
#pragma unroll
      for (int kx = 0; kx < 3; ++kx) {
        float4 w4 = *reinterpret_cast<const float4*>(&wl[ch * 36 + (ky * 3 + kx) * 4]);
#pragma unroll
        for (int j = 0; j < 4; ++j) {
          float tp = t6[kx + j];
          acc[0][j] = fmaf(w4.x, tp, acc[0][j]);
          acc[1][j] = fmaf(w4.y, tp, acc[1][j]);
          acc[2][j] = fmaf(w4.z, tp, acc[2][j]);
          acc[3][j] = fmaf(w4.w, tp, acc[3][j]);
        }
      }
    }
    float4 s4 = *reinterpret_cast<const float4*>(&scl[ch * 4]);
    float obvv[4] = {obc.x, obc.y, obc.z, obc.w};
#pragma unroll
    for (int j = 0; j < 4; ++j) {
      scp[0][j] = fmaf(s4.x, obvv[j], scp[0][j]);
      scp[1][j] = fmaf(s4.y, obvv[j], scp[1][j]);
      scp[2][j] = fmaf(s4.z, obvv[j], scp[2][j]);
      scp[3][j] = fmaf(s4.w, obvv[j], scp[3][j]);
    }
    obc = obn;
  }
  const float* go = ws + GO_OFF + (size_t)b * CN;
  float* ob = out + (size_t)b * CN;
#pragma unroll
  for (int oo = 0; oo < 4; ++oo) {
    float c2bv = c2b[o0 + oo];
    float scbv = scb[o0 + oo];
    float4 gv = *reinterpret_cast<const float4*>(go + (size_t)(o0 + oo) * N_ + mypix);
    float4 o;
    o.x = (acc[oo][0] + c2bv) + (scp[oo][0] + scbv) * gv.x;
    o.y = (acc[oo][1] + c2bv) + (scp[oo][1] + scbv) * gv.y;
    o.z = (acc[oo][2] + c2bv) + (scp[oo][2] + scbv) * gv.z;
    o.w = (acc[oo][3] + c2bv) + (scp[oo][3] + scbv) * gv.w;
    *reinterpret_cast<float4*>(ob + (size_t)(o0 + oo) * N_ + mypix) = o;
  }
}

extern "C" void kernel_launch(void* const* d_in, const int* in_sizes, int n_in,
                              void* d_out, int out_size, void* d_ws, size_t ws_size,
                              hipStream_t stream) {
  const float* x     = (const float*)d_in[0];
  const float* guide = (const float*)d_in[1];
  const float* lin_w = (const float*)d_in[2];
  const float* lin_b = (const float*)d_in[3];
  const float* cw    = (const float*)d_in[4];
  const float* xq_w  = (const float*)d_in[5];
  const float* xq_b  = (const float*)d_in[6];
  const float* xk_w  = (const float*)d_in[7];
  const float* xk_b  = (const float*)d_in[8];
  const float* xv_w  = (const float*)d_in[9];
  const float* xv_b  = (const float*)d_in[10];
  const float* gq_w  = (const float*)d_in[11];
  const float* gq_b  = (const float*)d_in[12];
  const float* gk_w  = (const float*)d_in[13];
  const float* gk_b  = (const float*)d_in[14];
  const float* gamma = (const float*)d_in[15];
  const float* alpha = (const float*)d_in[16];
  const float* c1_w  = (const float*)d_in[17];
  const float* c1_b  = (const float*)d_in[18];
  const float* c2_w  = (const float*)d_in[19];
  const float* c2_b  = (const float*)d_in[20];
  const float* sc_w  = (const float*)d_in[21];
  const float* sc_b  = (const float*)d_in[22];
  float* out = (float*)d_out;
  float* ws = (float*)d_ws;

  k_coordconv<<<256, 256, 0, stream>>>(x, guide, lin_w, lin_b, cw, ws);
  k_proj<<<640, 256, 0, stream>>>(ws, xq_w, xq_b, xk_w, xk_b, xv_w, xv_b,
                                  gq_w, gq_b, gk_w, gk_b);
  k_attn<<<512, 256, 0, stream>>>(ws);
  k_merge<<<512, 256, 0, stream>>>(ws, gamma, alpha);
  k_conv1<<<128, 256, 0, stream>>>(ws, c1_w, c1_b);
  k_final<<<128, 256, 0, stream>>>(ws, c2_w, c2_b, sc_w, sc_b, out);
}